// Round 2
// baseline (1155.524 us; speedup 1.0000x reference)
//
#include <hip/hip_runtime.h>
#include <hip/hip_bf16.h>
#include <stdint.h>

// ---------------------------------------------------------------------------
// SARoutingBlock: alphas = soft_routing(v); qkv projections; 3-order masked
// softmax attention combined by alphas; output projection.
// B=8, N=512, HID=768, HEADS=12, dk=64, ORDERS=3.
// Runtime-sniffs mask encoding AND float dtype (bf16 vs fp32) since the
// harness's device encoding is ambiguous (round-1 NaN => fp32 suspicion).
// ---------------------------------------------------------------------------

typedef __bf16 bf16x8 __attribute__((ext_vector_type(8)));
typedef float f32x4 __attribute__((ext_vector_type(4)));

#define NEGV -1e9f

__device__ __forceinline__ float b2f(unsigned short h) {
    union { unsigned int u; float f; } x; x.u = ((unsigned int)h) << 16; return x.f;
}
__device__ __forceinline__ unsigned short f2b(float f) {
    union { float f; unsigned int u; } x; x.f = f;
    unsigned int u = x.u + 0x7FFFu + ((x.u >> 16) & 1u);
    return (unsigned short)(u >> 16);
}
// RNE fp32->bf16 on raw bits, pack two into one word
__device__ __forceinline__ unsigned int packbf(unsigned int u0, unsigned int u1) {
    unsigned int r0 = (u0 + 0x7FFFu + ((u0 >> 16) & 1u)) >> 16;
    unsigned int r1 = (u1 + 0x7FFFu + ((u1 >> 16) & 1u)) & 0xFFFF0000u;
    return r0 | r1;
}
// load 8 consecutive elements as bf16x8 (packed in uint4), dtype-branched
__device__ __forceinline__ uint4 load8bf(const void* base, int elemOff, int isF32) {
    if (!isF32) return *(const uint4*)((const unsigned short*)base + elemOff);
    const uint4* f = (const uint4*)((const float*)base + elemOff);
    uint4 a = f[0], b = f[1];
    uint4 r;
    r.x = packbf(a.x, a.y);
    r.y = packbf(a.z, a.w);
    r.z = packbf(b.x, b.y);
    r.w = packbf(b.z, b.w);
    return r;
}
__device__ __forceinline__ float loadF(const void* p, int idx, int isF32) {
    return isF32 ? ((const float*)p)[idx] : b2f(((const unsigned short*)p)[idx]);
}

// ---------------------------------------------------------------------------
// Sniffer: flags[0] = mask mode (0=i32, 1=u8, 2=f32, 3=bf16)
//          flags[1] = v/k/q dtype (0=bf16, 1=fp32)
//          flags[2] = weights dtype (0=bf16, 1=fp32)
// fp32 detection: decode words as bf16 pairs; genuine bf16 activations/weights
// are |x|<10, fp32-mantissa halves blow past 1e4 / NaN with certainty over
// a 16k-half sample.
// ---------------------------------------------------------------------------
__global__ void sniff_kernel(const unsigned int* __restrict__ mp,
                             const unsigned int* __restrict__ vp,
                             const unsigned int* __restrict__ wp,
                             int* __restrict__ flags)
{
    __shared__ int oki, oku, okf, badv, badw;
    if (threadIdx.x == 0) { oki = 1; oku = 1; okf = 1; badv = 0; badw = 0; }
    __syncthreads();
    int li = 1, lu = 1, lf = 1, bv = 0, bw = 0;
    for (int i = threadIdx.x; i < 16384; i += 256) {
        unsigned int w = mp[i];
        if (w > 1u) li = 0;
        if (w & 0xFEFEFEFEu) lu = 0;
        if (w != 0u && w != 0x3F800000u) lf = 0;
    }
    for (int i = threadIdx.x; i < 8192; i += 256) {
        unsigned int w = vp[i];
        float f0 = b2f((unsigned short)(w & 0xFFFF));
        float f1 = b2f((unsigned short)(w >> 16));
        if (!(fabsf(f0) < 1e4f) || !(fabsf(f1) < 1e4f)) bv = 1;
        w = wp[i];
        f0 = b2f((unsigned short)(w & 0xFFFF));
        f1 = b2f((unsigned short)(w >> 16));
        if (!(fabsf(f0) < 1e4f) || !(fabsf(f1) < 1e4f)) bw = 1;
    }
    if (!li) atomicAnd(&oki, 0);
    if (!lu) atomicAnd(&oku, 0);
    if (!lf) atomicAnd(&okf, 0);
    if (bv) atomicOr(&badv, 1);
    if (bw) atomicOr(&badw, 1);
    __syncthreads();
    if (threadIdx.x == 0) {
        flags[0] = oki ? 0 : (oku ? 1 : (okf ? 2 : 3));
        flags[1] = badv;
        flags[2] = badw;
    }
}

// ---------------------------------------------------------------------------
// Routing: alphas[b][3] = softmax(MLP(attention-pooled v))
// One block per batch, 512 threads.
// ---------------------------------------------------------------------------
__global__ __launch_bounds__(512) void routing_kernel(
        const void* __restrict__ v,
        const void* __restrict__ pool_w,
        const void* __restrict__ pool_b,
        const void* __restrict__ w1,
        const void* __restrict__ w2,
        const void* __restrict__ b2,
        const int* __restrict__ flags,
        float* __restrict__ alphas)
{
    __shared__ float pw[768];
    __shared__ float scs[512];
    __shared__ float pool[768];
    __shared__ float hid[384];
    __shared__ float red[16];
    const int t = threadIdx.x;
    const int b = blockIdx.x;
    const int dtV = flags[1], dtW = flags[2];

    for (int d = t; d < 768; d += 512) pw[d] = loadF(pool_w, d, dtW);
    __syncthreads();

    // scores = v @ pool_w + pool_b ; pad rows (sum|v|==0) -> NEG
    float dot = 0.f, asum = 0.f;
    if (!dtV) {
        const unsigned short* vrow = (const unsigned short*)v + ((b << 9) + t) * 768;
        for (int i = 0; i < 96; i++) {
            uint4 u = ((const uint4*)vrow)[i];
            unsigned int uu[4] = {u.x, u.y, u.z, u.w};
            #pragma unroll
            for (int j = 0; j < 4; j++) {
                float f0 = b2f((unsigned short)(uu[j] & 0xFFFF));
                float f1 = b2f((unsigned short)(uu[j] >> 16));
                asum += fabsf(f0) + fabsf(f1);
                dot += f0 * pw[i * 8 + j * 2] + f1 * pw[i * 8 + j * 2 + 1];
            }
        }
    } else {
        const float* vrow = (const float*)v + ((b << 9) + t) * 768;
        for (int i = 0; i < 192; i++) {
            float4 u = ((const float4*)vrow)[i];
            asum += fabsf(u.x) + fabsf(u.y) + fabsf(u.z) + fabsf(u.w);
            dot += u.x * pw[4*i] + u.y * pw[4*i+1] + u.z * pw[4*i+2] + u.w * pw[4*i+3];
        }
    }
    float scv = dot + loadF(pool_b, 0, dtW);
    if (asum == 0.f) scv = NEGV;

    // block softmax over 512
    float mx = scv;
    #pragma unroll
    for (int off = 1; off < 64; off <<= 1) mx = fmaxf(mx, __shfl_xor(mx, off));
    if ((t & 63) == 0) red[t >> 6] = mx;
    __syncthreads();
    float M = red[0];
    #pragma unroll
    for (int i = 1; i < 8; i++) M = fmaxf(M, red[i]);
    float e = __expf(scv - M);
    __syncthreads();
    float sm = e;
    #pragma unroll
    for (int off = 1; off < 64; off <<= 1) sm += __shfl_xor(sm, off);
    if ((t & 63) == 0) red[t >> 6] = sm;
    __syncthreads();
    float SS = 0.f;
    #pragma unroll
    for (int i = 0; i < 8; i++) SS += red[i];
    scs[t] = e / SS;
    __syncthreads();

    // pooled[d] = sum_n v[b,n,d] * p[n]
    for (int d = t; d < 768; d += 512) {
        float a = 0.f;
        for (int n = 0; n < 512; n++)
            a += loadF(v, ((b << 9) + n) * 768 + d, dtV) * scs[n];
        pool[d] = a;
    }
    __syncthreads();

    // hidden = relu(pooled @ w1)   (w1: [768][384])
    for (int j = t; j < 384; j += 512) {
        float a = 0.f;
        for (int d = 0; d < 768; d++) a += pool[d] * loadF(w1, d * 384 + j, dtW);
        hid[j] = fmaxf(a, 0.f);
    }
    __syncthreads();

    // logits + softmax -> alphas
    if (t < 3) {
        float a = loadF(b2, t, dtW);
        for (int j = 0; j < 384; j++) a += hid[j] * loadF(w2, j * 3 + t, dtW);
        red[8 + t] = a;
    }
    __syncthreads();
    if (t == 0) {
        float l0 = red[8], l1 = red[9], l2 = red[10];
        float mm = fmaxf(l0, fmaxf(l1, l2));
        float e0 = __expf(l0 - mm), e1 = __expf(l1 - mm), e2 = __expf(l2 - mm);
        float ss = e0 + e1 + e2;
        alphas[b * 3 + 0] = e0 / ss;
        alphas[b * 3 + 1] = e1 / ss;
        alphas[b * 3 + 2] = e2 / ss;
    }
}

// ---------------------------------------------------------------------------
// MFMA bf16 GEMM: C[4096x768] = X[4096x768] @ W[768x768] + bias
// 64x64 tile/block, 4 waves, 16x16x32 MFMA. XOR-swizzled LDS (k-chunk ^ row).
// mode 0: write fp32 scattered to [B,H,N,dk] head layout (for q/k/v proj)
// mode 1: write output (bf16 or fp32 per dtX-class flag)
// xsel/wsel: index into flags for X/W dtype; <0 forces bf16.
// ---------------------------------------------------------------------------
__global__ __launch_bounds__(256) void gemm_kernel(
        const void* __restrict__ X,
        const void* __restrict__ W,
        const void* __restrict__ bias,
        const int* __restrict__ flags, int xsel, int wsel,
        void* __restrict__ dst, int mode)
{
    __shared__ unsigned short At[64 * 32];
    __shared__ unsigned short Bt[64 * 32];
    const int t = threadIdx.x;
    const int w = t >> 6, lane = t & 63, q = lane >> 4, lm = lane & 15;
    const int row0 = blockIdx.y << 6, col0 = blockIdx.x << 6;
    const int ar = t >> 2, ac = (t & 3) << 3;   // A staging: row, k-chunk base
    const int bk = t >> 3, bc = t & 7;          // B staging: k row, n-chunk
    const int aswz = ((ar >> 3) & 3) << 3;
    const int bswz = (bc & 3) << 3;
    const int am = (w << 4) + lm;
    const int acs = ((am >> 3) & 3) << 3;
    const int dtX = (xsel >= 0) ? flags[xsel] : 0;
    const int dtW = flags[wsel];
    const int dtOut = flags[1];   // output dtype follows activation class

    f32x4 acc[4];
    #pragma unroll
    for (int i = 0; i < 4; i++) acc[i] = (f32x4){0.f, 0.f, 0.f, 0.f};

    for (int k0 = 0; k0 < 768; k0 += 32) {
        uint4 av = load8bf(X, (row0 + ar) * 768 + k0 + ac, dtX);
        uint4 wv = load8bf(W, (k0 + bk) * 768 + col0 + (bc << 3), dtW);
        __syncthreads();
        *(uint4*)(&At[ar * 32 + (ac ^ aswz)]) = av;
        {
            unsigned short* bp = &Bt[(bc << 3) * 32 + (bk ^ bswz)];
            unsigned int uu[4] = {wv.x, wv.y, wv.z, wv.w};
            #pragma unroll
            for (int j = 0; j < 4; j++) {
                bp[(2 * j) * 32] = (unsigned short)(uu[j] & 0xFFFF);
                bp[(2 * j + 1) * 32] = (unsigned short)(uu[j] >> 16);
            }
        }
        __syncthreads();
        bf16x8 afr = *(const bf16x8*)(&At[am * 32 + ((q << 3) ^ acs)]);
        #pragma unroll
        for (int t4 = 0; t4 < 4; t4++) {
            int bn = (t4 << 4) + lm;
            bf16x8 bfr = *(const bf16x8*)(&Bt[bn * 32 + ((q << 3) ^ (((bn >> 3) & 3) << 3))]);
            acc[t4] = __builtin_amdgcn_mfma_f32_16x16x32_bf16(afr, bfr, acc[t4], 0, 0, 0);
        }
    }

    #pragma unroll
    for (int t4 = 0; t4 < 4; t4++) {
        int col = col0 + (t4 << 4) + lm;
        float bsv = loadF(bias, col, dtW);
        #pragma unroll
        for (int rg = 0; rg < 4; rg++) {
            int row = row0 + (w << 4) + (q << 2) + rg;
            float vo = acc[t4][rg] + bsv;
            if (mode == 0) {
                int b = row >> 9, n = row & 511, h = col >> 6, d = col & 63;
                ((float*)dst)[((((b * 12 + h) << 9) + n) << 6) + d] = vo;
            } else {
                if (dtOut) ((float*)dst)[row * 768 + col] = vo;
                else ((unsigned short*)dst)[row * 768 + col] = f2b(vo);
            }
        }
    }
}

// ---------------------------------------------------------------------------
// Fused attention: per (b, h, 16 q-rows): scores (fp32) -> 3-order masked
// softmax combined with alphas -> PV. qh/kh/vh are fp32 [B,H,N,64] in ws.
// 256 threads: thread = (r = t>>4, s = t&15).
// ---------------------------------------------------------------------------
__global__ __launch_bounds__(256) void attn_kernel(
        const float* __restrict__ qh, const float* __restrict__ kh,
        const float* __restrict__ vh, const void* __restrict__ masksp,
        const float* __restrict__ alphas, const int* __restrict__ flags,
        unsigned short* __restrict__ atted)
{
    __shared__ float S[16 * 520];   // scores then combined weights, stride 520
    __shared__ float KV[64 * 64];   // K/V chunk, float4-chunk XOR swizzle
    const int t = threadIdx.x;
    const int r = t >> 4, s = t & 15;
    const int b = blockIdx.z, h = blockIdx.y, n0 = blockIdx.x << 4;
    const int n = n0 + r;
    const int bh = b * 12 + h;

    // q row -> registers (fp32, 64)
    const float* qrow = qh + (((bh << 9) + n) << 6);
    float qreg[64];
    #pragma unroll
    for (int i = 0; i < 16; i++) {
        float4 v4 = ((const float4*)qrow)[i];
        qreg[4 * i + 0] = v4.x; qreg[4 * i + 1] = v4.y;
        qreg[4 * i + 2] = v4.z; qreg[4 * i + 3] = v4.w;
    }

    const int sm = t >> 2, sc0 = t & 3;  // staging: row, chunk base
    // ---- phase 1: scores ----
    const float* Kb = kh + ((bh << 9) << 6);
    for (int cm = 0; cm < 512; cm += 64) {
        __syncthreads();
        const float* krow = Kb + ((cm + sm) << 6);
        int pm = (sm + (sm >> 2)) & 15;
        #pragma unroll
        for (int i = 0; i < 4; i++) {
            int cj = sc0 + (i << 2);
            ((float4*)KV)[sm * 16 + (cj ^ pm)] = ((const float4*)krow)[cj];
        }
        __syncthreads();
        #pragma unroll
        for (int mi = 0; mi < 4; mi++) {
            int ml = (s << 2) + mi;
            int pmm = (ml + (ml >> 2)) & 15;
            float a = 0.f;
            #pragma unroll
            for (int dc = 0; dc < 16; dc++) {
                float4 kk = ((const float4*)KV)[ml * 16 + (dc ^ pmm)];
                a += qreg[4 * dc + 0] * kk.x + qreg[4 * dc + 1] * kk.y
                   + qreg[4 * dc + 2] * kk.z + qreg[4 * dc + 3] * kk.w;
            }
            S[r * 520 + cm + ml] = a * 0.125f;
        }
    }
    __syncthreads();

    // ---- phase 2: 3-order masked softmax, combined by alphas ----
    float sv[32];
    #pragma unroll
    for (int j = 0; j < 32; j++) sv[j] = S[r * 520 + (s << 5) + j];

    const int mode = flags[0];
    unsigned int mb[3];
    for (int l = 0; l < 3; l++) {
        int e0 = (((l * 8 + b) << 9) + n) * 512 + (s << 5);
        unsigned int bits = 0;
        if (mode == 0) {
            const uint4* p = (const uint4*)((const unsigned int*)masksp + e0);
            #pragma unroll
            for (int c = 0; c < 8; c++) {
                uint4 u = p[c];
                if (u.x) bits |= 1u << (c * 4 + 0);
                if (u.y) bits |= 1u << (c * 4 + 1);
                if (u.z) bits |= 1u << (c * 4 + 2);
                if (u.w) bits |= 1u << (c * 4 + 3);
            }
        } else if (mode == 1) {
            const uint4* p = (const uint4*)((const unsigned char*)masksp + e0);
            #pragma unroll
            for (int c = 0; c < 2; c++) {
                uint4 u = p[c];
                unsigned int uu[4] = {u.x, u.y, u.z, u.w};
                #pragma unroll
                for (int k2 = 0; k2 < 4; k2++)
                    #pragma unroll
                    for (int bb = 0; bb < 4; bb++)
                        if ((uu[k2] >> (bb * 8)) & 0xFFu)
                            bits |= 1u << (c * 16 + k2 * 4 + bb);
            }
        } else if (mode == 2) {
            const uint4* p = (const uint4*)((const float*)masksp + e0);
            #pragma unroll
            for (int c = 0; c < 8; c++) {
                uint4 u = p[c];
                if (u.x) bits |= 1u << (c * 4 + 0);
                if (u.y) bits |= 1u << (c * 4 + 1);
                if (u.z) bits |= 1u << (c * 4 + 2);
                if (u.w) bits |= 1u << (c * 4 + 3);
            }
        } else {
            const uint4* p = (const uint4*)((const unsigned short*)masksp + e0);
            #pragma unroll
            for (int c = 0; c < 4; c++) {
                uint4 u = p[c];
                unsigned int uu[4] = {u.x, u.y, u.z, u.w};
                #pragma unroll
                for (int k2 = 0; k2 < 4; k2++) {
                    if (uu[k2] & 0xFFFFu)  bits |= 1u << (c * 8 + k2 * 2 + 0);
                    if (uu[k2] >> 16)      bits |= 1u << (c * 8 + k2 * 2 + 1);
                }
            }
        }
        mb[l] = bits;
    }

    float M[3], coef[3];
    #pragma unroll
    for (int l = 0; l < 3; l++) {
        float mx = NEGV;
        #pragma unroll
        for (int j = 0; j < 32; j++) {
            float vv = ((mb[l] >> j) & 1) ? NEGV : sv[j];
            mx = fmaxf(mx, vv);
        }
        #pragma unroll
        for (int off = 1; off < 16; off <<= 1) mx = fmaxf(mx, __shfl_xor(mx, off));
        M[l] = mx;
    }
    #pragma unroll
    for (int l = 0; l < 3; l++) {
        float sm2 = 0.f;
        #pragma unroll
        for (int j = 0; j < 32; j++) {
            float vv = ((mb[l] >> j) & 1) ? NEGV : sv[j];
            sm2 += __expf(vv - M[l]);
        }
        #pragma unroll
        for (int off = 1; off < 16; off <<= 1) sm2 += __shfl_xor(sm2, off);
        coef[l] = alphas[b * 3 + l] / sm2;
    }
    #pragma unroll
    for (int j = 0; j < 32; j++) {
        float p = 0.f;
        #pragma unroll
        for (int l = 0; l < 3; l++) {
            float vv = ((mb[l] >> j) & 1) ? NEGV : sv[j];
            p += coef[l] * __expf(vv - M[l]);
        }
        S[r * 520 + (s << 5) + j] = p;
    }
    __syncthreads();

    // ---- phase 3: O = P @ V ----
    const float* Vb = vh + ((bh << 9) << 6);
    float O0 = 0.f, O1 = 0.f, O2 = 0.f, O3 = 0.f;
    for (int cm = 0; cm < 512; cm += 64) {
        __syncthreads();
        const float* vrow = Vb + ((cm + sm) << 6);
        int pm = (sm + (sm >> 2)) & 15;
        #pragma unroll
        for (int i = 0; i < 4; i++) {
            int cj = sc0 + (i << 2);
            ((float4*)KV)[sm * 16 + (cj ^ pm)] = ((const float4*)vrow)[cj];
        }
        __syncthreads();
        for (int m = 0; m < 64; m++) {
            float wv = S[r * 520 + cm + m];
            int pmm = (m + (m >> 2)) & 15;
            float4 vv = ((const float4*)KV)[m * 16 + (s ^ pmm)];
            O0 += wv * vv.x; O1 += wv * vv.y; O2 += wv * vv.z; O3 += wv * vv.w;
        }
    }

    unsigned int lo = (unsigned int)f2b(O0) | ((unsigned int)f2b(O1) << 16);
    unsigned int hi = (unsigned int)f2b(O2) | ((unsigned int)f2b(O3) << 16);
    uint2 val; val.x = lo; val.y = hi;
    *(uint2*)(&atted[(((b << 9) + n) * 768) + (h << 6) + (s << 2)]) = val;
}

// ---------------------------------------------------------------------------
extern "C" void kernel_launch(void* const* d_in, const int* in_sizes, int n_in,
                              void* d_out, int out_size, void* d_ws, size_t ws_size,
                              hipStream_t stream)
{
    const void* v  = d_in[0];
    const void* k  = d_in[1];
    const void* q  = d_in[2];
    const void* mk = d_in[3];
    const void* Wv = d_in[6];
    const void* bv = d_in[7];
    const void* Wk = d_in[8];
    const void* bk = d_in[9];
    const void* Wq = d_in[10];
    const void* bq = d_in[11];
    const void* Wm = d_in[12];
    const void* bm = d_in[13];
    const void* pool_w = d_in[14];
    const void* pool_b = d_in[15];
    const void* w1 = d_in[16];
    const void* w2 = d_in[17];
    const void* b2 = d_in[18];

    char* ws = (char*)d_ws;
    int*   flags  = (int*)ws;                         // 12 B
    float* alphas = (float*)(ws + 256);               // 96 B
    float* qh     = (float*)(ws + 512);               // 12.58 MB each
    float* kh     = (float*)(ws + 512 + 12582912L);
    float* vh     = (float*)(ws + 512 + 2 * 12582912L);
    unsigned short* atted = (unsigned short*)(ws + 512 + 3 * 12582912L);

    sniff_kernel<<<dim3(1), dim3(256), 0, stream>>>(
        (const unsigned int*)mk, (const unsigned int*)v, (const unsigned int*)Wv, flags);
    routing_kernel<<<dim3(8), dim3(512), 0, stream>>>(v, pool_w, pool_b, w1, w2, b2, flags, alphas);
    gemm_kernel<<<dim3(12, 64), dim3(256), 0, stream>>>(v, Wv, bv, flags, 1, 2, (void*)vh, 0);
    gemm_kernel<<<dim3(12, 64), dim3(256), 0, stream>>>(k, Wk, bk, flags, 1, 2, (void*)kh, 0);
    gemm_kernel<<<dim3(12, 64), dim3(256), 0, stream>>>(q, Wq, bq, flags, 1, 2, (void*)qh, 0);
    attn_kernel<<<dim3(32, 12, 8), dim3(256), 0, stream>>>(qh, kh, vh, mk, alphas, flags, atted);
    gemm_kernel<<<dim3(12, 64), dim3(256), 0, stream>>>(atted, Wm, bm, flags, -1, 2, d_out, 1);
}

// Round 3
// 605.318 us; speedup vs baseline: 1.9090x; 1.9090x over previous
//
#include <hip/hip_runtime.h>
#include <hip/hip_bf16.h>
#include <stdint.h>

// ---------------------------------------------------------------------------
// SARoutingBlock: alphas = soft_routing(v); qkv projections; 3-order masked
// softmax attention combined by alphas; output projection.
// B=8, N=512, HID=768, HEADS=12, dk=64, ORDERS=3.
// Round 3: MFMA attention (scores in-register, 1 exp/elem, bit-packed masks),
// bf16 intermediates, LDS-staged coalesced GEMM epilogues, parallel routing.
// ---------------------------------------------------------------------------

typedef __bf16 bf16x8 __attribute__((ext_vector_type(8)));
typedef float f32x4 __attribute__((ext_vector_type(4)));

#define NEGV -1e9f

__device__ __forceinline__ float b2f(unsigned short h) {
    union { unsigned int u; float f; } x; x.u = ((unsigned int)h) << 16; return x.f;
}
__device__ __forceinline__ unsigned short f2b(float f) {
    union { float f; unsigned int u; } x; x.f = f;
    unsigned int u = x.u + 0x7FFFu + ((x.u >> 16) & 1u);
    return (unsigned short)(u >> 16);
}
__device__ __forceinline__ unsigned int packbf(unsigned int u0, unsigned int u1) {
    unsigned int r0 = (u0 + 0x7FFFu + ((u0 >> 16) & 1u)) >> 16;
    unsigned int r1 = (u1 + 0x7FFFu + ((u1 >> 16) & 1u)) & 0xFFFF0000u;
    return r0 | r1;
}
__device__ __forceinline__ uint4 load8bf(const void* base, size_t elemOff, int isF32) {
    if (!isF32) return *(const uint4*)((const unsigned short*)base + elemOff);
    const uint4* f = (const uint4*)((const float*)base + elemOff);
    uint4 a = f[0], b = f[1];
    uint4 r;
    r.x = packbf(a.x, a.y);
    r.y = packbf(a.z, a.w);
    r.z = packbf(b.x, b.y);
    r.w = packbf(b.z, b.w);
    return r;
}
__device__ __forceinline__ float loadF(const void* p, int idx, int isF32) {
    return isF32 ? ((const float*)p)[idx] : b2f(((const unsigned short*)p)[idx]);
}

// ---------------------------------------------------------------------------
// Sniffer: flags[0]=mask mode (0=i32,1=u8,2=f32,3=bf16); flags[1]=v/k/q dtype
// (0=bf16,1=f32); flags[2]=weights dtype.
// ---------------------------------------------------------------------------
__global__ void sniff_kernel(const unsigned int* __restrict__ mp,
                             const unsigned int* __restrict__ vp,
                             const unsigned int* __restrict__ wp,
                             int* __restrict__ flags)
{
    __shared__ int oki, oku, okf, badv, badw;
    if (threadIdx.x == 0) { oki = 1; oku = 1; okf = 1; badv = 0; badw = 0; }
    __syncthreads();
    int li = 1, lu = 1, lf = 1, bv = 0, bw = 0;
    for (int i = threadIdx.x; i < 16384; i += 256) {
        unsigned int w = mp[i];
        if (w > 1u) li = 0;
        if (w & 0xFEFEFEFEu) lu = 0;
        if (w != 0u && w != 0x3F800000u) lf = 0;
    }
    for (int i = threadIdx.x; i < 8192; i += 256) {
        unsigned int w = vp[i];
        float f0 = b2f((unsigned short)(w & 0xFFFF));
        float f1 = b2f((unsigned short)(w >> 16));
        if (!(fabsf(f0) < 1e4f) || !(fabsf(f1) < 1e4f)) bv = 1;
        w = wp[i];
        f0 = b2f((unsigned short)(w & 0xFFFF));
        f1 = b2f((unsigned short)(w >> 16));
        if (!(fabsf(f0) < 1e4f) || !(fabsf(f1) < 1e4f)) bw = 1;
    }
    if (!li) atomicAnd(&oki, 0);
    if (!lu) atomicAnd(&oku, 0);
    if (!lf) atomicAnd(&okf, 0);
    if (bv) atomicOr(&badv, 1);
    if (bw) atomicOr(&badw, 1);
    __syncthreads();
    if (threadIdx.x == 0) {
        flags[0] = oki ? 0 : (oku ? 1 : (okf ? 2 : 3));
        flags[1] = badv;
        flags[2] = badw;
    }
}

// ---------------------------------------------------------------------------
// Mask bit-pack: output word pm[grow*16 + lm], grow = (l*8+b)*512 + n,
// bit g (0..31) = mask[l,b,n, g*16+lm]  (n-tile-major layout for MFMA lanes).
// One block packs 32 rows.
// ---------------------------------------------------------------------------
__global__ __launch_bounds__(256) void pack_kernel(
        const void* __restrict__ masks, const int* __restrict__ flags,
        unsigned int* __restrict__ pm)
{
    __shared__ unsigned char flg[32 * 512];
    const int t = threadIdx.x;
    const int mode = flags[0];
    const size_t e0 = (size_t)blockIdx.x * (32 * 512);
    if (mode == 0 || mode == 2) {
        const uint4* p = (const uint4*)((const unsigned int*)masks + e0);
        for (int i = t; i < 4096; i += 256) {
            uint4 u = p[i];
            int base = i << 2;
            flg[base + 0] = u.x ? 1 : 0;
            flg[base + 1] = u.y ? 1 : 0;
            flg[base + 2] = u.z ? 1 : 0;
            flg[base + 3] = u.w ? 1 : 0;
        }
    } else if (mode == 1) {
        const uint4* p = (const uint4*)((const unsigned char*)masks + e0);
        for (int i = t; i < 1024; i += 256) {
            uint4 u = p[i];
            unsigned int uu[4] = {u.x, u.y, u.z, u.w};
            int base = i << 4;
            #pragma unroll
            for (int k2 = 0; k2 < 4; k2++)
                #pragma unroll
                for (int bb = 0; bb < 4; bb++)
                    flg[base + k2 * 4 + bb] = ((uu[k2] >> (bb * 8)) & 0xFFu) ? 1 : 0;
        }
    } else {
        const uint4* p = (const uint4*)((const unsigned short*)masks + e0);
        for (int i = t; i < 2048; i += 256) {
            uint4 u = p[i];
            unsigned int uu[4] = {u.x, u.y, u.z, u.w};
            int base = i << 3;
            #pragma unroll
            for (int k2 = 0; k2 < 4; k2++) {
                flg[base + k2 * 2 + 0] = (uu[k2] & 0xFFFFu) ? 1 : 0;
                flg[base + k2 * 2 + 1] = (uu[k2] >> 16) ? 1 : 0;
            }
        }
    }
    __syncthreads();
    for (int widx = t; widx < 512; widx += 256) {
        int rl = widx >> 4, lm = widx & 15;
        unsigned int bits = 0;
        #pragma unroll
        for (int g = 0; g < 32; g++)
            bits |= ((unsigned int)(flg[rl * 512 + (g << 4) + lm] & 1)) << g;
        pm[(size_t)blockIdx.x * 512 + widx] = bits;
    }
}

// ---------------------------------------------------------------------------
// Routing stage 1: raw pooling scores per row (64 rows/block, 4 thr/row).
// ---------------------------------------------------------------------------
__global__ __launch_bounds__(256) void route_score_kernel(
        const void* __restrict__ v, const void* __restrict__ pool_w,
        const void* __restrict__ pool_b, const int* __restrict__ flags,
        float* __restrict__ scores)
{
    __shared__ float pw[768];
    const int t = threadIdx.x;
    const int b = blockIdx.x >> 3, ch = blockIdx.x & 7;
    const int dtV = flags[1], dtW = flags[2];
    for (int d = t; d < 768; d += 256) pw[d] = loadF(pool_w, d, dtW);
    __syncthreads();
    const int r = t >> 2, c4 = t & 3;
    const int n = (ch << 6) + r;
    float dot = 0.f, asum = 0.f;
    if (!dtV) {
        const unsigned int* vr = (const unsigned int*)v + ((size_t)(b * 512 + n)) * 384;
        for (int j = 0; j < 96; j++) {
            int p = c4 + (j << 2);
            unsigned int u = vr[p];
            float f0 = b2f((unsigned short)(u & 0xFFFF));
            float f1 = b2f((unsigned short)(u >> 16));
            asum += fabsf(f0) + fabsf(f1);
            dot += f0 * pw[2 * p] + f1 * pw[2 * p + 1];
        }
    } else {
        const float* vf = (const float*)v + ((size_t)(b * 512 + n)) * 768;
        for (int e = c4; e < 768; e += 4) {
            float f = vf[e];
            asum += fabsf(f);
            dot += f * pw[e];
        }
    }
    dot += __shfl_xor(dot, 1); dot += __shfl_xor(dot, 2);
    asum += __shfl_xor(asum, 1); asum += __shfl_xor(asum, 2);
    if (c4 == 0)
        scores[b * 512 + n] = (asum == 0.f) ? NEGV : dot + loadF(pool_b, 0, dtW);
}

// ---------------------------------------------------------------------------
// Routing stage 2: softmax over rows, pooled, MLP, alphas. One block per b.
// ---------------------------------------------------------------------------
__global__ __launch_bounds__(512) void route_rest_kernel(
        const void* __restrict__ v, const void* __restrict__ w1,
        const void* __restrict__ w2, const void* __restrict__ b2,
        const int* __restrict__ flags, const float* __restrict__ scores,
        float* __restrict__ alphas)
{
    __shared__ float scs[512];
    __shared__ float pool[768];
    __shared__ float hid[384];
    __shared__ float red[16];
    const int t = threadIdx.x;
    const int b = blockIdx.x;
    const int dtV = flags[1], dtW = flags[2];

    float scv = scores[b * 512 + t];
    float mx = scv;
    #pragma unroll
    for (int off = 1; off < 64; off <<= 1) mx = fmaxf(mx, __shfl_xor(mx, off));
    if ((t & 63) == 0) red[t >> 6] = mx;
    __syncthreads();
    float M = red[0];
    #pragma unroll
    for (int i = 1; i < 8; i++) M = fmaxf(M, red[i]);
    float e = __expf(scv - M);
    __syncthreads();
    float sm = e;
    #pragma unroll
    for (int off = 1; off < 64; off <<= 1) sm += __shfl_xor(sm, off);
    if ((t & 63) == 0) red[t >> 6] = sm;
    __syncthreads();
    float SS = 0.f;
    #pragma unroll
    for (int i = 0; i < 8; i++) SS += red[i];
    scs[t] = e / SS;
    __syncthreads();

    // pooled: coalesced over d, loop over n
    float a0 = 0.f, a1 = 0.f;
    if (!dtV) {
        const unsigned short* vb = (const unsigned short*)v + (size_t)b * 512 * 768;
        #pragma unroll 4
        for (int n = 0; n < 512; n++) {
            float p = scs[n];
            const unsigned short* vr = vb + (size_t)n * 768;
            a0 += b2f(vr[t]) * p;
            if (t < 256) a1 += b2f(vr[512 + t]) * p;
        }
    } else {
        const float* vb = (const float*)v + (size_t)b * 512 * 768;
        #pragma unroll 4
        for (int n = 0; n < 512; n++) {
            float p = scs[n];
            const float* vr = vb + (size_t)n * 768;
            a0 += vr[t] * p;
            if (t < 256) a1 += vr[512 + t] * p;
        }
    }
    pool[t] = a0;
    if (t < 256) pool[512 + t] = a1;
    __syncthreads();

    if (t < 384) {
        float a = 0.f;
        for (int d = 0; d < 768; d++) a += pool[d] * loadF(w1, d * 384 + t, dtW);
        hid[t] = fmaxf(a, 0.f);
    }
    __syncthreads();
    if (t < 3) {
        float a = loadF(b2, t, dtW);
        for (int j = 0; j < 384; j++) a += hid[j] * loadF(w2, j * 3 + t, dtW);
        red[8 + t] = a;
    }
    __syncthreads();
    if (t == 0) {
        float l0 = red[8], l1 = red[9], l2 = red[10];
        float mm = fmaxf(l0, fmaxf(l1, l2));
        float e0 = __expf(l0 - mm), e1 = __expf(l1 - mm), e2 = __expf(l2 - mm);
        float ss = e0 + e1 + e2;
        alphas[b * 3 + 0] = e0 / ss;
        alphas[b * 3 + 1] = e1 / ss;
        alphas[b * 3 + 2] = e2 / ss;
    }
}

// ---------------------------------------------------------------------------
// MFMA bf16 GEMM: C[4096x768] = X @ W + bias, 64x64 tile, 4 waves.
// Epilogue staged via LDS for coalesced bf16 stores.
// mode 0: dst[b][h][n][64] bf16 (head-split natural, for q/k)
// mode 1: dst[row][col]    bf16 (or f32 if dtOut) — final output
// mode 2: dst[b][h][64][n] bf16 (head-split transposed, for v)
// ---------------------------------------------------------------------------
__global__ __launch_bounds__(256) void gemm_kernel(
        const void* __restrict__ X,
        const void* __restrict__ W,
        const void* __restrict__ bias,
        const int* __restrict__ flags, int xsel, int wsel,
        void* __restrict__ dst, int mode)
{
    __shared__ unsigned short smem[64 * 72];   // 9216 B: At(2048)+Bt(2048) then tile
    unsigned short* At = smem;
    unsigned short* Bt = smem + 2048;
    const int t = threadIdx.x;
    const int w = t >> 6, lane = t & 63, q = lane >> 4, lm = lane & 15;
    const int row0 = blockIdx.y << 6, col0 = blockIdx.x << 6;
    const int ar = t >> 2, ac = (t & 3) << 3;
    const int bk = t >> 3, bc = t & 7;
    const int aswz = ((ar >> 3) & 3) << 3;
    const int bswz = (bc & 3) << 3;
    const int am = (w << 4) + lm;
    const int acs = ((am >> 3) & 3) << 3;
    const int dtX = (xsel >= 0) ? flags[xsel] : 0;
    const int dtW = flags[wsel];
    const int dtOut = flags[1];

    f32x4 acc[4];
    #pragma unroll
    for (int i = 0; i < 4; i++) acc[i] = (f32x4){0.f, 0.f, 0.f, 0.f};

    for (int k0 = 0; k0 < 768; k0 += 32) {
        uint4 av = load8bf(X, (size_t)(row0 + ar) * 768 + k0 + ac, dtX);
        uint4 wv = load8bf(W, (size_t)(k0 + bk) * 768 + col0 + (bc << 3), dtW);
        __syncthreads();
        *(uint4*)(&At[ar * 32 + (ac ^ aswz)]) = av;
        {
            unsigned short* bp = &Bt[(bc << 3) * 32 + (bk ^ bswz)];
            unsigned int uu[4] = {wv.x, wv.y, wv.z, wv.w};
            #pragma unroll
            for (int j = 0; j < 4; j++) {
                bp[(2 * j) * 32] = (unsigned short)(uu[j] & 0xFFFF);
                bp[(2 * j + 1) * 32] = (unsigned short)(uu[j] >> 16);
            }
        }
        __syncthreads();
        bf16x8 afr = *(const bf16x8*)(&At[am * 32 + ((q << 3) ^ acs)]);
        #pragma unroll
        for (int t4 = 0; t4 < 4; t4++) {
            int bn = (t4 << 4) + lm;
            bf16x8 bfr = *(const bf16x8*)(&Bt[bn * 32 + ((q << 3) ^ (((bn >> 3) & 3) << 3))]);
            acc[t4] = __builtin_amdgcn_mfma_f32_16x16x32_bf16(afr, bfr, acc[t4], 0, 0, 0);
        }
    }

    // fp32 full-width fallback (never expected; measured dtOut==0)
    if (mode == 1 && dtOut) {
        #pragma unroll
        for (int t4 = 0; t4 < 4; t4++) {
            int col = col0 + (t4 << 4) + lm;
            float bsv = loadF(bias, col, dtW);
            #pragma unroll
            for (int rg = 0; rg < 4; rg++) {
                int row = row0 + (w << 4) + (q << 2) + rg;
                ((float*)dst)[(size_t)row * 768 + col] = acc[t4][rg] + bsv;
            }
        }
        return;
    }

    __syncthreads();   // all LDS frag reads done; reuse smem as output tile
    #pragma unroll
    for (int t4 = 0; t4 < 4; t4++) {
        int colL = (t4 << 4) + lm;
        float bsv = loadF(bias, col0 + colL, dtW);
        #pragma unroll
        for (int rg = 0; rg < 4; rg++) {
            int rowL = (w << 4) + (q << 2) + rg;
            unsigned short hv = f2b(acc[t4][rg] + bsv);
            if (mode == 2) smem[colL * 72 + rowL] = hv;
            else           smem[rowL * 72 + colL] = hv;
        }
    }
    __syncthreads();
    const int g = t >> 2, c0 = (t & 3) << 4;
    uint4 w0 = *(const uint4*)&smem[g * 72 + c0];
    uint4 w1 = *(const uint4*)&smem[g * 72 + c0 + 8];
    unsigned short* o;
    if (mode == 0) {
        int b = row0 >> 9, n0b = row0 & 511, h = col0 >> 6;
        o = (unsigned short*)dst + ((size_t)(b * 12 + h) * 512 + n0b + g) * 64 + c0;
    } else if (mode == 2) {
        int b = row0 >> 9, n0b = row0 & 511, h = col0 >> 6;
        o = (unsigned short*)dst + ((size_t)(b * 12 + h) * 64 + g) * 512 + n0b + c0;
    } else {
        o = (unsigned short*)dst + (size_t)(row0 + g) * 768 + col0 + c0;
    }
    *(uint4*)o = w0;
    *(uint4*)(o + 8) = w1;
}

// ---------------------------------------------------------------------------
// MFMA attention. Block = 16 Q rows of one (b,h). 4 waves.
// Phase 1: S frags in registers (wave w owns keys w*128..+128).
// Phase 2: E=exp(s/8) in-register; per-order masked Z via shfl + tiny LDS;
//          P = sum_l alpha_l*E/Z_l -> bf16 -> XOR-swizzled LDS (A-layout).
// Phase 3: O = P @ V via MFMA, B frags from transposed V (global/L2).
// ---------------------------------------------------------------------------
__global__ __launch_bounds__(256) void attn_kernel(
        const unsigned short* __restrict__ qh, const unsigned short* __restrict__ kh,
        const unsigned short* __restrict__ vT, const unsigned int* __restrict__ pm,
        const float* __restrict__ alphas, unsigned short* __restrict__ atted)
{
    __shared__ unsigned short P[16 * 512];   // 16 KB, chunk-XOR swizzle
    __shared__ float Zp[4][16][3];
    __shared__ unsigned short Ost[16 * 72];
    const int t = threadIdx.x;
    const int w = t >> 6, lane = t & 63, quad = lane >> 4, lm = lane & 15;
    const int qb = blockIdx.x, h = blockIdx.y, b = blockIdx.z;
    const int n0 = qb << 4, bh = b * 12 + h;

    // ---- phase 1: S = Q K^T (raw, scale folded into exp) ----
    const unsigned short* qrow = qh + ((size_t)(bh * 512 + n0 + lm)) * 64 + (quad << 3);
    bf16x8 qa0 = *(const bf16x8*)qrow;
    bf16x8 qa1 = *(const bf16x8*)(qrow + 32);
    f32x4 acc[8];
    #pragma unroll
    for (int i = 0; i < 8; i++) acc[i] = (f32x4){0.f, 0.f, 0.f, 0.f};
    const unsigned short* kb0 = kh + ((size_t)(bh * 512 + (w << 7) + lm)) * 64 + (quad << 3);
    #pragma unroll
    for (int nt = 0; nt < 8; nt++) {
        const unsigned short* kr = kb0 + nt * (16 * 64);
        bf16x8 k0 = *(const bf16x8*)kr;
        bf16x8 k1 = *(const bf16x8*)(kr + 32);
        acc[nt] = __builtin_amdgcn_mfma_f32_16x16x32_bf16(qa0, k0, acc[nt], 0, 0, 0);
        acc[nt] = __builtin_amdgcn_mfma_f32_16x16x32_bf16(qa1, k1, acc[nt], 0, 0, 0);
    }

    // ---- phase 2 ----
    float al[3];
    #pragma unroll
    for (int l = 0; l < 3; l++) al[l] = alphas[b * 3 + l];

    #pragma unroll
    for (int nt = 0; nt < 8; nt++)
        #pragma unroll
        for (int rg = 0; rg < 4; rg++)
            acc[nt][rg] = __expf(acc[nt][rg] * 0.125f);

    unsigned int mk[4][3];
    #pragma unroll
    for (int rg = 0; rg < 4; rg++)
        #pragma unroll
        for (int l = 0; l < 3; l++)
            mk[rg][l] = pm[((size_t)((l << 3) + b) * 512 + n0 + (quad << 2) + rg) * 16 + lm];

    #pragma unroll
    for (int rg = 0; rg < 4; rg++) {
        float z0 = 0.f, z1 = 0.f, z2 = 0.f;
        #pragma unroll
        for (int nt = 0; nt < 8; nt++) {
            int g = (w << 3) + nt;
            float e = acc[nt][rg];
            if (!((mk[rg][0] >> g) & 1)) z0 += e;
            if (!((mk[rg][1] >> g) & 1)) z1 += e;
            if (!((mk[rg][2] >> g) & 1)) z2 += e;
        }
        #pragma unroll
        for (int off = 1; off < 16; off <<= 1) {
            z0 += __shfl_xor(z0, off);
            z1 += __shfl_xor(z1, off);
            z2 += __shfl_xor(z2, off);
        }
        if (lm == 0) {
            int row = (quad << 2) + rg;
            Zp[w][row][0] = z0; Zp[w][row][1] = z1; Zp[w][row][2] = z2;
        }
    }
    __syncthreads();

    #pragma unroll
    for (int rg = 0; rg < 4; rg++) {
        int row = (quad << 2) + rg;
        float coef[3]; float addu = 0.f;
        #pragma unroll
        for (int l = 0; l < 3; l++) {
            float Z = Zp[0][row][l] + Zp[1][row][l] + Zp[2][row][l] + Zp[3][row][l];
            if (Z > 0.f) coef[l] = al[l] / Z;
            else { coef[l] = 0.f; addu += al[l] * (1.0f / 512.0f); }
        }
        #pragma unroll
        for (int nt = 0; nt < 8; nt++) {
            int g = (w << 3) + nt;
            float p = addu;
            float e = acc[nt][rg];
            if (!((mk[rg][0] >> g) & 1)) p += coef[0] * e;
            if (!((mk[rg][1] >> g) & 1)) p += coef[1] * e;
            if (!((mk[rg][2] >> g) & 1)) p += coef[2] * e;
            int c = (g << 4) + lm;
            int chunk = c >> 3, j = c & 7;
            P[row * 512 + (((chunk ^ (row & 7))) << 3) + j] = f2b(p);
        }
    }
    __syncthreads();

    // ---- phase 3: O = P @ V ; wave w -> output dims w*16..+16 ----
    f32x4 accO = (f32x4){0.f, 0.f, 0.f, 0.f};
    const unsigned short* vb = vT + ((size_t)(bh * 64 + (w << 4) + lm)) * 512 + (quad << 3);
    #pragma unroll
    for (int ks = 0; ks < 16; ks++) {
        bf16x8 pa = *(const bf16x8*)&P[lm * 512 + ((((ks << 2) + quad) ^ (lm & 7)) << 3)];
        bf16x8 vf = *(const bf16x8*)(vb + (ks << 5));
        accO = __builtin_amdgcn_mfma_f32_16x16x32_bf16(pa, vf, accO, 0, 0, 0);
    }
    #pragma unroll
    for (int rg = 0; rg < 4; rg++)
        Ost[((quad << 2) + rg) * 72 + (w << 4) + lm] = f2b(accO[rg]);
    __syncthreads();
    const int r2 = t >> 4, c4 = t & 15;
    uint2 val = *(const uint2*)&Ost[r2 * 72 + (c4 << 2)];
    *(uint2*)&atted[((size_t)(b * 512 + n0 + r2)) * 768 + (h << 6) + (c4 << 2)] = val;
}

// ---------------------------------------------------------------------------
extern "C" void kernel_launch(void* const* d_in, const int* in_sizes, int n_in,
                              void* d_out, int out_size, void* d_ws, size_t ws_size,
                              hipStream_t stream)
{
    const void* v  = d_in[0];
    const void* k  = d_in[1];
    const void* q  = d_in[2];
    const void* mk = d_in[3];
    const void* Wv = d_in[6];
    const void* bv = d_in[7];
    const void* Wk = d_in[8];
    const void* bk = d_in[9];
    const void* Wq = d_in[10];
    const void* bq = d_in[11];
    const void* Wm = d_in[12];
    const void* bm = d_in[13];
    const void* pool_w = d_in[14];
    const void* pool_b = d_in[15];
    const void* w1 = d_in[16];
    const void* w2 = d_in[17];
    const void* b2 = d_in[18];

    char* ws = (char*)d_ws;
    int*   flags  = (int*)ws;                                   // 64 B
    float* alphas = (float*)(ws + 256);                         // 96 B
    float* scores = (float*)(ws + 512);                         // 16 KB
    unsigned int* pm = (unsigned int*)(ws + 32768);             // 786 KB
    unsigned short* qh    = (unsigned short*)(ws + 1048576);    // 6.29 MB each
    unsigned short* kh    = (unsigned short*)(ws + 1048576 + 6291456L);
    unsigned short* vT    = (unsigned short*)(ws + 1048576 + 2 * 6291456L);
    unsigned short* atted = (unsigned short*)(ws + 1048576 + 3 * 6291456L);

    sniff_kernel<<<dim3(1), dim3(256), 0, stream>>>(
        (const unsigned int*)mk, (const unsigned int*)v, (const unsigned int*)Wv, flags);
    pack_kernel<<<dim3(384), dim3(256), 0, stream>>>(mk, flags, pm);
    route_score_kernel<<<dim3(64), dim3(256), 0, stream>>>(v, pool_w, pool_b, flags, scores);
    route_rest_kernel<<<dim3(8), dim3(512), 0, stream>>>(v, w1, w2, b2, flags, scores, alphas);
    gemm_kernel<<<dim3(12, 64), dim3(256), 0, stream>>>(v, Wv, bv, flags, 1, 2, (void*)vT, 2);
    gemm_kernel<<<dim3(12, 64), dim3(256), 0, stream>>>(k, Wk, bk, flags, 1, 2, (void*)kh, 0);
    gemm_kernel<<<dim3(12, 64), dim3(256), 0, stream>>>(q, Wq, bq, flags, 1, 2, (void*)qh, 0);
    attn_kernel<<<dim3(32, 12, 8), dim3(256), 0, stream>>>(qh, kh, vT, pm, alphas, atted);
    gemm_kernel<<<dim3(12, 64), dim3(256), 0, stream>>>(atted, Wm, bm, flags, -1, 2, d_out, 1);
}

// Round 4
// 441.444 us; speedup vs baseline: 2.6176x; 1.3712x over previous
//
#include <hip/hip_runtime.h>
#include <hip/hip_bf16.h>
#include <stdint.h>

// ---------------------------------------------------------------------------
// SARoutingBlock: alphas = soft_routing(v); qkv projections; 3-order masked
// softmax attention combined by alphas; output projection.
// B=8, N=512, HID=768, HEADS=12, dk=64, ORDERS=3.
// Round 4: routing parallelized (8-block latency-bound route_rest ->
// softmax/pool(64 blk)/mlp chain). Attention/GEMM unchanged from round 3.
// ---------------------------------------------------------------------------

typedef __bf16 bf16x8 __attribute__((ext_vector_type(8)));
typedef float f32x4 __attribute__((ext_vector_type(4)));

#define NEGV -1e9f

__device__ __forceinline__ float b2f(unsigned short h) {
    union { unsigned int u; float f; } x; x.u = ((unsigned int)h) << 16; return x.f;
}
__device__ __forceinline__ unsigned short f2b(float f) {
    union { float f; unsigned int u; } x; x.f = f;
    unsigned int u = x.u + 0x7FFFu + ((x.u >> 16) & 1u);
    return (unsigned short)(u >> 16);
}
__device__ __forceinline__ unsigned int packbf(unsigned int u0, unsigned int u1) {
    unsigned int r0 = (u0 + 0x7FFFu + ((u0 >> 16) & 1u)) >> 16;
    unsigned int r1 = (u1 + 0x7FFFu + ((u1 >> 16) & 1u)) & 0xFFFF0000u;
    return r0 | r1;
}
__device__ __forceinline__ uint4 load8bf(const void* base, size_t elemOff, int isF32) {
    if (!isF32) return *(const uint4*)((const unsigned short*)base + elemOff);
    const uint4* f = (const uint4*)((const float*)base + elemOff);
    uint4 a = f[0], b = f[1];
    uint4 r;
    r.x = packbf(a.x, a.y);
    r.y = packbf(a.z, a.w);
    r.z = packbf(b.x, b.y);
    r.w = packbf(b.z, b.w);
    return r;
}
__device__ __forceinline__ float loadF(const void* p, int idx, int isF32) {
    return isF32 ? ((const float*)p)[idx] : b2f(((const unsigned short*)p)[idx]);
}

// ---------------------------------------------------------------------------
// Sniffer: flags[0]=mask mode (0=i32,1=u8,2=f32,3=bf16); flags[1]=v/k/q dtype
// (0=bf16,1=f32); flags[2]=weights dtype.
// ---------------------------------------------------------------------------
__global__ void sniff_kernel(const unsigned int* __restrict__ mp,
                             const unsigned int* __restrict__ vp,
                             const unsigned int* __restrict__ wp,
                             int* __restrict__ flags)
{
    __shared__ int oki, oku, okf, badv, badw;
    if (threadIdx.x == 0) { oki = 1; oku = 1; okf = 1; badv = 0; badw = 0; }
    __syncthreads();
    int li = 1, lu = 1, lf = 1, bv = 0, bw = 0;
    for (int i = threadIdx.x; i < 16384; i += 256) {
        unsigned int w = mp[i];
        if (w > 1u) li = 0;
        if (w & 0xFEFEFEFEu) lu = 0;
        if (w != 0u && w != 0x3F800000u) lf = 0;
    }
    for (int i = threadIdx.x; i < 8192; i += 256) {
        unsigned int w = vp[i];
        float f0 = b2f((unsigned short)(w & 0xFFFF));
        float f1 = b2f((unsigned short)(w >> 16));
        if (!(fabsf(f0) < 1e4f) || !(fabsf(f1) < 1e4f)) bv = 1;
        w = wp[i];
        f0 = b2f((unsigned short)(w & 0xFFFF));
        f1 = b2f((unsigned short)(w >> 16));
        if (!(fabsf(f0) < 1e4f) || !(fabsf(f1) < 1e4f)) bw = 1;
    }
    if (!li) atomicAnd(&oki, 0);
    if (!lu) atomicAnd(&oku, 0);
    if (!lf) atomicAnd(&okf, 0);
    if (bv) atomicOr(&badv, 1);
    if (bw) atomicOr(&badw, 1);
    __syncthreads();
    if (threadIdx.x == 0) {
        flags[0] = oki ? 0 : (oku ? 1 : (okf ? 2 : 3));
        flags[1] = badv;
        flags[2] = badw;
    }
}

// ---------------------------------------------------------------------------
// Mask bit-pack: pm[grow*16 + lm], grow = (l*8+b)*512 + n,
// bit g = mask[l,b,n, g*16+lm]. One block packs 32 rows.
// ---------------------------------------------------------------------------
__global__ __launch_bounds__(256) void pack_kernel(
        const void* __restrict__ masks, const int* __restrict__ flags,
        unsigned int* __restrict__ pm)
{
    __shared__ unsigned char flg[32 * 512];
    const int t = threadIdx.x;
    const int mode = flags[0];
    const size_t e0 = (size_t)blockIdx.x * (32 * 512);
    if (mode == 0 || mode == 2) {
        const uint4* p = (const uint4*)((const unsigned int*)masks + e0);
        for (int i = t; i < 4096; i += 256) {
            uint4 u = p[i];
            int base = i << 2;
            flg[base + 0] = u.x ? 1 : 0;
            flg[base + 1] = u.y ? 1 : 0;
            flg[base + 2] = u.z ? 1 : 0;
            flg[base + 3] = u.w ? 1 : 0;
        }
    } else if (mode == 1) {
        const uint4* p = (const uint4*)((const unsigned char*)masks + e0);
        for (int i = t; i < 1024; i += 256) {
            uint4 u = p[i];
            unsigned int uu[4] = {u.x, u.y, u.z, u.w};
            int base = i << 4;
            #pragma unroll
            for (int k2 = 0; k2 < 4; k2++)
                #pragma unroll
                for (int bb = 0; bb < 4; bb++)
                    flg[base + k2 * 4 + bb] = ((uu[k2] >> (bb * 8)) & 0xFFu) ? 1 : 0;
        }
    } else {
        const uint4* p = (const uint4*)((const unsigned short*)masks + e0);
        for (int i = t; i < 2048; i += 256) {
            uint4 u = p[i];
            unsigned int uu[4] = {u.x, u.y, u.z, u.w};
            int base = i << 3;
            #pragma unroll
            for (int k2 = 0; k2 < 4; k2++) {
                flg[base + k2 * 2 + 0] = (uu[k2] & 0xFFFFu) ? 1 : 0;
                flg[base + k2 * 2 + 1] = (uu[k2] >> 16) ? 1 : 0;
            }
        }
    }
    __syncthreads();
    for (int widx = t; widx < 512; widx += 256) {
        int rl = widx >> 4, lm = widx & 15;
        unsigned int bits = 0;
        #pragma unroll
        for (int g = 0; g < 32; g++)
            bits |= ((unsigned int)(flg[rl * 512 + (g << 4) + lm] & 1)) << g;
        pm[(size_t)blockIdx.x * 512 + widx] = bits;
    }
}

// ---------------------------------------------------------------------------
// Routing stage 1: raw pooling scores per row (64 rows/block, 4 thr/row).
// ---------------------------------------------------------------------------
__global__ __launch_bounds__(256) void route_score_kernel(
        const void* __restrict__ v, const void* __restrict__ pool_w,
        const void* __restrict__ pool_b, const int* __restrict__ flags,
        float* __restrict__ scores)
{
    __shared__ float pw[768];
    const int t = threadIdx.x;
    const int b = blockIdx.x >> 3, ch = blockIdx.x & 7;
    const int dtV = flags[1], dtW = flags[2];
    for (int d = t; d < 768; d += 256) pw[d] = loadF(pool_w, d, dtW);
    __syncthreads();
    const int r = t >> 2, c4 = t & 3;
    const int n = (ch << 6) + r;
    float dot = 0.f, asum = 0.f;
    if (!dtV) {
        const unsigned int* vr = (const unsigned int*)v + ((size_t)(b * 512 + n)) * 384;
        for (int j = 0; j < 96; j++) {
            int p = c4 + (j << 2);
            unsigned int u = vr[p];
            float f0 = b2f((unsigned short)(u & 0xFFFF));
            float f1 = b2f((unsigned short)(u >> 16));
            asum += fabsf(f0) + fabsf(f1);
            dot += f0 * pw[2 * p] + f1 * pw[2 * p + 1];
        }
    } else {
        const float* vf = (const float*)v + ((size_t)(b * 512 + n)) * 768;
        for (int j = 0; j < 48; j++) {
            float4 u = ((const float4*)vf)[c4 + (j << 2)];
            int e = (c4 + (j << 2)) << 2;
            asum += fabsf(u.x) + fabsf(u.y) + fabsf(u.z) + fabsf(u.w);
            dot += u.x * pw[e] + u.y * pw[e + 1] + u.z * pw[e + 2] + u.w * pw[e + 3];
        }
    }
    dot += __shfl_xor(dot, 1); dot += __shfl_xor(dot, 2);
    asum += __shfl_xor(asum, 1); asum += __shfl_xor(asum, 2);
    if (c4 == 0)
        scores[b * 512 + n] = (asum == 0.f) ? NEGV : dot + loadF(pool_b, 0, dtW);
}

// ---------------------------------------------------------------------------
// Routing stage 2: softmax over N per batch -> scs. 8 blocks x 512.
// ---------------------------------------------------------------------------
__global__ __launch_bounds__(512) void route_softmax_kernel(
        const float* __restrict__ scores, float* __restrict__ scs)
{
    __shared__ float red[8];
    const int t = threadIdx.x, b = blockIdx.x;
    float scv = scores[b * 512 + t];
    float mx = scv;
    #pragma unroll
    for (int off = 1; off < 64; off <<= 1) mx = fmaxf(mx, __shfl_xor(mx, off));
    if ((t & 63) == 0) red[t >> 6] = mx;
    __syncthreads();
    float M = red[0];
    #pragma unroll
    for (int i = 1; i < 8; i++) M = fmaxf(M, red[i]);
    float e = __expf(scv - M);
    __syncthreads();
    float sm = e;
    #pragma unroll
    for (int off = 1; off < 64; off <<= 1) sm += __shfl_xor(sm, off);
    if ((t & 63) == 0) red[t >> 6] = sm;
    __syncthreads();
    float SS = 0.f;
    #pragma unroll
    for (int i = 0; i < 8; i++) SS += red[i];
    scs[b * 512 + t] = e / SS;
}

// ---------------------------------------------------------------------------
// Routing stage 3: partial pooled sums. Grid (8 chunks, 8 b), 256 thr.
// Thread t owns d = 3t..3t+2; loops its chunk's 64 rows. Coalesced.
// ---------------------------------------------------------------------------
__global__ __launch_bounds__(256) void route_pool_kernel(
        const void* __restrict__ v, const int* __restrict__ flags,
        const float* __restrict__ scs, float* __restrict__ ppart)
{
    __shared__ float ps[64];
    const int t = threadIdx.x;
    const int ch = blockIdx.x, b = blockIdx.y;
    const int dtV = flags[1];
    if (t < 64) ps[t] = scs[b * 512 + (ch << 6) + t];
    __syncthreads();
    const int d0 = t * 3;
    float a0 = 0.f, a1 = 0.f, a2 = 0.f;
    if (!dtV) {
        const unsigned short* vb = (const unsigned short*)v
            + ((size_t)(b * 512 + (ch << 6))) * 768 + d0;
        #pragma unroll 4
        for (int r = 0; r < 64; r++) {
            float p = ps[r];
            a0 += b2f(vb[0]) * p; a1 += b2f(vb[1]) * p; a2 += b2f(vb[2]) * p;
            vb += 768;
        }
    } else {
        const float* vb = (const float*)v + ((size_t)(b * 512 + (ch << 6))) * 768 + d0;
        #pragma unroll 4
        for (int r = 0; r < 64; r++) {
            float p = ps[r];
            a0 += vb[0] * p; a1 += vb[1] * p; a2 += vb[2] * p;
            vb += 768;
        }
    }
    float* o = ppart + ((size_t)(b * 8 + ch)) * 768 + d0;
    o[0] = a0; o[1] = a1; o[2] = a2;
}

// ---------------------------------------------------------------------------
// Routing stage 4: reduce partials, MLP, alphas. 8 blocks x 512.
// ---------------------------------------------------------------------------
__global__ __launch_bounds__(512) void route_mlp_kernel(
        const void* __restrict__ w1, const void* __restrict__ w2,
        const void* __restrict__ b2, const int* __restrict__ flags,
        const float* __restrict__ ppart, float* __restrict__ alphas)
{
    __shared__ float pool[768];
    __shared__ float hid[384];
    __shared__ float red[4];
    const int t = threadIdx.x, b = blockIdx.x;
    const int dtW = flags[2];
    for (int d = t; d < 768; d += 512) {
        float a = 0.f;
        #pragma unroll
        for (int c = 0; c < 8; c++) a += ppart[((size_t)(b * 8 + c)) * 768 + d];
        pool[d] = a;
    }
    __syncthreads();
    if (t < 384) {
        float a = 0.f;
        for (int d = 0; d < 768; d++) a += pool[d] * loadF(w1, d * 384 + t, dtW);
        hid[t] = fmaxf(a, 0.f);
    }
    __syncthreads();
    if (t < 3) {
        float a = loadF(b2, t, dtW);
        for (int j = 0; j < 384; j++) a += hid[j] * loadF(w2, j * 3 + t, dtW);
        red[t] = a;
    }
    __syncthreads();
    if (t == 0) {
        float l0 = red[0], l1 = red[1], l2 = red[2];
        float mm = fmaxf(l0, fmaxf(l1, l2));
        float e0 = __expf(l0 - mm), e1 = __expf(l1 - mm), e2 = __expf(l2 - mm);
        float ss = e0 + e1 + e2;
        alphas[b * 3 + 0] = e0 / ss;
        alphas[b * 3 + 1] = e1 / ss;
        alphas[b * 3 + 2] = e2 / ss;
    }
}

// ---------------------------------------------------------------------------
// MFMA bf16 GEMM: C[4096x768] = X @ W + bias, 64x64 tile, 4 waves.
// mode 0: dst[b][h][n][64] bf16 ; mode 1: dst[row][col] (bf16 or f32)
// mode 2: dst[b][h][64][n] bf16 (transposed V)
// ---------------------------------------------------------------------------
__global__ __launch_bounds__(256) void gemm_kernel(
        const void* __restrict__ X,
        const void* __restrict__ W,
        const void* __restrict__ bias,
        const int* __restrict__ flags, int xsel, int wsel,
        void* __restrict__ dst, int mode)
{
    __shared__ unsigned short smem[64 * 72];
    unsigned short* At = smem;
    unsigned short* Bt = smem + 2048;
    const int t = threadIdx.x;
    const int w = t >> 6, lane = t & 63, q = lane >> 4, lm = lane & 15;
    const int row0 = blockIdx.y << 6, col0 = blockIdx.x << 6;
    const int ar = t >> 2, ac = (t & 3) << 3;
    const int bk = t >> 3, bc = t & 7;
    const int aswz = ((ar >> 3) & 3) << 3;
    const int bswz = (bc & 3) << 3;
    const int am = (w << 4) + lm;
    const int acs = ((am >> 3) & 3) << 3;
    const int dtX = (xsel >= 0) ? flags[xsel] : 0;
    const int dtW = flags[wsel];
    const int dtOut = flags[1];

    f32x4 acc[4];
    #pragma unroll
    for (int i = 0; i < 4; i++) acc[i] = (f32x4){0.f, 0.f, 0.f, 0.f};

    for (int k0 = 0; k0 < 768; k0 += 32) {
        uint4 av = load8bf(X, (size_t)(row0 + ar) * 768 + k0 + ac, dtX);
        uint4 wv = load8bf(W, (size_t)(k0 + bk) * 768 + col0 + (bc << 3), dtW);
        __syncthreads();
        *(uint4*)(&At[ar * 32 + (ac ^ aswz)]) = av;
        {
            unsigned short* bp = &Bt[(bc << 3) * 32 + (bk ^ bswz)];
            unsigned int uu[4] = {wv.x, wv.y, wv.z, wv.w};
            #pragma unroll
            for (int j = 0; j < 4; j++) {
                bp[(2 * j) * 32] = (unsigned short)(uu[j] & 0xFFFF);
                bp[(2 * j + 1) * 32] = (unsigned short)(uu[j] >> 16);
            }
        }
        __syncthreads();
        bf16x8 afr = *(const bf16x8*)(&At[am * 32 + ((q << 3) ^ acs)]);
        #pragma unroll
        for (int t4 = 0; t4 < 4; t4++) {
            int bn = (t4 << 4) + lm;
            bf16x8 bfr = *(const bf16x8*)(&Bt[bn * 32 + ((q << 3) ^ (((bn >> 3) & 3) << 3))]);
            acc[t4] = __builtin_amdgcn_mfma_f32_16x16x32_bf16(afr, bfr, acc[t4], 0, 0, 0);
        }
    }

    if (mode == 1 && dtOut) {
        #pragma unroll
        for (int t4 = 0; t4 < 4; t4++) {
            int col = col0 + (t4 << 4) + lm;
            float bsv = loadF(bias, col, dtW);
            #pragma unroll
            for (int rg = 0; rg < 4; rg++) {
                int row = row0 + (w << 4) + (q << 2) + rg;
                ((float*)dst)[(size_t)row * 768 + col] = acc[t4][rg] + bsv;
            }
        }
        return;
    }

    __syncthreads();
    #pragma unroll
    for (int t4 = 0; t4 < 4; t4++) {
        int colL = (t4 << 4) + lm;
        float bsv = loadF(bias, col0 + colL, dtW);
        #pragma unroll
        for (int rg = 0; rg < 4; rg++) {
            int rowL = (w << 4) + (q << 2) + rg;
            unsigned short hv = f2b(acc[t4][rg] + bsv);
            if (mode == 2) smem[colL * 72 + rowL] = hv;
            else           smem[rowL * 72 + colL] = hv;
        }
    }
    __syncthreads();
    const int g = t >> 2, c0 = (t & 3) << 4;
    uint4 w0 = *(const uint4*)&smem[g * 72 + c0];
    uint4 w1v = *(const uint4*)&smem[g * 72 + c0 + 8];
    unsigned short* o;
    if (mode == 0) {
        int b = row0 >> 9, n0b = row0 & 511, h = col0 >> 6;
        o = (unsigned short*)dst + ((size_t)(b * 12 + h) * 512 + n0b + g) * 64 + c0;
    } else if (mode == 2) {
        int b = row0 >> 9, n0b = row0 & 511, h = col0 >> 6;
        o = (unsigned short*)dst + ((size_t)(b * 12 + h) * 64 + g) * 512 + n0b + c0;
    } else {
        o = (unsigned short*)dst + (size_t)(row0 + g) * 768 + col0 + c0;
    }
    *(uint4*)o = w0;
    *(uint4*)(o + 8) = w1v;
}

// ---------------------------------------------------------------------------
// MFMA attention. Block = 16 Q rows of one (b,h). 4 waves.
// ---------------------------------------------------------------------------
__global__ __launch_bounds__(256) void attn_kernel(
        const unsigned short* __restrict__ qh, const unsigned short* __restrict__ kh,
        const unsigned short* __restrict__ vT, const unsigned int* __restrict__ pm,
        const float* __restrict__ alphas, unsigned short* __restrict__ atted)
{
    __shared__ unsigned short P[16 * 512];
    __shared__ float Zp[4][16][3];
    __shared__ unsigned short Ost[16 * 72];
    const int t = threadIdx.x;
    const int w = t >> 6, lane = t & 63, quad = lane >> 4, lm = lane & 15;
    const int qb = blockIdx.x, h = blockIdx.y, b = blockIdx.z;
    const int n0 = qb << 4, bh = b * 12 + h;

    const unsigned short* qrow = qh + ((size_t)(bh * 512 + n0 + lm)) * 64 + (quad << 3);
    bf16x8 qa0 = *(const bf16x8*)qrow;
    bf16x8 qa1 = *(const bf16x8*)(qrow + 32);
    f32x4 acc[8];
    #pragma unroll
    for (int i = 0; i < 8; i++) acc[i] = (f32x4){0.f, 0.f, 0.f, 0.f};
    const unsigned short* kb0 = kh + ((size_t)(bh * 512 + (w << 7) + lm)) * 64 + (quad << 3);
    #pragma unroll
    for (int nt = 0; nt < 8; nt++) {
        const unsigned short* kr = kb0 + nt * (16 * 64);
        bf16x8 k0 = *(const bf16x8*)kr;
        bf16x8 k1 = *(const bf16x8*)(kr + 32);
        acc[nt] = __builtin_amdgcn_mfma_f32_16x16x32_bf16(qa0, k0, acc[nt], 0, 0, 0);
        acc[nt] = __builtin_amdgcn_mfma_f32_16x16x32_bf16(qa1, k1, acc[nt], 0, 0, 0);
    }

    float al[3];
    #pragma unroll
    for (int l = 0; l < 3; l++) al[l] = alphas[b * 3 + l];

    #pragma unroll
    for (int nt = 0; nt < 8; nt++)
        #pragma unroll
        for (int rg = 0; rg < 4; rg++)
            acc[nt][rg] = __expf(acc[nt][rg] * 0.125f);

    unsigned int mk[4][3];
    #pragma unroll
    for (int rg = 0; rg < 4; rg++)
        #pragma unroll
        for (int l = 0; l < 3; l++)
            mk[rg][l] = pm[((size_t)((l << 3) + b) * 512 + n0 + (quad << 2) + rg) * 16 + lm];

    #pragma unroll
    for (int rg = 0; rg < 4; rg++) {
        float z0 = 0.f, z1 = 0.f, z2 = 0.f;
        #pragma unroll
        for (int nt = 0; nt < 8; nt++) {
            int g = (w << 3) + nt;
            float e = acc[nt][rg];
            if (!((mk[rg][0] >> g) & 1)) z0 += e;
            if (!((mk[rg][1] >> g) & 1)) z1 += e;
            if (!((mk[rg][2] >> g) & 1)) z2 += e;
        }
        #pragma unroll
        for (int off = 1; off < 16; off <<= 1) {
            z0 += __shfl_xor(z0, off);
            z1 += __shfl_xor(z1, off);
            z2 += __shfl_xor(z2, off);
        }
        if (lm == 0) {
            int row = (quad << 2) + rg;
            Zp[w][row][0] = z0; Zp[w][row][1] = z1; Zp[w][row][2] = z2;
        }
    }
    __syncthreads();

    #pragma unroll
    for (int rg = 0; rg < 4; rg++) {
        int row = (quad << 2) + rg;
        float coef[3]; float addu = 0.f;
        #pragma unroll
        for (int l = 0; l < 3; l++) {
            float Z = Zp[0][row][l] + Zp[1][row][l] + Zp[2][row][l] + Zp[3][row][l];
            if (Z > 0.f) coef[l] = al[l] / Z;
            else { coef[l] = 0.f; addu += al[l] * (1.0f / 512.0f); }
        }
        #pragma unroll
        for (int nt = 0; nt < 8; nt++) {
            int g = (w << 3) + nt;
            float p = addu;
            float e = acc[nt][rg];
            if (!((mk[rg][0] >> g) & 1)) p += coef[0] * e;
            if (!((mk[rg][1] >> g) & 1)) p += coef[1] * e;
            if (!((mk[rg][2] >> g) & 1)) p += coef[2] * e;
            int c = (g << 4) + lm;
            int chunk = c >> 3, j = c & 7;
            P[row * 512 + (((chunk ^ (row & 7))) << 3) + j] = f2b(p);
        }
    }
    __syncthreads();

    f32x4 accO = (f32x4){0.f, 0.f, 0.f, 0.f};
    const unsigned short* vb = vT + ((size_t)(bh * 64 + (w << 4) + lm)) * 512 + (quad << 3);
    #pragma unroll
    for (int ks = 0; ks < 16; ks++) {
        bf16x8 pa = *(const bf16x8*)&P[lm * 512 + ((((ks << 2) + quad) ^ (lm & 7)) << 3)];
        bf16x8 vf = *(const bf16x8*)(vb + (ks << 5));
        accO = __builtin_amdgcn_mfma_f32_16x16x32_bf16(pa, vf, accO, 0, 0, 0);
    }
    #pragma unroll
    for (int rg = 0; rg < 4; rg++)
        Ost[((quad << 2) + rg) * 72 + (w << 4) + lm] = f2b(accO[rg]);
    __syncthreads();
    const int r2 = t >> 4, c4 = t & 15;
    uint2 val = *(const uint2*)&Ost[r2 * 72 + (c4 << 2)];
    *(uint2*)&atted[((size_t)(b * 512 + n0 + r2)) * 768 + (h << 6) + (c4 << 2)] = val;
}

// ---------------------------------------------------------------------------
extern "C" void kernel_launch(void* const* d_in, const int* in_sizes, int n_in,
                              void* d_out, int out_size, void* d_ws, size_t ws_size,
                              hipStream_t stream)
{
    const void* v  = d_in[0];
    const void* k  = d_in[1];
    const void* q  = d_in[2];
    const void* mk = d_in[3];
    const void* Wv = d_in[6];
    const void* bv = d_in[7];
    const void* Wk = d_in[8];
    const void* bk = d_in[9];
    const void* Wq = d_in[10];
    const void* bq = d_in[11];
    const void* Wm = d_in[12];
    const void* bm = d_in[13];
    const void* pool_w = d_in[14];
    const void* pool_b = d_in[15];
    const void* w1 = d_in[16];
    const void* w2 = d_in[17];
    const void* b2 = d_in[18];

    char* ws = (char*)d_ws;
    int*   flags  = (int*)ws;                                   // 64 B
    float* alphas = (float*)(ws + 256);                         // 96 B
    float* scores = (float*)(ws + 512);                         // 16 KB
    float* scs    = (float*)(ws + 16896);                       // 16 KB
    float* ppart  = (float*)(ws + 33280);                       // 196 KB
    unsigned int* pm = (unsigned int*)(ws + 229888);            // 786 KB
    unsigned short* qh    = (unsigned short*)(ws + 1048576);    // 6.29 MB each
    unsigned short* kh    = (unsigned short*)(ws + 1048576 + 6291456L);
    unsigned short* vT    = (unsigned short*)(ws + 1048576 + 2 * 6291456L);
    unsigned short* atted = (unsigned short*)(ws + 1048576 + 3 * 6291456L);

    sniff_kernel<<<dim3(1), dim3(256), 0, stream>>>(
        (const unsigned int*)mk, (const unsigned int*)v, (const unsigned int*)Wv, flags);
    pack_kernel<<<dim3(384), dim3(256), 0, stream>>>(mk, flags, pm);
    route_score_kernel<<<dim3(64), dim3(256), 0, stream>>>(v, pool_w, pool_b, flags, scores);
    route_softmax_kernel<<<dim3(8), dim3(512), 0, stream>>>(scores, scs);
    route_pool_kernel<<<dim3(8, 8), dim3(256), 0, stream>>>(v, flags, scs, ppart);
    route_mlp_kernel<<<dim3(8), dim3(512), 0, stream>>>(w1, w2, b2, flags, ppart, alphas);
    gemm_kernel<<<dim3(12, 64), dim3(256), 0, stream>>>(v, Wv, bv, flags, 1, 2, (void*)vT, 2);
    gemm_kernel<<<dim3(12, 64), dim3(256), 0, stream>>>(k, Wk, bk, flags, 1, 2, (void*)kh, 0);
    gemm_kernel<<<dim3(12, 64), dim3(256), 0, stream>>>(q, Wq, bq, flags, 1, 2, (void*)qh, 0);
    attn_kernel<<<dim3(32, 12, 8), dim3(256), 0, stream>>>(qh, kh, vT, pm, alphas, atted);
    gemm_kernel<<<dim3(12, 64), dim3(256), 0, stream>>>(atted, Wm, bm, flags, -1, 2, d_out, 1);
}

// Round 5
// 366.172 us; speedup vs baseline: 3.1557x; 1.2056x over previous
//
#include <hip/hip_runtime.h>
#include <hip/hip_bf16.h>
#include <stdint.h>

// ---------------------------------------------------------------------------
// SARoutingBlock: alphas = soft_routing(v); qkv projections; 3-order masked
// softmax attention combined by alphas; output projection.
// B=8, N=512, HID=768, HEADS=12, dk=64, ORDERS=3.
// Round 5: route_mlp (8-block latency-bound w1 matvec, 88us) -> route_hid
// (96 blocks, sliced w1) + route_alpha. Rest unchanged from round 4.
// ---------------------------------------------------------------------------

typedef __bf16 bf16x8 __attribute__((ext_vector_type(8)));
typedef float f32x4 __attribute__((ext_vector_type(4)));

#define NEGV -1e9f

__device__ __forceinline__ float b2f(unsigned short h) {
    union { unsigned int u; float f; } x; x.u = ((unsigned int)h) << 16; return x.f;
}
__device__ __forceinline__ unsigned short f2b(float f) {
    union { float f; unsigned int u; } x; x.f = f;
    unsigned int u = x.u + 0x7FFFu + ((x.u >> 16) & 1u);
    return (unsigned short)(u >> 16);
}
__device__ __forceinline__ unsigned int packbf(unsigned int u0, unsigned int u1) {
    unsigned int r0 = (u0 + 0x7FFFu + ((u0 >> 16) & 1u)) >> 16;
    unsigned int r1 = (u1 + 0x7FFFu + ((u1 >> 16) & 1u)) & 0xFFFF0000u;
    return r0 | r1;
}
__device__ __forceinline__ uint4 load8bf(const void* base, size_t elemOff, int isF32) {
    if (!isF32) return *(const uint4*)((const unsigned short*)base + elemOff);
    const uint4* f = (const uint4*)((const float*)base + elemOff);
    uint4 a = f[0], b = f[1];
    uint4 r;
    r.x = packbf(a.x, a.y);
    r.y = packbf(a.z, a.w);
    r.z = packbf(b.x, b.y);
    r.w = packbf(b.z, b.w);
    return r;
}
__device__ __forceinline__ float loadF(const void* p, int idx, int isF32) {
    return isF32 ? ((const float*)p)[idx] : b2f(((const unsigned short*)p)[idx]);
}

// ---------------------------------------------------------------------------
// Sniffer: flags[0]=mask mode (0=i32,1=u8,2=f32,3=bf16); flags[1]=v/k/q dtype
// (0=bf16,1=f32); flags[2]=weights dtype.
// ---------------------------------------------------------------------------
__global__ void sniff_kernel(const unsigned int* __restrict__ mp,
                             const unsigned int* __restrict__ vp,
                             const unsigned int* __restrict__ wp,
                             int* __restrict__ flags)
{
    __shared__ int oki, oku, okf, badv, badw;
    if (threadIdx.x == 0) { oki = 1; oku = 1; okf = 1; badv = 0; badw = 0; }
    __syncthreads();
    int li = 1, lu = 1, lf = 1, bv = 0, bw = 0;
    for (int i = threadIdx.x; i < 16384; i += 256) {
        unsigned int w = mp[i];
        if (w > 1u) li = 0;
        if (w & 0xFEFEFEFEu) lu = 0;
        if (w != 0u && w != 0x3F800000u) lf = 0;
    }
    for (int i = threadIdx.x; i < 8192; i += 256) {
        unsigned int w = vp[i];
        float f0 = b2f((unsigned short)(w & 0xFFFF));
        float f1 = b2f((unsigned short)(w >> 16));
        if (!(fabsf(f0) < 1e4f) || !(fabsf(f1) < 1e4f)) bv = 1;
        w = wp[i];
        f0 = b2f((unsigned short)(w & 0xFFFF));
        f1 = b2f((unsigned short)(w >> 16));
        if (!(fabsf(f0) < 1e4f) || !(fabsf(f1) < 1e4f)) bw = 1;
    }
    if (!li) atomicAnd(&oki, 0);
    if (!lu) atomicAnd(&oku, 0);
    if (!lf) atomicAnd(&okf, 0);
    if (bv) atomicOr(&badv, 1);
    if (bw) atomicOr(&badw, 1);
    __syncthreads();
    if (threadIdx.x == 0) {
        flags[0] = oki ? 0 : (oku ? 1 : (okf ? 2 : 3));
        flags[1] = badv;
        flags[2] = badw;
    }
}

// ---------------------------------------------------------------------------
// Mask bit-pack: pm[grow*16 + lm], grow = (l*8+b)*512 + n,
// bit g = mask[l,b,n, g*16+lm]. One block packs 32 rows.
// ---------------------------------------------------------------------------
__global__ __launch_bounds__(256) void pack_kernel(
        const void* __restrict__ masks, const int* __restrict__ flags,
        unsigned int* __restrict__ pm)
{
    __shared__ unsigned char flg[32 * 512];
    const int t = threadIdx.x;
    const int mode = flags[0];
    const size_t e0 = (size_t)blockIdx.x * (32 * 512);
    if (mode == 0 || mode == 2) {
        const uint4* p = (const uint4*)((const unsigned int*)masks + e0);
        for (int i = t; i < 4096; i += 256) {
            uint4 u = p[i];
            int base = i << 2;
            flg[base + 0] = u.x ? 1 : 0;
            flg[base + 1] = u.y ? 1 : 0;
            flg[base + 2] = u.z ? 1 : 0;
            flg[base + 3] = u.w ? 1 : 0;
        }
    } else if (mode == 1) {
        const uint4* p = (const uint4*)((const unsigned char*)masks + e0);
        for (int i = t; i < 1024; i += 256) {
            uint4 u = p[i];
            unsigned int uu[4] = {u.x, u.y, u.z, u.w};
            int base = i << 4;
            #pragma unroll
            for (int k2 = 0; k2 < 4; k2++)
                #pragma unroll
                for (int bb = 0; bb < 4; bb++)
                    flg[base + k2 * 4 + bb] = ((uu[k2] >> (bb * 8)) & 0xFFu) ? 1 : 0;
        }
    } else {
        const uint4* p = (const uint4*)((const unsigned short*)masks + e0);
        for (int i = t; i < 2048; i += 256) {
            uint4 u = p[i];
            unsigned int uu[4] = {u.x, u.y, u.z, u.w};
            int base = i << 3;
            #pragma unroll
            for (int k2 = 0; k2 < 4; k2++) {
                flg[base + k2 * 2 + 0] = (uu[k2] & 0xFFFFu) ? 1 : 0;
                flg[base + k2 * 2 + 1] = (uu[k2] >> 16) ? 1 : 0;
            }
        }
    }
    __syncthreads();
    for (int widx = t; widx < 512; widx += 256) {
        int rl = widx >> 4, lm = widx & 15;
        unsigned int bits = 0;
        #pragma unroll
        for (int g = 0; g < 32; g++)
            bits |= ((unsigned int)(flg[rl * 512 + (g << 4) + lm] & 1)) << g;
        pm[(size_t)blockIdx.x * 512 + widx] = bits;
    }
}

// ---------------------------------------------------------------------------
// Routing stage 1: raw pooling scores per row (64 rows/block, 4 thr/row).
// ---------------------------------------------------------------------------
__global__ __launch_bounds__(256) void route_score_kernel(
        const void* __restrict__ v, const void* __restrict__ pool_w,
        const void* __restrict__ pool_b, const int* __restrict__ flags,
        float* __restrict__ scores)
{
    __shared__ float pw[768];
    const int t = threadIdx.x;
    const int b = blockIdx.x >> 3, ch = blockIdx.x & 7;
    const int dtV = flags[1], dtW = flags[2];
    for (int d = t; d < 768; d += 256) pw[d] = loadF(pool_w, d, dtW);
    __syncthreads();
    const int r = t >> 2, c4 = t & 3;
    const int n = (ch << 6) + r;
    float dot = 0.f, asum = 0.f;
    if (!dtV) {
        const unsigned int* vr = (const unsigned int*)v + ((size_t)(b * 512 + n)) * 384;
        for (int j = 0; j < 96; j++) {
            int p = c4 + (j << 2);
            unsigned int u = vr[p];
            float f0 = b2f((unsigned short)(u & 0xFFFF));
            float f1 = b2f((unsigned short)(u >> 16));
            asum += fabsf(f0) + fabsf(f1);
            dot += f0 * pw[2 * p] + f1 * pw[2 * p + 1];
        }
    } else {
        const float* vf = (const float*)v + ((size_t)(b * 512 + n)) * 768;
        for (int j = 0; j < 48; j++) {
            float4 u = ((const float4*)vf)[c4 + (j << 2)];
            int e = (c4 + (j << 2)) << 2;
            asum += fabsf(u.x) + fabsf(u.y) + fabsf(u.z) + fabsf(u.w);
            dot += u.x * pw[e] + u.y * pw[e + 1] + u.z * pw[e + 2] + u.w * pw[e + 3];
        }
    }
    dot += __shfl_xor(dot, 1); dot += __shfl_xor(dot, 2);
    asum += __shfl_xor(asum, 1); asum += __shfl_xor(asum, 2);
    if (c4 == 0)
        scores[b * 512 + n] = (asum == 0.f) ? NEGV : dot + loadF(pool_b, 0, dtW);
}

// ---------------------------------------------------------------------------
// Routing stage 2: softmax over N per batch -> scs. 8 blocks x 512.
// ---------------------------------------------------------------------------
__global__ __launch_bounds__(512) void route_softmax_kernel(
        const float* __restrict__ scores, float* __restrict__ scs)
{
    __shared__ float red[8];
    const int t = threadIdx.x, b = blockIdx.x;
    float scv = scores[b * 512 + t];
    float mx = scv;
    #pragma unroll
    for (int off = 1; off < 64; off <<= 1) mx = fmaxf(mx, __shfl_xor(mx, off));
    if ((t & 63) == 0) red[t >> 6] = mx;
    __syncthreads();
    float M = red[0];
    #pragma unroll
    for (int i = 1; i < 8; i++) M = fmaxf(M, red[i]);
    float e = __expf(scv - M);
    __syncthreads();
    float sm = e;
    #pragma unroll
    for (int off = 1; off < 64; off <<= 1) sm += __shfl_xor(sm, off);
    if ((t & 63) == 0) red[t >> 6] = sm;
    __syncthreads();
    float SS = 0.f;
    #pragma unroll
    for (int i = 0; i < 8; i++) SS += red[i];
    scs[b * 512 + t] = e / SS;
}

// ---------------------------------------------------------------------------
// Routing stage 3: partial pooled sums. Grid (8 chunks, 8 b), 256 thr.
// ---------------------------------------------------------------------------
__global__ __launch_bounds__(256) void route_pool_kernel(
        const void* __restrict__ v, const int* __restrict__ flags,
        const float* __restrict__ scs, float* __restrict__ ppart)
{
    __shared__ float ps[64];
    const int t = threadIdx.x;
    const int ch = blockIdx.x, b = blockIdx.y;
    const int dtV = flags[1];
    if (t < 64) ps[t] = scs[b * 512 + (ch << 6) + t];
    __syncthreads();
    const int d0 = t * 3;
    float a0 = 0.f, a1 = 0.f, a2 = 0.f;
    if (!dtV) {
        const unsigned short* vb = (const unsigned short*)v
            + ((size_t)(b * 512 + (ch << 6))) * 768 + d0;
        #pragma unroll 4
        for (int r = 0; r < 64; r++) {
            float p = ps[r];
            a0 += b2f(vb[0]) * p; a1 += b2f(vb[1]) * p; a2 += b2f(vb[2]) * p;
            vb += 768;
        }
    } else {
        const float* vb = (const float*)v + ((size_t)(b * 512 + (ch << 6))) * 768 + d0;
        #pragma unroll 4
        for (int r = 0; r < 64; r++) {
            float p = ps[r];
            a0 += vb[0] * p; a1 += vb[1] * p; a2 += vb[2] * p;
            vb += 768;
        }
    }
    float* o = ppart + ((size_t)(b * 8 + ch)) * 768 + d0;
    o[0] = a0; o[1] = a1; o[2] = a2;
}

// ---------------------------------------------------------------------------
// Routing stage 4: hidden units + partial logits. Grid (12 jc, 8 b), 256 thr.
// Block handles 32 hidden units from a 768x32 w1 slice; emits plog[b][jc][3].
// ---------------------------------------------------------------------------
__global__ __launch_bounds__(256) void route_hid_kernel(
        const void* __restrict__ w1, const void* __restrict__ w2,
        const int* __restrict__ flags, const float* __restrict__ ppart,
        float* __restrict__ plog)
{
    __shared__ float pool[768];
    __shared__ float red[4][32];
    const int t = threadIdx.x;
    const int jc = blockIdx.x, b = blockIdx.y;
    const int dtW = flags[2];
    for (int d = t; d < 768; d += 256) {
        float a = 0.f;
        #pragma unroll
        for (int c = 0; c < 8; c++) a += ppart[((size_t)(b * 8 + c)) * 768 + d];
        pool[d] = a;
    }
    __syncthreads();
    const int jo = (t & 3) << 3;
    const int dr = t >> 2;
    float acc[8];
    #pragma unroll
    for (int j = 0; j < 8; j++) acc[j] = 0.f;
    for (int it = 0; it < 12; it++) {
        int d = (it << 6) + dr;
        float pv = pool[d];
        size_t off = (size_t)d * 384 + (jc << 5) + jo;
        if (!dtW) {
            uint4 u = *(const uint4*)((const unsigned short*)w1 + off);
            unsigned int uu[4] = {u.x, u.y, u.z, u.w};
            #pragma unroll
            for (int j2 = 0; j2 < 4; j2++) {
                acc[2 * j2]     += pv * b2f((unsigned short)(uu[j2] & 0xFFFF));
                acc[2 * j2 + 1] += pv * b2f((unsigned short)(uu[j2] >> 16));
            }
        } else {
            const float4* f = (const float4*)((const float*)w1 + off);
            float4 u0 = f[0], u1 = f[1];
            acc[0] += pv * u0.x; acc[1] += pv * u0.y;
            acc[2] += pv * u0.z; acc[3] += pv * u0.w;
            acc[4] += pv * u1.x; acc[5] += pv * u1.y;
            acc[6] += pv * u1.z; acc[7] += pv * u1.w;
        }
    }
    #pragma unroll
    for (int off = 4; off < 64; off <<= 1)
        #pragma unroll
        for (int j = 0; j < 8; j++) acc[j] += __shfl_xor(acc[j], off);
    const int w = t >> 6, lane = t & 63;
    if (lane < 4) {
        #pragma unroll
        for (int j = 0; j < 8; j++) red[w][lane * 8 + j] = acc[j];
    }
    __syncthreads();
    if (t < 32) {
        float h = red[0][t] + red[1][t] + red[2][t] + red[3][t];
        h = fmaxf(h, 0.f);
        int jg = (jc << 5) + t;
        float l0 = h * loadF(w2, jg * 3 + 0, dtW);
        float l1 = h * loadF(w2, jg * 3 + 1, dtW);
        float l2 = h * loadF(w2, jg * 3 + 2, dtW);
        #pragma unroll
        for (int off = 1; off < 32; off <<= 1) {
            l0 += __shfl_xor(l0, off);
            l1 += __shfl_xor(l1, off);
            l2 += __shfl_xor(l2, off);
        }
        if (t == 0) {
            float* o = plog + ((size_t)(b * 12 + jc)) * 3;
            o[0] = l0; o[1] = l1; o[2] = l2;
        }
    }
}

// ---------------------------------------------------------------------------
// Routing stage 5: reduce partial logits, softmax -> alphas. 8 tiny blocks.
// ---------------------------------------------------------------------------
__global__ __launch_bounds__(64) void route_alpha_kernel(
        const void* __restrict__ b2, const int* __restrict__ flags,
        const float* __restrict__ plog, float* __restrict__ alphas)
{
    const int t = threadIdx.x, b = blockIdx.x;
    if (t == 0) {
        const int dtW = flags[2];
        float lg[3];
        #pragma unroll
        for (int l = 0; l < 3; l++) {
            float a = loadF(b2, l, dtW);
            for (int jc = 0; jc < 12; jc++) a += plog[((size_t)(b * 12 + jc)) * 3 + l];
            lg[l] = a;
        }
        float mm = fmaxf(lg[0], fmaxf(lg[1], lg[2]));
        float e0 = __expf(lg[0] - mm), e1 = __expf(lg[1] - mm), e2 = __expf(lg[2] - mm);
        float ss = e0 + e1 + e2;
        alphas[b * 3 + 0] = e0 / ss;
        alphas[b * 3 + 1] = e1 / ss;
        alphas[b * 3 + 2] = e2 / ss;
    }
}

// ---------------------------------------------------------------------------
// MFMA bf16 GEMM: C[4096x768] = X @ W + bias, 64x64 tile, 4 waves.
// mode 0: dst[b][h][n][64] bf16 ; mode 1: dst[row][col] (bf16 or f32)
// mode 2: dst[b][h][64][n] bf16 (transposed V)
// ---------------------------------------------------------------------------
__global__ __launch_bounds__(256) void gemm_kernel(
        const void* __restrict__ X,
        const void* __restrict__ W,
        const void* __restrict__ bias,
        const int* __restrict__ flags, int xsel, int wsel,
        void* __restrict__ dst, int mode)
{
    __shared__ unsigned short smem[64 * 72];
    unsigned short* At = smem;
    unsigned short* Bt = smem + 2048;
    const int t = threadIdx.x;
    const int w = t >> 6, lane = t & 63, q = lane >> 4, lm = lane & 15;
    const int row0 = blockIdx.y << 6, col0 = blockIdx.x << 6;
    const int ar = t >> 2, ac = (t & 3) << 3;
    const int bk = t >> 3, bc = t & 7;
    const int aswz = ((ar >> 3) & 3) << 3;
    const int bswz = (bc & 3) << 3;
    const int am = (w << 4) + lm;
    const int acs = ((am >> 3) & 3) << 3;
    const int dtX = (xsel >= 0) ? flags[xsel] : 0;
    const int dtW = flags[wsel];
    const int dtOut = flags[1];

    f32x4 acc[4];
    #pragma unroll
    for (int i = 0; i < 4; i++) acc[i] = (f32x4){0.f, 0.f, 0.f, 0.f};

    for (int k0 = 0; k0 < 768; k0 += 32) {
        uint4 av = load8bf(X, (size_t)(row0 + ar) * 768 + k0 + ac, dtX);
        uint4 wv = load8bf(W, (size_t)(k0 + bk) * 768 + col0 + (bc << 3), dtW);
        __syncthreads();
        *(uint4*)(&At[ar * 32 + (ac ^ aswz)]) = av;
        {
            unsigned short* bp = &Bt[(bc << 3) * 32 + (bk ^ bswz)];
            unsigned int uu[4] = {wv.x, wv.y, wv.z, wv.w};
            #pragma unroll
            for (int j = 0; j < 4; j++) {
                bp[(2 * j) * 32] = (unsigned short)(uu[j] & 0xFFFF);
                bp[(2 * j + 1) * 32] = (unsigned short)(uu[j] >> 16);
            }
        }
        __syncthreads();
        bf16x8 afr = *(const bf16x8*)(&At[am * 32 + ((q << 3) ^ acs)]);
        #pragma unroll
        for (int t4 = 0; t4 < 4; t4++) {
            int bn = (t4 << 4) + lm;
            bf16x8 bfr = *(const bf16x8*)(&Bt[bn * 32 + ((q << 3) ^ (((bn >> 3) & 3) << 3))]);
            acc[t4] = __builtin_amdgcn_mfma_f32_16x16x32_bf16(afr, bfr, acc[t4], 0, 0, 0);
        }
    }

    if (mode == 1 && dtOut) {
        #pragma unroll
        for (int t4 = 0; t4 < 4; t4++) {
            int col = col0 + (t4 << 4) + lm;
            float bsv = loadF(bias, col, dtW);
            #pragma unroll
            for (int rg = 0; rg < 4; rg++) {
                int row = row0 + (w << 4) + (q << 2) + rg;
                ((float*)dst)[(size_t)row * 768 + col] = acc[t4][rg] + bsv;
            }
        }
        return;
    }

    __syncthreads();
    #pragma unroll
    for (int t4 = 0; t4 < 4; t4++) {
        int colL = (t4 << 4) + lm;
        float bsv = loadF(bias, col0 + colL, dtW);
        #pragma unroll
        for (int rg = 0; rg < 4; rg++) {
            int rowL = (w << 4) + (q << 2) + rg;
            unsigned short hv = f2b(acc[t4][rg] + bsv);
            if (mode == 2) smem[colL * 72 + rowL] = hv;
            else           smem[rowL * 72 + colL] = hv;
        }
    }
    __syncthreads();
    const int g = t >> 2, c0 = (t & 3) << 4;
    uint4 w0 = *(const uint4*)&smem[g * 72 + c0];
    uint4 w1v = *(const uint4*)&smem[g * 72 + c0 + 8];
    unsigned short* o;
    if (mode == 0) {
        int b = row0 >> 9, n0b = row0 & 511, h = col0 >> 6;
        o = (unsigned short*)dst + ((size_t)(b * 12 + h) * 512 + n0b + g) * 64 + c0;
    } else if (mode == 2) {
        int b = row0 >> 9, n0b = row0 & 511, h = col0 >> 6;
        o = (unsigned short*)dst + ((size_t)(b * 12 + h) * 64 + g) * 512 + n0b + c0;
    } else {
        o = (unsigned short*)dst + (size_t)(row0 + g) * 768 + col0 + c0;
    }
    *(uint4*)o = w0;
    *(uint4*)(o + 8) = w1v;
}

// ---------------------------------------------------------------------------
// MFMA attention. Block = 16 Q rows of one (b,h). 4 waves.
// ---------------------------------------------------------------------------
__global__ __launch_bounds__(256) void attn_kernel(
        const unsigned short* __restrict__ qh, const unsigned short* __restrict__ kh,
        const unsigned short* __restrict__ vT, const unsigned int* __restrict__ pm,
        const float* __restrict__ alphas, unsigned short* __restrict__ atted)
{
    __shared__ unsigned short P[16 * 512];
    __shared__ float Zp[4][16][3];
    __shared__ unsigned short Ost[16 * 72];
    const int t = threadIdx.x;
    const int w = t >> 6, lane = t & 63, quad = lane >> 4, lm = lane & 15;
    const int qb = blockIdx.x, h = blockIdx.y, b = blockIdx.z;
    const int n0 = qb << 4, bh = b * 12 + h;

    const unsigned short* qrow = qh + ((size_t)(bh * 512 + n0 + lm)) * 64 + (quad << 3);
    bf16x8 qa0 = *(const bf16x8*)qrow;
    bf16x8 qa1 = *(const bf16x8*)(qrow + 32);
    f32x4 acc[8];
    #pragma unroll
    for (int i = 0; i < 8; i++) acc[i] = (f32x4){0.f, 0.f, 0.f, 0.f};
    const unsigned short* kb0 = kh + ((size_t)(bh * 512 + (w << 7) + lm)) * 64 + (quad << 3);
    #pragma unroll
    for (int nt = 0; nt < 8; nt++) {
        const unsigned short* kr = kb0 + nt * (16 * 64);
        bf16x8 k0 = *(const bf16x8*)kr;
        bf16x8 k1 = *(const bf16x8*)(kr + 32);
        acc[nt] = __builtin_amdgcn_mfma_f32_16x16x32_bf16(qa0, k0, acc[nt], 0, 0, 0);
        acc[nt] = __builtin_amdgcn_mfma_f32_16x16x32_bf16(qa1, k1, acc[nt], 0, 0, 0);
    }

    float al[3];
    #pragma unroll
    for (int l = 0; l < 3; l++) al[l] = alphas[b * 3 + l];

    #pragma unroll
    for (int nt = 0; nt < 8; nt++)
        #pragma unroll
        for (int rg = 0; rg < 4; rg++)
            acc[nt][rg] = __expf(acc[nt][rg] * 0.125f);

    unsigned int mk[4][3];
    #pragma unroll
    for (int rg = 0; rg < 4; rg++)
        #pragma unroll
        for (int l = 0; l < 3; l++)
            mk[rg][l] = pm[((size_t)((l << 3) + b) * 512 + n0 + (quad << 2) + rg) * 16 + lm];

    #pragma unroll
    for (int rg = 0; rg < 4; rg++) {
        float z0 = 0.f, z1 = 0.f, z2 = 0.f;
        #pragma unroll
        for (int nt = 0; nt < 8; nt++) {
            int g = (w << 3) + nt;
            float e = acc[nt][rg];
            if (!((mk[rg][0] >> g) & 1)) z0 += e;
            if (!((mk[rg][1] >> g) & 1)) z1 += e;
            if (!((mk[rg][2] >> g) & 1)) z2 += e;
        }
        #pragma unroll
        for (int off = 1; off < 16; off <<= 1) {
            z0 += __shfl_xor(z0, off);
            z1 += __shfl_xor(z1, off);
            z2 += __shfl_xor(z2, off);
        }
        if (lm == 0) {
            int row = (quad << 2) + rg;
            Zp[w][row][0] = z0; Zp[w][row][1] = z1; Zp[w][row][2] = z2;
        }
    }
    __syncthreads();

    #pragma unroll
    for (int rg = 0; rg < 4; rg++) {
        int row = (quad << 2) + rg;
        float coef[3]; float addu = 0.f;
        #pragma unroll
        for (int l = 0; l < 3; l++) {
            float Z = Zp[0][row][l] + Zp[1][row][l] + Zp[2][row][l] + Zp[3][row][l];
            if (Z > 0.f) coef[l] = al[l] / Z;
            else { coef[l] = 0.f; addu += al[l] * (1.0f / 512.0f); }
        }
        #pragma unroll
        for (int nt = 0; nt < 8; nt++) {
            int g = (w << 3) + nt;
            float p = addu;
            float e = acc[nt][rg];
            if (!((mk[rg][0] >> g) & 1)) p += coef[0] * e;
            if (!((mk[rg][1] >> g) & 1)) p += coef[1] * e;
            if (!((mk[rg][2] >> g) & 1)) p += coef[2] * e;
            int c = (g << 4) + lm;
            int chunk = c >> 3, j = c & 7;
            P[row * 512 + (((chunk ^ (row & 7))) << 3) + j] = f2b(p);
        }
    }
    __syncthreads();

    f32x4 accO = (f32x4){0.f, 0.f, 0.f, 0.f};
    const unsigned short* vb = vT + ((size_t)(bh * 64 + (w << 4) + lm)) * 512 + (quad << 3);
    #pragma unroll
    for (int ks = 0; ks < 16; ks++) {
        bf16x8 pa = *(const bf16x8*)&P[lm * 512 + ((((ks << 2) + quad) ^ (lm & 7)) << 3)];
        bf16x8 vf = *(const bf16x8*)(vb + (ks << 5));
        accO = __builtin_amdgcn_mfma_f32_16x16x32_bf16(pa, vf, accO, 0, 0, 0);
    }
    #pragma unroll
    for (int rg = 0; rg < 4; rg++)
        Ost[((quad << 2) + rg) * 72 + (w << 4) + lm] = f2b(accO[rg]);
    __syncthreads();
    const int r2 = t >> 4, c4 = t & 15;
    uint2 val = *(const uint2*)&Ost[r2 * 72 + (c4 << 2)];
    *(uint2*)&atted[((size_t)(b * 512 + n0 + r2)) * 768 + (h << 6) + (c4 << 2)] = val;
}

// ---------------------------------------------------------------------------
extern "C" void kernel_launch(void* const* d_in, const int* in_sizes, int n_in,
                              void* d_out, int out_size, void* d_ws, size_t ws_size,
                              hipStream_t stream)
{
    const void* v  = d_in[0];
    const void* k  = d_in[1];
    const void* q  = d_in[2];
    const void* mk = d_in[3];
    const void* Wv = d_in[6];
    const void* bv = d_in[7];
    const void* Wk = d_in[8];
    const void* bk = d_in[9];
    const void* Wq = d_in[10];
    const void* bq = d_in[11];
    const void* Wm = d_in[12];
    const void* bm = d_in[13];
    const void* pool_w = d_in[14];
    const void* pool_b = d_in[15];
    const void* w1 = d_in[16];
    const void* w2 = d_in[17];
    const void* b2 = d_in[18];

    char* ws = (char*)d_ws;
    int*   flags  = (int*)ws;                                   // 64 B
    float* alphas = (float*)(ws + 256);                         // 96 B
    float* scores = (float*)(ws + 512);                         // 16 KB
    float* scs    = (float*)(ws + 16896);                       // 16 KB
    float* ppart  = (float*)(ws + 33280);                       // 196 KB
    float* plog   = (float*)(ws + 229888);                      // 1.2 KB
    unsigned int* pm = (unsigned int*)(ws + 262144);            // 786 KB
    unsigned short* qh    = (unsigned short*)(ws + 1048576);    // 6.29 MB each
    unsigned short* kh    = (unsigned short*)(ws + 1048576 + 6291456L);
    unsigned short* vT    = (unsigned short*)(ws + 1048576 + 2 * 6291456L);
    unsigned short* atted = (unsigned short*)(ws + 1048576 + 3 * 6291456L);

    sniff_kernel<<<dim3(1), dim3(256), 0, stream>>>(
        (const unsigned int*)mk, (const unsigned int*)v, (const unsigned int*)Wv, flags);
    pack_kernel<<<dim3(384), dim3(256), 0, stream>>>(mk, flags, pm);
    route_score_kernel<<<dim3(64), dim3(256), 0, stream>>>(v, pool_w, pool_b, flags, scores);
    route_softmax_kernel<<<dim3(8), dim3(512), 0, stream>>>(scores, scs);
    route_pool_kernel<<<dim3(8, 8), dim3(256), 0, stream>>>(v, flags, scs, ppart);
    route_hid_kernel<<<dim3(12, 8), dim3(256), 0, stream>>>(w1, w2, flags, ppart, plog);
    route_alpha_kernel<<<dim3(8), dim3(64), 0, stream>>>(b2, flags, plog, alphas);
    gemm_kernel<<<dim3(12, 64), dim3(256), 0, stream>>>(v, Wv, bv, flags, 1, 2, (void*)vT, 2);
    gemm_kernel<<<dim3(12, 64), dim3(256), 0, stream>>>(k, Wk, bk, flags, 1, 2, (void*)kh, 0);
    gemm_kernel<<<dim3(12, 64), dim3(256), 0, stream>>>(q, Wq, bq, flags, 1, 2, (void*)qh, 0);
    attn_kernel<<<dim3(32, 12, 8), dim3(256), 0, stream>>>(qh, kh, vT, pm, alphas, atted);
    gemm_kernel<<<dim3(12, 64), dim3(256), 0, stream>>>(atted, Wm, bm, flags, -1, 2, d_out, 1);
}

// Round 6
// 358.422 us; speedup vs baseline: 3.2239x; 1.0216x over previous
//
#include <hip/hip_runtime.h>
#include <hip/hip_bf16.h>
#include <stdint.h>

// ---------------------------------------------------------------------------
// SARoutingBlock: alphas = soft_routing(v); qkv projections; 3-order masked
// softmax attention combined by alphas; output projection.
// B=8, N=512, HID=768, HEADS=12, dk=64, ORDERS=3.
// Round 6: XCD-aware 1-D grid swizzles. attn: id = bh + 96*qb so all 32
// q-blocks of one (b,h) share id%8 (same XCD L2) -> K/V stays resident.
// gemm: id = y + 64*x co-locates one X row-panel's 12 col-blocks per XCD.
// ---------------------------------------------------------------------------

typedef __bf16 bf16x8 __attribute__((ext_vector_type(8)));
typedef float f32x4 __attribute__((ext_vector_type(4)));

#define NEGV -1e9f

__device__ __forceinline__ float b2f(unsigned short h) {
    union { unsigned int u; float f; } x; x.u = ((unsigned int)h) << 16; return x.f;
}
__device__ __forceinline__ unsigned short f2b(float f) {
    union { float f; unsigned int u; } x; x.f = f;
    unsigned int u = x.u + 0x7FFFu + ((x.u >> 16) & 1u);
    return (unsigned short)(u >> 16);
}
__device__ __forceinline__ unsigned int packbf(unsigned int u0, unsigned int u1) {
    unsigned int r0 = (u0 + 0x7FFFu + ((u0 >> 16) & 1u)) >> 16;
    unsigned int r1 = (u1 + 0x7FFFu + ((u1 >> 16) & 1u)) & 0xFFFF0000u;
    return r0 | r1;
}
__device__ __forceinline__ uint4 load8bf(const void* base, size_t elemOff, int isF32) {
    if (!isF32) return *(const uint4*)((const unsigned short*)base + elemOff);
    const uint4* f = (const uint4*)((const float*)base + elemOff);
    uint4 a = f[0], b = f[1];
    uint4 r;
    r.x = packbf(a.x, a.y);
    r.y = packbf(a.z, a.w);
    r.z = packbf(b.x, b.y);
    r.w = packbf(b.z, b.w);
    return r;
}
__device__ __forceinline__ float loadF(const void* p, int idx, int isF32) {
    return isF32 ? ((const float*)p)[idx] : b2f(((const unsigned short*)p)[idx]);
}

// ---------------------------------------------------------------------------
// Sniffer: flags[0]=mask mode (0=i32,1=u8,2=f32,3=bf16); flags[1]=v/k/q dtype
// (0=bf16,1=f32); flags[2]=weights dtype.
// ---------------------------------------------------------------------------
__global__ void sniff_kernel(const unsigned int* __restrict__ mp,
                             const unsigned int* __restrict__ vp,
                             const unsigned int* __restrict__ wp,
                             int* __restrict__ flags)
{
    __shared__ int oki, oku, okf, badv, badw;
    if (threadIdx.x == 0) { oki = 1; oku = 1; okf = 1; badv = 0; badw = 0; }
    __syncthreads();
    int li = 1, lu = 1, lf = 1, bv = 0, bw = 0;
    for (int i = threadIdx.x; i < 16384; i += 256) {
        unsigned int w = mp[i];
        if (w > 1u) li = 0;
        if (w & 0xFEFEFEFEu) lu = 0;
        if (w != 0u && w != 0x3F800000u) lf = 0;
    }
    for (int i = threadIdx.x; i < 8192; i += 256) {
        unsigned int w = vp[i];
        float f0 = b2f((unsigned short)(w & 0xFFFF));
        float f1 = b2f((unsigned short)(w >> 16));
        if (!(fabsf(f0) < 1e4f) || !(fabsf(f1) < 1e4f)) bv = 1;
        w = wp[i];
        f0 = b2f((unsigned short)(w & 0xFFFF));
        f1 = b2f((unsigned short)(w >> 16));
        if (!(fabsf(f0) < 1e4f) || !(fabsf(f1) < 1e4f)) bw = 1;
    }
    if (!li) atomicAnd(&oki, 0);
    if (!lu) atomicAnd(&oku, 0);
    if (!lf) atomicAnd(&okf, 0);
    if (bv) atomicOr(&badv, 1);
    if (bw) atomicOr(&badw, 1);
    __syncthreads();
    if (threadIdx.x == 0) {
        flags[0] = oki ? 0 : (oku ? 1 : (okf ? 2 : 3));
        flags[1] = badv;
        flags[2] = badw;
    }
}

// ---------------------------------------------------------------------------
// Mask bit-pack: pm[grow*16 + lm], grow = (l*8+b)*512 + n,
// bit g = mask[l,b,n, g*16+lm]. One block packs 32 rows.
// ---------------------------------------------------------------------------
__global__ __launch_bounds__(256) void pack_kernel(
        const void* __restrict__ masks, const int* __restrict__ flags,
        unsigned int* __restrict__ pm)
{
    __shared__ unsigned char flg[32 * 512];
    const int t = threadIdx.x;
    const int mode = flags[0];
    const size_t e0 = (size_t)blockIdx.x * (32 * 512);
    if (mode == 0 || mode == 2) {
        const uint4* p = (const uint4*)((const unsigned int*)masks + e0);
        for (int i = t; i < 4096; i += 256) {
            uint4 u = p[i];
            int base = i << 2;
            flg[base + 0] = u.x ? 1 : 0;
            flg[base + 1] = u.y ? 1 : 0;
            flg[base + 2] = u.z ? 1 : 0;
            flg[base + 3] = u.w ? 1 : 0;
        }
    } else if (mode == 1) {
        const uint4* p = (const uint4*)((const unsigned char*)masks + e0);
        for (int i = t; i < 1024; i += 256) {
            uint4 u = p[i];
            unsigned int uu[4] = {u.x, u.y, u.z, u.w};
            int base = i << 4;
            #pragma unroll
            for (int k2 = 0; k2 < 4; k2++)
                #pragma unroll
                for (int bb = 0; bb < 4; bb++)
                    flg[base + k2 * 4 + bb] = ((uu[k2] >> (bb * 8)) & 0xFFu) ? 1 : 0;
        }
    } else {
        const uint4* p = (const uint4*)((const unsigned short*)masks + e0);
        for (int i = t; i < 2048; i += 256) {
            uint4 u = p[i];
            unsigned int uu[4] = {u.x, u.y, u.z, u.w};
            int base = i << 3;
            #pragma unroll
            for (int k2 = 0; k2 < 4; k2++) {
                flg[base + k2 * 2 + 0] = (uu[k2] & 0xFFFFu) ? 1 : 0;
                flg[base + k2 * 2 + 1] = (uu[k2] >> 16) ? 1 : 0;
            }
        }
    }
    __syncthreads();
    for (int widx = t; widx < 512; widx += 256) {
        int rl = widx >> 4, lm = widx & 15;
        unsigned int bits = 0;
        #pragma unroll
        for (int g = 0; g < 32; g++)
            bits |= ((unsigned int)(flg[rl * 512 + (g << 4) + lm] & 1)) << g;
        pm[(size_t)blockIdx.x * 512 + widx] = bits;
    }
}

// ---------------------------------------------------------------------------
// Routing stage 1: raw pooling scores per row (64 rows/block, 4 thr/row).
// ---------------------------------------------------------------------------
__global__ __launch_bounds__(256) void route_score_kernel(
        const void* __restrict__ v, const void* __restrict__ pool_w,
        const void* __restrict__ pool_b, const int* __restrict__ flags,
        float* __restrict__ scores)
{
    __shared__ float pw[768];
    const int t = threadIdx.x;
    const int b = blockIdx.x >> 3, ch = blockIdx.x & 7;
    const int dtV = flags[1], dtW = flags[2];
    for (int d = t; d < 768; d += 256) pw[d] = loadF(pool_w, d, dtW);
    __syncthreads();
    const int r = t >> 2, c4 = t & 3;
    const int n = (ch << 6) + r;
    float dot = 0.f, asum = 0.f;
    if (!dtV) {
        const unsigned int* vr = (const unsigned int*)v + ((size_t)(b * 512 + n)) * 384;
        for (int j = 0; j < 96; j++) {
            int p = c4 + (j << 2);
            unsigned int u = vr[p];
            float f0 = b2f((unsigned short)(u & 0xFFFF));
            float f1 = b2f((unsigned short)(u >> 16));
            asum += fabsf(f0) + fabsf(f1);
            dot += f0 * pw[2 * p] + f1 * pw[2 * p + 1];
        }
    } else {
        const float* vf = (const float*)v + ((size_t)(b * 512 + n)) * 768;
        for (int j = 0; j < 48; j++) {
            float4 u = ((const float4*)vf)[c4 + (j << 2)];
            int e = (c4 + (j << 2)) << 2;
            asum += fabsf(u.x) + fabsf(u.y) + fabsf(u.z) + fabsf(u.w);
            dot += u.x * pw[e] + u.y * pw[e + 1] + u.z * pw[e + 2] + u.w * pw[e + 3];
        }
    }
    dot += __shfl_xor(dot, 1); dot += __shfl_xor(dot, 2);
    asum += __shfl_xor(asum, 1); asum += __shfl_xor(asum, 2);
    if (c4 == 0)
        scores[b * 512 + n] = (asum == 0.f) ? NEGV : dot + loadF(pool_b, 0, dtW);
}

// ---------------------------------------------------------------------------
// Routing stage 2: softmax over N per batch -> scs. 8 blocks x 512.
// ---------------------------------------------------------------------------
__global__ __launch_bounds__(512) void route_softmax_kernel(
        const float* __restrict__ scores, float* __restrict__ scs)
{
    __shared__ float red[8];
    const int t = threadIdx.x, b = blockIdx.x;
    float scv = scores[b * 512 + t];
    float mx = scv;
    #pragma unroll
    for (int off = 1; off < 64; off <<= 1) mx = fmaxf(mx, __shfl_xor(mx, off));
    if ((t & 63) == 0) red[t >> 6] = mx;
    __syncthreads();
    float M = red[0];
    #pragma unroll
    for (int i = 1; i < 8; i++) M = fmaxf(M, red[i]);
    float e = __expf(scv - M);
    __syncthreads();
    float sm = e;
    #pragma unroll
    for (int off = 1; off < 64; off <<= 1) sm += __shfl_xor(sm, off);
    if ((t & 63) == 0) red[t >> 6] = sm;
    __syncthreads();
    float SS = 0.f;
    #pragma unroll
    for (int i = 0; i < 8; i++) SS += red[i];
    scs[b * 512 + t] = e / SS;
}

// ---------------------------------------------------------------------------
// Routing stage 3: partial pooled sums. Grid (8 chunks, 8 b), 256 thr.
// ---------------------------------------------------------------------------
__global__ __launch_bounds__(256) void route_pool_kernel(
        const void* __restrict__ v, const int* __restrict__ flags,
        const float* __restrict__ scs, float* __restrict__ ppart)
{
    __shared__ float ps[64];
    const int t = threadIdx.x;
    const int ch = blockIdx.x, b = blockIdx.y;
    const int dtV = flags[1];
    if (t < 64) ps[t] = scs[b * 512 + (ch << 6) + t];
    __syncthreads();
    const int d0 = t * 3;
    float a0 = 0.f, a1 = 0.f, a2 = 0.f;
    if (!dtV) {
        const unsigned short* vb = (const unsigned short*)v
            + ((size_t)(b * 512 + (ch << 6))) * 768 + d0;
        #pragma unroll 4
        for (int r = 0; r < 64; r++) {
            float p = ps[r];
            a0 += b2f(vb[0]) * p; a1 += b2f(vb[1]) * p; a2 += b2f(vb[2]) * p;
            vb += 768;
        }
    } else {
        const float* vb = (const float*)v + ((size_t)(b * 512 + (ch << 6))) * 768 + d0;
        #pragma unroll 4
        for (int r = 0; r < 64; r++) {
            float p = ps[r];
            a0 += vb[0] * p; a1 += vb[1] * p; a2 += vb[2] * p;
            vb += 768;
        }
    }
    float* o = ppart + ((size_t)(b * 8 + ch)) * 768 + d0;
    o[0] = a0; o[1] = a1; o[2] = a2;
}

// ---------------------------------------------------------------------------
// Routing stage 4: hidden units + partial logits. Grid (12 jc, 8 b), 256 thr.
// ---------------------------------------------------------------------------
__global__ __launch_bounds__(256) void route_hid_kernel(
        const void* __restrict__ w1, const void* __restrict__ w2,
        const int* __restrict__ flags, const float* __restrict__ ppart,
        float* __restrict__ plog)
{
    __shared__ float pool[768];
    __shared__ float red[4][32];
    const int t = threadIdx.x;
    const int jc = blockIdx.x, b = blockIdx.y;
    const int dtW = flags[2];
    for (int d = t; d < 768; d += 256) {
        float a = 0.f;
        #pragma unroll
        for (int c = 0; c < 8; c++) a += ppart[((size_t)(b * 8 + c)) * 768 + d];
        pool[d] = a;
    }
    __syncthreads();
    const int jo = (t & 3) << 3;
    const int dr = t >> 2;
    float acc[8];
    #pragma unroll
    for (int j = 0; j < 8; j++) acc[j] = 0.f;
    for (int it = 0; it < 12; it++) {
        int d = (it << 6) + dr;
        float pv = pool[d];
        size_t off = (size_t)d * 384 + (jc << 5) + jo;
        if (!dtW) {
            uint4 u = *(const uint4*)((const unsigned short*)w1 + off);
            unsigned int uu[4] = {u.x, u.y, u.z, u.w};
            #pragma unroll
            for (int j2 = 0; j2 < 4; j2++) {
                acc[2 * j2]     += pv * b2f((unsigned short)(uu[j2] & 0xFFFF));
                acc[2 * j2 + 1] += pv * b2f((unsigned short)(uu[j2] >> 16));
            }
        } else {
            const float4* f = (const float4*)((const float*)w1 + off);
            float4 u0 = f[0], u1 = f[1];
            acc[0] += pv * u0.x; acc[1] += pv * u0.y;
            acc[2] += pv * u0.z; acc[3] += pv * u0.w;
            acc[4] += pv * u1.x; acc[5] += pv * u1.y;
            acc[6] += pv * u1.z; acc[7] += pv * u1.w;
        }
    }
    #pragma unroll
    for (int off = 4; off < 64; off <<= 1)
        #pragma unroll
        for (int j = 0; j < 8; j++) acc[j] += __shfl_xor(acc[j], off);
    const int w = t >> 6, lane = t & 63;
    if (lane < 4) {
        #pragma unroll
        for (int j = 0; j < 8; j++) red[w][lane * 8 + j] = acc[j];
    }
    __syncthreads();
    if (t < 32) {
        float h = red[0][t] + red[1][t] + red[2][t] + red[3][t];
        h = fmaxf(h, 0.f);
        int jg = (jc << 5) + t;
        float l0 = h * loadF(w2, jg * 3 + 0, dtW);
        float l1 = h * loadF(w2, jg * 3 + 1, dtW);
        float l2 = h * loadF(w2, jg * 3 + 2, dtW);
        #pragma unroll
        for (int off = 1; off < 32; off <<= 1) {
            l0 += __shfl_xor(l0, off);
            l1 += __shfl_xor(l1, off);
            l2 += __shfl_xor(l2, off);
        }
        if (t == 0) {
            float* o = plog + ((size_t)(b * 12 + jc)) * 3;
            o[0] = l0; o[1] = l1; o[2] = l2;
        }
    }
}

// ---------------------------------------------------------------------------
// Routing stage 5: reduce partial logits, softmax -> alphas. 8 tiny blocks.
// ---------------------------------------------------------------------------
__global__ __launch_bounds__(64) void route_alpha_kernel(
        const void* __restrict__ b2, const int* __restrict__ flags,
        const float* __restrict__ plog, float* __restrict__ alphas)
{
    const int t = threadIdx.x, b = blockIdx.x;
    if (t == 0) {
        const int dtW = flags[2];
        float lg[3];
        #pragma unroll
        for (int l = 0; l < 3; l++) {
            float a = loadF(b2, l, dtW);
            for (int jc = 0; jc < 12; jc++) a += plog[((size_t)(b * 12 + jc)) * 3 + l];
            lg[l] = a;
        }
        float mm = fmaxf(lg[0], fmaxf(lg[1], lg[2]));
        float e0 = __expf(lg[0] - mm), e1 = __expf(lg[1] - mm), e2 = __expf(lg[2] - mm);
        float ss = e0 + e1 + e2;
        alphas[b * 3 + 0] = e0 / ss;
        alphas[b * 3 + 1] = e1 / ss;
        alphas[b * 3 + 2] = e2 / ss;
    }
}

// ---------------------------------------------------------------------------
// MFMA bf16 GEMM: C[4096x768] = X @ W + bias, 64x64 tile, 4 waves.
// 1-D grid, id = y + 64*x: co-locates one X row-panel's 12 col-blocks on one
// XCD (id%8 = y%8); whole W (2.25 MB) fits each XCD L2.
// mode 0: dst[b][h][n][64] bf16 ; mode 1: dst[row][col] (bf16 or f32)
// mode 2: dst[b][h][64][n] bf16 (transposed V)
// ---------------------------------------------------------------------------
__global__ __launch_bounds__(256) void gemm_kernel(
        const void* __restrict__ X,
        const void* __restrict__ W,
        const void* __restrict__ bias,
        const int* __restrict__ flags, int xsel, int wsel,
        void* __restrict__ dst, int mode)
{
    __shared__ unsigned short smem[64 * 72];
    unsigned short* At = smem;
    unsigned short* Bt = smem + 2048;
    const int t = threadIdx.x;
    const int id = blockIdx.x;
    const int bx = id >> 6, by = id & 63;     // bx = col-panel, by = row-panel
    const int w = t >> 6, lane = t & 63, q = lane >> 4, lm = lane & 15;
    const int row0 = by << 6, col0 = bx << 6;
    const int ar = t >> 2, ac = (t & 3) << 3;
    const int bk = t >> 3, bc = t & 7;
    const int aswz = ((ar >> 3) & 3) << 3;
    const int bswz = (bc & 3) << 3;
    const int am = (w << 4) + lm;
    const int acs = ((am >> 3) & 3) << 3;
    const int dtX = (xsel >= 0) ? flags[xsel] : 0;
    const int dtW = flags[wsel];
    const int dtOut = flags[1];

    f32x4 acc[4];
    #pragma unroll
    for (int i = 0; i < 4; i++) acc[i] = (f32x4){0.f, 0.f, 0.f, 0.f};

    for (int k0 = 0; k0 < 768; k0 += 32) {
        uint4 av = load8bf(X, (size_t)(row0 + ar) * 768 + k0 + ac, dtX);
        uint4 wv = load8bf(W, (size_t)(k0 + bk) * 768 + col0 + (bc << 3), dtW);
        __syncthreads();
        *(uint4*)(&At[ar * 32 + (ac ^ aswz)]) = av;
        {
            unsigned short* bp = &Bt[(bc << 3) * 32 + (bk ^ bswz)];
            unsigned int uu[4] = {wv.x, wv.y, wv.z, wv.w};
            #pragma unroll
            for (int j = 0; j < 4; j++) {
                bp[(2 * j) * 32] = (unsigned short)(uu[j] & 0xFFFF);
                bp[(2 * j + 1) * 32] = (unsigned short)(uu[j] >> 16);
            }
        }
        __syncthreads();
        bf16x8 afr = *(const bf16x8*)(&At[am * 32 + ((q << 3) ^ acs)]);
        #pragma unroll
        for (int t4 = 0; t4 < 4; t4++) {
            int bn = (t4 << 4) + lm;
            bf16x8 bfr = *(const bf16x8*)(&Bt[bn * 32 + ((q << 3) ^ (((bn >> 3) & 3) << 3))]);
            acc[t4] = __builtin_amdgcn_mfma_f32_16x16x32_bf16(afr, bfr, acc[t4], 0, 0, 0);
        }
    }

    if (mode == 1 && dtOut) {
        #pragma unroll
        for (int t4 = 0; t4 < 4; t4++) {
            int col = col0 + (t4 << 4) + lm;
            float bsv = loadF(bias, col, dtW);
            #pragma unroll
            for (int rg = 0; rg < 4; rg++) {
                int row = row0 + (w << 4) + (q << 2) + rg;
                ((float*)dst)[(size_t)row * 768 + col] = acc[t4][rg] + bsv;
            }
        }
        return;
    }

    __syncthreads();
    #pragma unroll
    for (int t4 = 0; t4 < 4; t4++) {
        int colL = (t4 << 4) + lm;
        float bsv = loadF(bias, col0 + colL, dtW);
        #pragma unroll
        for (int rg = 0; rg < 4; rg++) {
            int rowL = (w << 4) + (q << 2) + rg;
            unsigned short hv = f2b(acc[t4][rg] + bsv);
            if (mode == 2) smem[colL * 72 + rowL] = hv;
            else           smem[rowL * 72 + colL] = hv;
        }
    }
    __syncthreads();
    const int g = t >> 2, c0 = (t & 3) << 4;
    uint4 w0 = *(const uint4*)&smem[g * 72 + c0];
    uint4 w1v = *(const uint4*)&smem[g * 72 + c0 + 8];
    unsigned short* o;
    if (mode == 0) {
        int b = row0 >> 9, n0b = row0 & 511, h = col0 >> 6;
        o = (unsigned short*)dst + ((size_t)(b * 12 + h) * 512 + n0b + g) * 64 + c0;
    } else if (mode == 2) {
        int b = row0 >> 9, n0b = row0 & 511, h = col0 >> 6;
        o = (unsigned short*)dst + ((size_t)(b * 12 + h) * 64 + g) * 512 + n0b + c0;
    } else {
        o = (unsigned short*)dst + (size_t)(row0 + g) * 768 + col0 + c0;
    }
    *(uint4*)o = w0;
    *(uint4*)(o + 8) = w1v;
}

// ---------------------------------------------------------------------------
// MFMA attention. Block = 16 Q rows of one (b,h). 4 waves.
// 1-D grid, id = bh + 96*qb: all 32 q-blocks of a (b,h) share id%8 -> same
// XCD -> K/V working set (128 KB) stays in that XCD's L2.
// ---------------------------------------------------------------------------
__global__ __launch_bounds__(256) void attn_kernel(
        const unsigned short* __restrict__ qh, const unsigned short* __restrict__ kh,
        const unsigned short* __restrict__ vT, const unsigned int* __restrict__ pm,
        const float* __restrict__ alphas, unsigned short* __restrict__ atted)
{
    __shared__ unsigned short P[16 * 512];
    __shared__ float Zp[4][16][3];
    __shared__ unsigned short Ost[16 * 72];
    const int t = threadIdx.x;
    const int w = t >> 6, lane = t & 63, quad = lane >> 4, lm = lane & 15;
    const int id = blockIdx.x;
    const int bh = id % 96, qb = id / 96;
    const int b = bh / 12, h = bh % 12;
    const int n0 = qb << 4;

    const unsigned short* qrow = qh + ((size_t)(bh * 512 + n0 + lm)) * 64 + (quad << 3);
    bf16x8 qa0 = *(const bf16x8*)qrow;
    bf16x8 qa1 = *(const bf16x8*)(qrow + 32);
    f32x4 acc[8];
    #pragma unroll
    for (int i = 0; i < 8; i++) acc[i] = (f32x4){0.f, 0.f, 0.f, 0.f};
    const unsigned short* kb0 = kh + ((size_t)(bh * 512 + (w << 7) + lm)) * 64 + (quad << 3);
    #pragma unroll
    for (int nt = 0; nt < 8; nt++) {
        const unsigned short* kr = kb0 + nt * (16 * 64);
        bf16x8 k0 = *(const bf16x8*)kr;
        bf16x8 k1 = *(const bf16x8*)(kr + 32);
        acc[nt] = __builtin_amdgcn_mfma_f32_16x16x32_bf16(qa0, k0, acc[nt], 0, 0, 0);
        acc[nt] = __builtin_amdgcn_mfma_f32_16x16x32_bf16(qa1, k1, acc[nt], 0, 0, 0);
    }

    float al[3];
    #pragma unroll
    for (int l = 0; l < 3; l++) al[l] = alphas[b * 3 + l];

    #pragma unroll
    for (int nt = 0; nt < 8; nt++)
        #pragma unroll
        for (int rg = 0; rg < 4; rg++)
            acc[nt][rg] = __expf(acc[nt][rg] * 0.125f);

    unsigned int mk[4][3];
    #pragma unroll
    for (int rg = 0; rg < 4; rg++)
        #pragma unroll
        for (int l = 0; l < 3; l++)
            mk[rg][l] = pm[((size_t)((l << 3) + b) * 512 + n0 + (quad << 2) + rg) * 16 + lm];

    #pragma unroll
    for (int rg = 0; rg < 4; rg++) {
        float z0 = 0.f, z1 = 0.f, z2 = 0.f;
        #pragma unroll
        for (int nt = 0; nt < 8; nt++) {
            int g = (w << 3) + nt;
            float e = acc[nt][rg];
            if (!((mk[rg][0] >> g) & 1)) z0 += e;
            if (!((mk[rg][1] >> g) & 1)) z1 += e;
            if (!((mk[rg][2] >> g) & 1)) z2 += e;
        }
        #pragma unroll
        for (int off = 1; off < 16; off <<= 1) {
            z0 += __shfl_xor(z0, off);
            z1 += __shfl_xor(z1, off);
            z2 += __shfl_xor(z2, off);
        }
        if (lm == 0) {
            int row = (quad << 2) + rg;
            Zp[w][row][0] = z0; Zp[w][row][1] = z1; Zp[w][row][2] = z2;
        }
    }
    __syncthreads();

    #pragma unroll
    for (int rg = 0; rg < 4; rg++) {
        int row = (quad << 2) + rg;
        float coef[3]; float addu = 0.f;
        #pragma unroll
        for (int l = 0; l < 3; l++) {
            float Z = Zp[0][row][l] + Zp[1][row][l] + Zp[2][row][l] + Zp[3][row][l];
            if (Z > 0.f) coef[l] = al[l] / Z;
            else { coef[l] = 0.f; addu += al[l] * (1.0f / 512.0f); }
        }
        #pragma unroll
        for (int nt = 0; nt < 8; nt++) {
            int g = (w << 3) + nt;
            float p = addu;
            float e = acc[nt][rg];
            if (!((mk[rg][0] >> g) & 1)) p += coef[0] * e;
            if (!((mk[rg][1] >> g) & 1)) p += coef[1] * e;
            if (!((mk[rg][2] >> g) & 1)) p += coef[2] * e;
            int c = (g << 4) + lm;
            int chunk = c >> 3, j = c & 7;
            P[row * 512 + (((chunk ^ (row & 7))) << 3) + j] = f2b(p);
        }
    }
    __syncthreads();

    f32x4 accO = (f32x4){0.f, 0.f, 0.f, 0.f};
    const unsigned short* vb = vT + ((size_t)(bh * 64 + (w << 4) + lm)) * 512 + (quad << 3);
    #pragma unroll
    for (int ks = 0; ks < 16; ks++) {
        bf16x8 pa = *(const bf16x8*)&P[lm * 512 + ((((ks << 2) + quad) ^ (lm & 7)) << 3)];
        bf16x8 vf = *(const bf16x8*)(vb + (ks << 5));
        accO = __builtin_amdgcn_mfma_f32_16x16x32_bf16(pa, vf, accO, 0, 0, 0);
    }
    #pragma unroll
    for (int rg = 0; rg < 4; rg++)
        Ost[((quad << 2) + rg) * 72 + (w << 4) + lm] = f2b(accO[rg]);
    __syncthreads();
    const int r2 = t >> 4, c4 = t & 15;
    uint2 val = *(const uint2*)&Ost[r2 * 72 + (c4 << 2)];
    *(uint2*)&atted[((size_t)(b * 512 + n0 + r2)) * 768 + (h << 6) + (c4 << 2)] = val;
}

// ---------------------------------------------------------------------------
extern "C" void kernel_launch(void* const* d_in, const int* in_sizes, int n_in,
                              void* d_out, int out_size, void* d_ws, size_t ws_size,
                              hipStream_t stream)
{
    const void* v  = d_in[0];
    const void* k  = d_in[1];
    const void* q  = d_in[2];
    const void* mk = d_in[3];
    const void* Wv = d_in[6];
    const void* bv = d_in[7];
    const void* Wk = d_in[8];
    const void* bk = d_in[9];
    const void* Wq = d_in[10];
    const void* bq = d_in[11];
    const void* Wm = d_in[12];
    const void* bm = d_in[13];
    const void* pool_w = d_in[14];
    const void* pool_b = d_in[15];
    const void* w1 = d_in[16];
    const void* w2 = d_in[17];
    const void* b2 = d_in[18];

    char* ws = (char*)d_ws;
    int*   flags  = (int*)ws;                                   // 64 B
    float* alphas = (float*)(ws + 256);                         // 96 B
    float* scores = (float*)(ws + 512);                         // 16 KB
    float* scs    = (float*)(ws + 16896);                       // 16 KB
    float* ppart  = (float*)(ws + 33280);                       // 196 KB
    float* plog   = (float*)(ws + 229888);                      // 1.2 KB
    unsigned int* pm = (unsigned int*)(ws + 262144);            // 786 KB
    unsigned short* qh    = (unsigned short*)(ws + 1048576);    // 6.29 MB each
    unsigned short* kh    = (unsigned short*)(ws + 1048576 + 6291456L);
    unsigned short* vT    = (unsigned short*)(ws + 1048576 + 2 * 6291456L);
    unsigned short* atted = (unsigned short*)(ws + 1048576 + 3 * 6291456L);

    sniff_kernel<<<dim3(1), dim3(256), 0, stream>>>(
        (const unsigned int*)mk, (const unsigned int*)v, (const unsigned int*)Wv, flags);
    pack_kernel<<<dim3(384), dim3(256), 0, stream>>>(mk, flags, pm);
    route_score_kernel<<<dim3(64), dim3(256), 0, stream>>>(v, pool_w, pool_b, flags, scores);
    route_softmax_kernel<<<dim3(8), dim3(512), 0, stream>>>(scores, scs);
    route_pool_kernel<<<dim3(8, 8), dim3(256), 0, stream>>>(v, flags, scs, ppart);
    route_hid_kernel<<<dim3(12, 8), dim3(256), 0, stream>>>(w1, w2, flags, ppart, plog);
    route_alpha_kernel<<<dim3(8), dim3(64), 0, stream>>>(b2, flags, plog, alphas);
    gemm_kernel<<<dim3(768), dim3(256), 0, stream>>>(v, Wv, bv, flags, 1, 2, (void*)vT, 2);
    gemm_kernel<<<dim3(768), dim3(256), 0, stream>>>(k, Wk, bk, flags, 1, 2, (void*)kh, 0);
    gemm_kernel<<<dim3(768), dim3(256), 0, stream>>>(q, Wq, bq, flags, 1, 2, (void*)qh, 0);
    attn_kernel<<<dim3(3072), dim3(256), 0, stream>>>(qh, kh, vT, pm, alphas, atted);
    gemm_kernel<<<dim3(768), dim3(256), 0, stream>>>(atted, Wm, bm, flags, -1, 2, d_out, 1);
}

// Round 7
// 314.019 us; speedup vs baseline: 3.6798x; 1.1414x over previous
//
#include <hip/hip_runtime.h>
#include <hip/hip_bf16.h>
#include <stdint.h>

// ---------------------------------------------------------------------------
// SARoutingBlock. Round 7: hoist fp32->bf16 conversion + W transpose out of
// the GEMM K-loop (conv_act / conv_wt pre-passes); GEMM stages both A and B
// with contiguous uint4 -> ds_write_b128 (no per-element repack/scatter).
// atted aliases vb to stay in the known-good workspace budget.
// ---------------------------------------------------------------------------

typedef __bf16 bf16x8 __attribute__((ext_vector_type(8)));
typedef float f32x4 __attribute__((ext_vector_type(4)));

#define NEGV -1e9f

__device__ __forceinline__ float b2f(unsigned short h) {
    union { unsigned int u; float f; } x; x.u = ((unsigned int)h) << 16; return x.f;
}
__device__ __forceinline__ unsigned short f2b(float f) {
    union { float f; unsigned int u; } x; x.f = f;
    unsigned int u = x.u + 0x7FFFu + ((x.u >> 16) & 1u);
    return (unsigned short)(u >> 16);
}
__device__ __forceinline__ unsigned int packbf(unsigned int u0, unsigned int u1) {
    unsigned int r0 = (u0 + 0x7FFFu + ((u0 >> 16) & 1u)) >> 16;
    unsigned int r1 = (u1 + 0x7FFFu + ((u1 >> 16) & 1u)) & 0xFFFF0000u;
    return r0 | r1;
}
__device__ __forceinline__ uint4 load8bf(const void* base, size_t elemOff, int isF32) {
    if (!isF32) return *(const uint4*)((const unsigned short*)base + elemOff);
    const uint4* f = (const uint4*)((const float*)base + elemOff);
    uint4 a = f[0], b = f[1];
    uint4 r;
    r.x = packbf(a.x, a.y);
    r.y = packbf(a.z, a.w);
    r.z = packbf(b.x, b.y);
    r.w = packbf(b.z, b.w);
    return r;
}
__device__ __forceinline__ float loadF(const void* p, int idx, int isF32) {
    return isF32 ? ((const float*)p)[idx] : b2f(((const unsigned short*)p)[idx]);
}

// ---------------------------------------------------------------------------
// Sniffer: flags[0]=mask mode (0=i32,1=u8,2=f32,3=bf16); flags[1]=v/k/q dtype
// (0=bf16,1=f32); flags[2]=weights dtype.
// ---------------------------------------------------------------------------
__global__ void sniff_kernel(const unsigned int* __restrict__ mp,
                             const unsigned int* __restrict__ vp,
                             const unsigned int* __restrict__ wp,
                             int* __restrict__ flags)
{
    __shared__ int oki, oku, okf, badv, badw;
    if (threadIdx.x == 0) { oki = 1; oku = 1; okf = 1; badv = 0; badw = 0; }
    __syncthreads();
    int li = 1, lu = 1, lf = 1, bv = 0, bw = 0;
    for (int i = threadIdx.x; i < 16384; i += 256) {
        unsigned int w = mp[i];
        if (w > 1u) li = 0;
        if (w & 0xFEFEFEFEu) lu = 0;
        if (w != 0u && w != 0x3F800000u) lf = 0;
    }
    for (int i = threadIdx.x; i < 8192; i += 256) {
        unsigned int w = vp[i];
        float f0 = b2f((unsigned short)(w & 0xFFFF));
        float f1 = b2f((unsigned short)(w >> 16));
        if (!(fabsf(f0) < 1e4f) || !(fabsf(f1) < 1e4f)) bv = 1;
        w = wp[i];
        f0 = b2f((unsigned short)(w & 0xFFFF));
        f1 = b2f((unsigned short)(w >> 16));
        if (!(fabsf(f0) < 1e4f) || !(fabsf(f1) < 1e4f)) bw = 1;
    }
    if (!li) atomicAnd(&oki, 0);
    if (!lu) atomicAnd(&oku, 0);
    if (!lf) atomicAnd(&okf, 0);
    if (bv) atomicOr(&badv, 1);
    if (bw) atomicOr(&badw, 1);
    __syncthreads();
    if (threadIdx.x == 0) {
        flags[0] = oki ? 0 : (oku ? 1 : (okf ? 2 : 3));
        flags[1] = badv;
        flags[2] = badw;
    }
}

// ---------------------------------------------------------------------------
// conv_act: v,k,q -> contiguous bf16 copies. Grid (1536, 3) x 256 thr, 8/thr.
// ---------------------------------------------------------------------------
__global__ __launch_bounds__(256) void conv_act_kernel(
        const void* __restrict__ v, const void* __restrict__ k,
        const void* __restrict__ q, const int* __restrict__ flags,
        unsigned short* __restrict__ vb, unsigned short* __restrict__ kb,
        unsigned short* __restrict__ qb)
{
    const int dtV = flags[1];
    const int which = blockIdx.y;
    const void* src = (which == 0) ? v : (which == 1) ? k : q;
    unsigned short* dst = (which == 0) ? vb : (which == 1) ? kb : qb;
    size_t off = ((size_t)blockIdx.x * 256 + threadIdx.x) * 8;
    uint4 r = load8bf(src, off, dtV);
    *(uint4*)(dst + off) = r;
}

// ---------------------------------------------------------------------------
// conv_wt: W[768][768] -> WT bf16 [n][k] (transposed). Grid (144, 4), 256 thr.
// 64x64 tile via LDS (pad 65 shorts).
// ---------------------------------------------------------------------------
__global__ __launch_bounds__(256) void conv_wt_kernel(
        const void* __restrict__ W0, const void* __restrict__ W1,
        const void* __restrict__ W2, const void* __restrict__ W3,
        const int* __restrict__ flags,
        unsigned short* __restrict__ T0, unsigned short* __restrict__ T1,
        unsigned short* __restrict__ T2, unsigned short* __restrict__ T3)
{
    __shared__ unsigned short tile[64][65];
    const int t = threadIdx.x;
    const int dtW = flags[2];
    const int which = blockIdx.y;
    const void* W = (which == 0) ? W0 : (which == 1) ? W1 : (which == 2) ? W2 : W3;
    unsigned short* T = (which == 0) ? T0 : (which == 1) ? T1 : (which == 2) ? T2 : T3;
    const int tk = (blockIdx.x / 12) << 6;
    const int tn = (blockIdx.x % 12) << 6;
    #pragma unroll
    for (int i = 0; i < 16; i++) {
        int idx = (i << 8) + t;
        int r = idx >> 6, c = idx & 63;
        tile[r][c] = f2b(loadF(W, (tk + r) * 768 + tn + c, dtW));
    }
    __syncthreads();
    #pragma unroll
    for (int i = 0; i < 16; i++) {
        int idx = (i << 8) + t;
        int rn = idx >> 6, ck = idx & 63;
        T[(size_t)(tn + rn) * 768 + tk + ck] = tile[ck][rn];
    }
}

// ---------------------------------------------------------------------------
// Mask bit-pack: pm[grow*16 + lm], grow = (l*8+b)*512 + n,
// bit g = mask[l,b,n, g*16+lm]. One block packs 32 rows.
// ---------------------------------------------------------------------------
__global__ __launch_bounds__(256) void pack_kernel(
        const void* __restrict__ masks, const int* __restrict__ flags,
        unsigned int* __restrict__ pm)
{
    __shared__ unsigned char flg[32 * 512];
    const int t = threadIdx.x;
    const int mode = flags[0];
    const size_t e0 = (size_t)blockIdx.x * (32 * 512);
    if (mode == 0 || mode == 2) {
        const uint4* p = (const uint4*)((const unsigned int*)masks + e0);
        for (int i = t; i < 4096; i += 256) {
            uint4 u = p[i];
            int base = i << 2;
            flg[base + 0] = u.x ? 1 : 0;
            flg[base + 1] = u.y ? 1 : 0;
            flg[base + 2] = u.z ? 1 : 0;
            flg[base + 3] = u.w ? 1 : 0;
        }
    } else if (mode == 1) {
        const uint4* p = (const uint4*)((const unsigned char*)masks + e0);
        for (int i = t; i < 1024; i += 256) {
            uint4 u = p[i];
            unsigned int uu[4] = {u.x, u.y, u.z, u.w};
            int base = i << 4;
            #pragma unroll
            for (int k2 = 0; k2 < 4; k2++)
                #pragma unroll
                for (int bb = 0; bb < 4; bb++)
                    flg[base + k2 * 4 + bb] = ((uu[k2] >> (bb * 8)) & 0xFFu) ? 1 : 0;
        }
    } else {
        const uint4* p = (const uint4*)((const unsigned short*)masks + e0);
        for (int i = t; i < 2048; i += 256) {
            uint4 u = p[i];
            unsigned int uu[4] = {u.x, u.y, u.z, u.w};
            int base = i << 3;
            #pragma unroll
            for (int k2 = 0; k2 < 4; k2++) {
                flg[base + k2 * 2 + 0] = (uu[k2] & 0xFFFFu) ? 1 : 0;
                flg[base + k2 * 2 + 1] = (uu[k2] >> 16) ? 1 : 0;
            }
        }
    }
    __syncthreads();
    for (int widx = t; widx < 512; widx += 256) {
        int rl = widx >> 4, lm = widx & 15;
        unsigned int bits = 0;
        #pragma unroll
        for (int g = 0; g < 32; g++)
            bits |= ((unsigned int)(flg[rl * 512 + (g << 4) + lm] & 1)) << g;
        pm[(size_t)blockIdx.x * 512 + widx] = bits;
    }
}

// ---------------------------------------------------------------------------
// Routing stage 1: raw pooling scores per row (64 rows/block, 4 thr/row).
// ---------------------------------------------------------------------------
__global__ __launch_bounds__(256) void route_score_kernel(
        const void* __restrict__ v, const void* __restrict__ pool_w,
        const void* __restrict__ pool_b, const int* __restrict__ flags,
        float* __restrict__ scores)
{
    __shared__ float pw[768];
    const int t = threadIdx.x;
    const int b = blockIdx.x >> 3, ch = blockIdx.x & 7;
    const int dtV = flags[1], dtW = flags[2];
    for (int d = t; d < 768; d += 256) pw[d] = loadF(pool_w, d, dtW);
    __syncthreads();
    const int r = t >> 2, c4 = t & 3;
    const int n = (ch << 6) + r;
    float dot = 0.f, asum = 0.f;
    if (!dtV) {
        const unsigned int* vr = (const unsigned int*)v + ((size_t)(b * 512 + n)) * 384;
        for (int j = 0; j < 96; j++) {
            int p = c4 + (j << 2);
            unsigned int u = vr[p];
            float f0 = b2f((unsigned short)(u & 0xFFFF));
            float f1 = b2f((unsigned short)(u >> 16));
            asum += fabsf(f0) + fabsf(f1);
            dot += f0 * pw[2 * p] + f1 * pw[2 * p + 1];
        }
    } else {
        const float* vf = (const float*)v + ((size_t)(b * 512 + n)) * 768;
        for (int j = 0; j < 48; j++) {
            float4 u = ((const float4*)vf)[c4 + (j << 2)];
            int e = (c4 + (j << 2)) << 2;
            asum += fabsf(u.x) + fabsf(u.y) + fabsf(u.z) + fabsf(u.w);
            dot += u.x * pw[e] + u.y * pw[e + 1] + u.z * pw[e + 2] + u.w * pw[e + 3];
        }
    }
    dot += __shfl_xor(dot, 1); dot += __shfl_xor(dot, 2);
    asum += __shfl_xor(asum, 1); asum += __shfl_xor(asum, 2);
    if (c4 == 0)
        scores[b * 512 + n] = (asum == 0.f) ? NEGV : dot + loadF(pool_b, 0, dtW);
}

// ---------------------------------------------------------------------------
// Routing stage 2: softmax over N per batch -> scs. 8 blocks x 512.
// ---------------------------------------------------------------------------
__global__ __launch_bounds__(512) void route_softmax_kernel(
        const float* __restrict__ scores, float* __restrict__ scs)
{
    __shared__ float red[8];
    const int t = threadIdx.x, b = blockIdx.x;
    float scv = scores[b * 512 + t];
    float mx = scv;
    #pragma unroll
    for (int off = 1; off < 64; off <<= 1) mx = fmaxf(mx, __shfl_xor(mx, off));
    if ((t & 63) == 0) red[t >> 6] = mx;
    __syncthreads();
    float M = red[0];
    #pragma unroll
    for (int i = 1; i < 8; i++) M = fmaxf(M, red[i]);
    float e = __expf(scv - M);
    __syncthreads();
    float sm = e;
    #pragma unroll
    for (int off = 1; off < 64; off <<= 1) sm += __shfl_xor(sm, off);
    if ((t & 63) == 0) red[t >> 6] = sm;
    __syncthreads();
    float SS = 0.f;
    #pragma unroll
    for (int i = 0; i < 8; i++) SS += red[i];
    scs[b * 512 + t] = e / SS;
}

// ---------------------------------------------------------------------------
// Routing stage 3: partial pooled sums. Grid (8 chunks, 8 b), 256 thr.
// ---------------------------------------------------------------------------
__global__ __launch_bounds__(256) void route_pool_kernel(
        const void* __restrict__ v, const int* __restrict__ flags,
        const float* __restrict__ scs, float* __restrict__ ppart)
{
    __shared__ float ps[64];
    const int t = threadIdx.x;
    const int ch = blockIdx.x, b = blockIdx.y;
    const int dtV = flags[1];
    if (t < 64) ps[t] = scs[b * 512 + (ch << 6) + t];
    __syncthreads();
    const int d0 = t * 3;
    float a0 = 0.f, a1 = 0.f, a2 = 0.f;
    if (!dtV) {
        const unsigned short* vb = (const unsigned short*)v
            + ((size_t)(b * 512 + (ch << 6))) * 768 + d0;
        #pragma unroll 4
        for (int r = 0; r < 64; r++) {
            float p = ps[r];
            a0 += b2f(vb[0]) * p; a1 += b2f(vb[1]) * p; a2 += b2f(vb[2]) * p;
            vb += 768;
        }
    } else {
        const float* vb = (const float*)v + ((size_t)(b * 512 + (ch << 6))) * 768 + d0;
        #pragma unroll 4
        for (int r = 0; r < 64; r++) {
            float p = ps[r];
            a0 += vb[0] * p; a1 += vb[1] * p; a2 += vb[2] * p;
            vb += 768;
        }
    }
    float* o = ppart + ((size_t)(b * 8 + ch)) * 768 + d0;
    o[0] = a0; o[1] = a1; o[2] = a2;
}

// ---------------------------------------------------------------------------
// Routing stage 4: hidden units + partial logits. Grid (12 jc, 8 b), 256 thr.
// ---------------------------------------------------------------------------
__global__ __launch_bounds__(256) void route_hid_kernel(
        const void* __restrict__ w1, const void* __restrict__ w2,
        const int* __restrict__ flags, const float* __restrict__ ppart,
        float* __restrict__ plog)
{
    __shared__ float pool[768];
    __shared__ float red[4][32];
    const int t = threadIdx.x;
    const int jc = blockIdx.x, b = blockIdx.y;
    const int dtW = flags[2];
    for (int d = t; d < 768; d += 256) {
        float a = 0.f;
        #pragma unroll
        for (int c = 0; c < 8; c++) a += ppart[((size_t)(b * 8 + c)) * 768 + d];
        pool[d] = a;
    }
    __syncthreads();
    const int jo = (t & 3) << 3;
    const int dr = t >> 2;
    float acc[8];
    #pragma unroll
    for (int j = 0; j < 8; j++) acc[j] = 0.f;
    for (int it = 0; it < 12; it++) {
        int d = (it << 6) + dr;
        float pv = pool[d];
        size_t off = (size_t)d * 384 + (jc << 5) + jo;
        if (!dtW) {
            uint4 u = *(const uint4*)((const unsigned short*)w1 + off);
            unsigned int uu[4] = {u.x, u.y, u.z, u.w};
            #pragma unroll
            for (int j2 = 0; j2 < 4; j2++) {
                acc[2 * j2]     += pv * b2f((unsigned short)(uu[j2] & 0xFFFF));
                acc[2 * j2 + 1] += pv * b2f((unsigned short)(uu[j2] >> 16));
            }
        } else {
            const float4* f = (const float4*)((const float*)w1 + off);
            float4 u0 = f[0], u1 = f[1];
            acc[0] += pv * u0.x; acc[1] += pv * u0.y;
            acc[2] += pv * u0.z; acc[3] += pv * u0.w;
            acc[4] += pv * u1.x; acc[5] += pv * u1.y;
            acc[6] += pv * u1.z; acc[7] += pv * u1.w;
        }
    }
    #pragma unroll
    for (int off = 4; off < 64; off <<= 1)
        #pragma unroll
        for (int j = 0; j < 8; j++) acc[j] += __shfl_xor(acc[j], off);
    const int w = t >> 6, lane = t & 63;
    if (lane < 4) {
        #pragma unroll
        for (int j = 0; j < 8; j++) red[w][lane * 8 + j] = acc[j];
    }
    __syncthreads();
    if (t < 32) {
        float h = red[0][t] + red[1][t] + red[2][t] + red[3][t];
        h = fmaxf(h, 0.f);
        int jg = (jc << 5) + t;
        float l0 = h * loadF(w2, jg * 3 + 0, dtW);
        float l1 = h * loadF(w2, jg * 3 + 1, dtW);
        float l2 = h * loadF(w2, jg * 3 + 2, dtW);
        #pragma unroll
        for (int off = 1; off < 32; off <<= 1) {
            l0 += __shfl_xor(l0, off);
            l1 += __shfl_xor(l1, off);
            l2 += __shfl_xor(l2, off);
        }
        if (t == 0) {
            float* o = plog + ((size_t)(b * 12 + jc)) * 3;
            o[0] = l0; o[1] = l1; o[2] = l2;
        }
    }
}

// ---------------------------------------------------------------------------
// Routing stage 5: reduce partial logits, softmax -> alphas. 8 tiny blocks.
// ---------------------------------------------------------------------------
__global__ __launch_bounds__(64) void route_alpha_kernel(
        const void* __restrict__ b2, const int* __restrict__ flags,
        const float* __restrict__ plog, float* __restrict__ alphas)
{
    const int t = threadIdx.x, b = blockIdx.x;
    if (t == 0) {
        const int dtW = flags[2];
        float lg[3];
        #pragma unroll
        for (int l = 0; l < 3; l++) {
            float a = loadF(b2, l, dtW);
            for (int jc = 0; jc < 12; jc++) a += plog[((size_t)(b * 12 + jc)) * 3 + l];
            lg[l] = a;
        }
        float mm = fmaxf(lg[0], fmaxf(lg[1], lg[2]));
        float e0 = __expf(lg[0] - mm), e1 = __expf(lg[1] - mm), e2 = __expf(lg[2] - mm);
        float ss = e0 + e1 + e2;
        alphas[b * 3 + 0] = e0 / ss;
        alphas[b * 3 + 1] = e1 / ss;
        alphas[b * 3 + 2] = e2 / ss;
    }
}

// ---------------------------------------------------------------------------
// MFMA bf16 GEMM: C[4096x768] = X @ W + bias. X bf16 [row][k]; WT bf16 [n][k]
// (pre-transposed). 64x64 tile, 4 waves; both tiles staged uint4->b128.
// 1-D grid id = y + 64*x (XCD co-location of a row-panel's col-blocks).
// mode 0: dst[b][h][n][64] bf16 ; mode 1: dst[row][col] (bf16, or f32 if
// activations were f32) ; mode 2: dst[b][h][64][n] bf16 (transposed V).
// ---------------------------------------------------------------------------
__global__ __launch_bounds__(256) void gemm_kernel(
        const unsigned short* __restrict__ X,
        const unsigned short* __restrict__ WT,
        const void* __restrict__ bias,
        const int* __restrict__ flags,
        void* __restrict__ dst, int mode)
{
    __shared__ unsigned short smem[64 * 72];
    unsigned short* At = smem;
    unsigned short* Bt = smem + 2048;
    const int t = threadIdx.x;
    const int id = blockIdx.x;
    const int bx = id >> 6, by = id & 63;
    const int w = t >> 6, lane = t & 63, q = lane >> 4, lm = lane & 15;
    const int row0 = by << 6, col0 = bx << 6;
    const int ar = t >> 2, ac = (t & 3) << 3;
    const int aswz = ((ar >> 3) & 3) << 3;
    const int am = (w << 4) + lm;
    const int acs = ((am >> 3) & 3) << 3;
    const int dtW = flags[2];
    const int dtOut = flags[1];

    f32x4 acc[4];
    #pragma unroll
    for (int i = 0; i < 4; i++) acc[i] = (f32x4){0.f, 0.f, 0.f, 0.f};

    const unsigned short* xp = X + (size_t)(row0 + ar) * 768 + ac;
    const unsigned short* wp = WT + (size_t)(col0 + ar) * 768 + ac;
    for (int k0 = 0; k0 < 768; k0 += 32) {
        uint4 av = *(const uint4*)(xp + k0);
        uint4 wv = *(const uint4*)(wp + k0);
        __syncthreads();
        *(uint4*)(&At[ar * 32 + (ac ^ aswz)]) = av;
        *(uint4*)(&Bt[ar * 32 + (ac ^ aswz)]) = wv;
        __syncthreads();
        bf16x8 afr = *(const bf16x8*)(&At[am * 32 + ((q << 3) ^ acs)]);
        #pragma unroll
        for (int t4 = 0; t4 < 4; t4++) {
            int bn = (t4 << 4) + lm;
            bf16x8 bfr = *(const bf16x8*)(&Bt[bn * 32 + ((q << 3) ^ (((bn >> 3) & 3) << 3))]);
            acc[t4] = __builtin_amdgcn_mfma_f32_16x16x32_bf16(afr, bfr, acc[t4], 0, 0, 0);
        }
    }

    if (mode == 1 && dtOut) {
        #pragma unroll
        for (int t4 = 0; t4 < 4; t4++) {
            int col = col0 + (t4 << 4) + lm;
            float bsv = loadF(bias, col, dtW);
            #pragma unroll
            for (int rg = 0; rg < 4; rg++) {
                int row = row0 + (w << 4) + (q << 2) + rg;
                ((float*)dst)[(size_t)row * 768 + col] = acc[t4][rg] + bsv;
            }
        }
        return;
    }

    __syncthreads();
    #pragma unroll
    for (int t4 = 0; t4 < 4; t4++) {
        int colL = (t4 << 4) + lm;
        float bsv = loadF(bias, col0 + colL, dtW);
        #pragma unroll
        for (int rg = 0; rg < 4; rg++) {
            int rowL = (w << 4) + (q << 2) + rg;
            unsigned short hv = f2b(acc[t4][rg] + bsv);
            if (mode == 2) smem[colL * 72 + rowL] = hv;
            else           smem[rowL * 72 + colL] = hv;
        }
    }
    __syncthreads();
    const int g = t >> 2, c0 = (t & 3) << 4;
    uint4 w0 = *(const uint4*)&smem[g * 72 + c0];
    uint4 w1v = *(const uint4*)&smem[g * 72 + c0 + 8];
    unsigned short* o;
    if (mode == 0) {
        int b = row0 >> 9, n0b = row0 & 511, h = col0 >> 6;
        o = (unsigned short*)dst + ((size_t)(b * 12 + h) * 512 + n0b + g) * 64 + c0;
    } else if (mode == 2) {
        int b = row0 >> 9, n0b = row0 & 511, h = col0 >> 6;
        o = (unsigned short*)dst + ((size_t)(b * 12 + h) * 64 + g) * 512 + n0b + c0;
    } else {
        o = (unsigned short*)dst + (size_t)(row0 + g) * 768 + col0 + c0;
    }
    *(uint4*)o = w0;
    *(uint4*)(o + 8) = w1v;
}

// ---------------------------------------------------------------------------
// MFMA attention. Block = 16 Q rows of one (b,h). 4 waves.
// 1-D grid, id = bh + 96*qb (XCD-resident K/V).
// ---------------------------------------------------------------------------
__global__ __launch_bounds__(256) void attn_kernel(
        const unsigned short* __restrict__ qh, const unsigned short* __restrict__ kh,
        const unsigned short* __restrict__ vT, const unsigned int* __restrict__ pm,
        const float* __restrict__ alphas, unsigned short* __restrict__ atted)
{
    __shared__ unsigned short P[16 * 512];
    __shared__ float Zp[4][16][3];
    __shared__ unsigned short Ost[16 * 72];
    const int t = threadIdx.x;
    const int w = t >> 6, lane = t & 63, quad = lane >> 4, lm = lane & 15;
    const int id = blockIdx.x;
    const int bh = id % 96, qb = id / 96;
    const int b = bh / 12, h = bh % 12;
    const int n0 = qb << 4;

    const unsigned short* qrow = qh + ((size_t)(bh * 512 + n0 + lm)) * 64 + (quad << 3);
    bf16x8 qa0 = *(const bf16x8*)qrow;
    bf16x8 qa1 = *(const bf16x8*)(qrow + 32);
    f32x4 acc[8];
    #pragma unroll
    for (int i = 0; i < 8; i++) acc[i] = (f32x4){0.f, 0.f, 0.f, 0.f};
    const unsigned short* kb0 = kh + ((size_t)(bh * 512 + (w << 7) + lm)) * 64 + (quad << 3);
    #pragma unroll
    for (int nt = 0; nt < 8; nt++) {
        const unsigned short* kr = kb0 + nt * (16 * 64);
        bf16x8 k0 = *(const bf16x8*)kr;
        bf16x8 k1 = *(const bf16x8*)(kr + 32);
        acc[nt] = __builtin_amdgcn_mfma_f32_16x16x32_bf16(qa0, k0, acc[nt], 0, 0, 0);
        acc[nt] = __builtin_amdgcn_mfma_f32_16x16x32_bf16(qa1, k1, acc[nt], 0, 0, 0);
    }

    float al[3];
    #pragma unroll
    for (int l = 0; l < 3; l++) al[l] = alphas[b * 3 + l];

    #pragma unroll
    for (int nt = 0; nt < 8; nt++)
        #pragma unroll
        for (int rg = 0; rg < 4; rg++)
            acc[nt][rg] = __expf(acc[nt][rg] * 0.125f);

    unsigned int mk[4][3];
    #pragma unroll
    for (int rg = 0; rg < 4; rg++)
        #pragma unroll
        for (int l = 0; l < 3; l++)
            mk[rg][l] = pm[((size_t)((l << 3) + b) * 512 + n0 + (quad << 2) + rg) * 16 + lm];

    #pragma unroll
    for (int rg = 0; rg < 4; rg++) {
        float z0 = 0.f, z1 = 0.f, z2 = 0.f;
        #pragma unroll
        for (int nt = 0; nt < 8; nt++) {
            int g = (w << 3) + nt;
            float e = acc[nt][rg];
            if (!((mk[rg][0] >> g) & 1)) z0 += e;
            if (!((mk[rg][1] >> g) & 1)) z1 += e;
            if (!((mk[rg][2] >> g) & 1)) z2 += e;
        }
        #pragma unroll
        for (int off = 1; off < 16; off <<= 1) {
            z0 += __shfl_xor(z0, off);
            z1 += __shfl_xor(z1, off);
            z2 += __shfl_xor(z2, off);
        }
        if (lm == 0) {
            int row = (quad << 2) + rg;
            Zp[w][row][0] = z0; Zp[w][row][1] = z1; Zp[w][row][2] = z2;
        }
    }
    __syncthreads();

    #pragma unroll
    for (int rg = 0; rg < 4; rg++) {
        int row = (quad << 2) + rg;
        float coef[3]; float addu = 0.f;
        #pragma unroll
        for (int l = 0; l < 3; l++) {
            float Z = Zp[0][row][l] + Zp[1][row][l] + Zp[2][row][l] + Zp[3][row][l];
            if (Z > 0.f) coef[l] = al[l] / Z;
            else { coef[l] = 0.f; addu += al[l] * (1.0f / 512.0f); }
        }
        #pragma unroll
        for (int nt = 0; nt < 8; nt++) {
            int g = (w << 3) + nt;
            float p = addu;
            float e = acc[nt][rg];
            if (!((mk[rg][0] >> g) & 1)) p += coef[0] * e;
            if (!((mk[rg][1] >> g) & 1)) p += coef[1] * e;
            if (!((mk[rg][2] >> g) & 1)) p += coef[2] * e;
            int c = (g << 4) + lm;
            int chunk = c >> 3, j = c & 7;
            P[row * 512 + (((chunk ^ (row & 7))) << 3) + j] = f2b(p);
        }
    }
    __syncthreads();

    f32x4 accO = (f32x4){0.f, 0.f, 0.f, 0.f};
    const unsigned short* vb = vT + ((size_t)(bh * 64 + (w << 4) + lm)) * 512 + (quad << 3);
    #pragma unroll
    for (int ks = 0; ks < 16; ks++) {
        bf16x8 pa = *(const bf16x8*)&P[lm * 512 + ((((ks << 2) + quad) ^ (lm & 7)) << 3)];
        bf16x8 vf = *(const bf16x8*)(vb + (ks << 5));
        accO = __builtin_amdgcn_mfma_f32_16x16x32_bf16(pa, vf, accO, 0, 0, 0);
    }
    #pragma unroll
    for (int rg = 0; rg < 4; rg++)
        Ost[((quad << 2) + rg) * 72 + (w << 4) + lm] = f2b(accO[rg]);
    __syncthreads();
    const int r2 = t >> 4, c4 = t & 15;
    uint2 val = *(const uint2*)&Ost[r2 * 72 + (c4 << 2)];
    *(uint2*)&atted[((size_t)(b * 512 + n0 + r2)) * 768 + (h << 6) + (c4 << 2)] = val;
}

// ---------------------------------------------------------------------------
extern "C" void kernel_launch(void* const* d_in, const int* in_sizes, int n_in,
                              void* d_out, int out_size, void* d_ws, size_t ws_size,
                              hipStream_t stream)
{
    const void* v  = d_in[0];
    const void* k  = d_in[1];
    const void* q  = d_in[2];
    const void* mk = d_in[3];
    const void* Wv = d_in[6];
    const void* bv = d_in[7];
    const void* Wk = d_in[8];
    const void* bk = d_in[9];
    const void* Wq = d_in[10];
    const void* bq = d_in[11];
    const void* Wm = d_in[12];
    const void* bm = d_in[13];
    const void* pool_w = d_in[14];
    const void* pool_b = d_in[15];
    const void* w1 = d_in[16];
    const void* w2 = d_in[17];
    const void* b2 = d_in[18];

    char* ws = (char*)d_ws;
    int*   flags  = (int*)ws;                                   // 64 B
    float* alphas = (float*)(ws + 256);
    float* scores = (float*)(ws + 512);                         // 16 KB
    float* scs    = (float*)(ws + 16896);                       // 16 KB
    float* ppart  = (float*)(ws + 33280);                       // 196 KB
    float* plog   = (float*)(ws + 229888);                      // 1.2 KB
    unsigned int* pm = (unsigned int*)(ws + 262144);            // 786 KB
    unsigned short* qh  = (unsigned short*)(ws + 1048576);      // 6.29 MB each
    unsigned short* kh  = (unsigned short*)(ws + 1048576 + 1 * 6291456L);
    unsigned short* vT  = (unsigned short*)(ws + 1048576 + 2 * 6291456L);
    unsigned short* vb  = (unsigned short*)(ws + 1048576 + 3 * 6291456L);
    unsigned short* kb  = (unsigned short*)(ws + 1048576 + 4 * 6291456L);
    unsigned short* qb  = (unsigned short*)(ws + 1048576 + 5 * 6291456L);
    unsigned short* atted = vb;  // alias: vb dead by attention time
    char* wt0 = ws + 1048576 + 6 * 6291456L;                    // 1.18 MB each
    unsigned short* WTv = (unsigned short*)(wt0);
    unsigned short* WTk = (unsigned short*)(wt0 + 1 * 1179648L);
    unsigned short* WTq = (unsigned short*)(wt0 + 2 * 1179648L);
    unsigned short* WTm = (unsigned short*)(wt0 + 3 * 1179648L);

    sniff_kernel<<<dim3(1), dim3(256), 0, stream>>>(
        (const unsigned int*)mk, (const unsigned int*)v, (const unsigned int*)Wv, flags);
    conv_act_kernel<<<dim3(1536, 3), dim3(256), 0, stream>>>(v, k, q, flags, vb, kb, qb);
    conv_wt_kernel<<<dim3(144, 4), dim3(256), 0, stream>>>(
        Wv, Wk, Wq, Wm, flags, WTv, WTk, WTq, WTm);
    pack_kernel<<<dim3(384), dim3(256), 0, stream>>>(mk, flags, pm);
    route_score_kernel<<<dim3(64), dim3(256), 0, stream>>>(v, pool_w, pool_b, flags, scores);
    route_softmax_kernel<<<dim3(8), dim3(512), 0, stream>>>(scores, scs);
    route_pool_kernel<<<dim3(8, 8), dim3(256), 0, stream>>>(v, flags, scs, ppart);
    route_hid_kernel<<<dim3(12, 8), dim3(256), 0, stream>>>(w1, w2, flags, ppart, plog);
    route_alpha_kernel<<<dim3(8), dim3(64), 0, stream>>>(b2, flags, plog, alphas);
    gemm_kernel<<<dim3(768), dim3(256), 0, stream>>>(vb, WTv, bv, flags, (void*)vT, 2);
    gemm_kernel<<<dim3(768), dim3(256), 0, stream>>>(kb, WTk, bk, flags, (void*)kh, 0);
    gemm_kernel<<<dim3(768), dim3(256), 0, stream>>>(qb, WTq, bq, flags, (void*)qh, 0);
    attn_kernel<<<dim3(3072), dim3(256), 0, stream>>>(qh, kh, vT, pm, alphas, atted);
    gemm_kernel<<<dim3(768), dim3(256), 0, stream>>>(atted, WTm, bm, flags, d_out, 1);
}

// Round 8
// 294.922 us; speedup vs baseline: 3.9181x; 1.0648x over previous
//
#include <hip/hip_runtime.h>
#include <hip/hip_bf16.h>
#include <stdint.h>

// ---------------------------------------------------------------------------
// SARoutingBlock. Round 8: BK=64 software-pipelined GEMM (register prefetch
// across the barrier, 12 K-steps, 16 KB LDS -> 10 blocks/CU) and the three
// projection GEMMs fused into one (768,3) launch (9 blocks/CU TLP).
// Attn: pre-shifted mask words (bfe-able bit tests). Rest unchanged.
// ---------------------------------------------------------------------------

typedef __bf16 bf16x8 __attribute__((ext_vector_type(8)));
typedef float f32x4 __attribute__((ext_vector_type(4)));

#define NEGV -1e9f

__device__ __forceinline__ float b2f(unsigned short h) {
    union { unsigned int u; float f; } x; x.u = ((unsigned int)h) << 16; return x.f;
}
__device__ __forceinline__ unsigned short f2b(float f) {
    union { float f; unsigned int u; } x; x.f = f;
    unsigned int u = x.u + 0x7FFFu + ((x.u >> 16) & 1u);
    return (unsigned short)(u >> 16);
}
__device__ __forceinline__ unsigned int packbf(unsigned int u0, unsigned int u1) {
    unsigned int r0 = (u0 + 0x7FFFu + ((u0 >> 16) & 1u)) >> 16;
    unsigned int r1 = (u1 + 0x7FFFu + ((u1 >> 16) & 1u)) & 0xFFFF0000u;
    return r0 | r1;
}
__device__ __forceinline__ uint4 load8bf(const void* base, size_t elemOff, int isF32) {
    if (!isF32) return *(const uint4*)((const unsigned short*)base + elemOff);
    const uint4* f = (const uint4*)((const float*)base + elemOff);
    uint4 a = f[0], b = f[1];
    uint4 r;
    r.x = packbf(a.x, a.y);
    r.y = packbf(a.z, a.w);
    r.z = packbf(b.x, b.y);
    r.w = packbf(b.z, b.w);
    return r;
}
__device__ __forceinline__ float loadF(const void* p, int idx, int isF32) {
    return isF32 ? ((const float*)p)[idx] : b2f(((const unsigned short*)p)[idx]);
}

// ---------------------------------------------------------------------------
// Sniffer: flags[0]=mask mode (0=i32,1=u8,2=f32,3=bf16); flags[1]=v/k/q dtype
// (0=bf16,1=f32); flags[2]=weights dtype.
// ---------------------------------------------------------------------------
__global__ void sniff_kernel(const unsigned int* __restrict__ mp,
                             const unsigned int* __restrict__ vp,
                             const unsigned int* __restrict__ wp,
                             int* __restrict__ flags)
{
    __shared__ int oki, oku, okf, badv, badw;
    if (threadIdx.x == 0) { oki = 1; oku = 1; okf = 1; badv = 0; badw = 0; }
    __syncthreads();
    int li = 1, lu = 1, lf = 1, bv = 0, bw = 0;
    for (int i = threadIdx.x; i < 16384; i += 256) {
        unsigned int w = mp[i];
        if (w > 1u) li = 0;
        if (w & 0xFEFEFEFEu) lu = 0;
        if (w != 0u && w != 0x3F800000u) lf = 0;
    }
    for (int i = threadIdx.x; i < 8192; i += 256) {
        unsigned int w = vp[i];
        float f0 = b2f((unsigned short)(w & 0xFFFF));
        float f1 = b2f((unsigned short)(w >> 16));
        if (!(fabsf(f0) < 1e4f) || !(fabsf(f1) < 1e4f)) bv = 1;
        w = wp[i];
        f0 = b2f((unsigned short)(w & 0xFFFF));
        f1 = b2f((unsigned short)(w >> 16));
        if (!(fabsf(f0) < 1e4f) || !(fabsf(f1) < 1e4f)) bw = 1;
    }
    if (!li) atomicAnd(&oki, 0);
    if (!lu) atomicAnd(&oku, 0);
    if (!lf) atomicAnd(&okf, 0);
    if (bv) atomicOr(&badv, 1);
    if (bw) atomicOr(&badw, 1);
    __syncthreads();
    if (threadIdx.x == 0) {
        flags[0] = oki ? 0 : (oku ? 1 : (okf ? 2 : 3));
        flags[1] = badv;
        flags[2] = badw;
    }
}

// ---------------------------------------------------------------------------
// conv_act: v,k,q -> contiguous bf16 copies. Grid (1536, 3) x 256 thr, 8/thr.
// ---------------------------------------------------------------------------
__global__ __launch_bounds__(256) void conv_act_kernel(
        const void* __restrict__ v, const void* __restrict__ k,
        const void* __restrict__ q, const int* __restrict__ flags,
        unsigned short* __restrict__ vb, unsigned short* __restrict__ kb,
        unsigned short* __restrict__ qb)
{
    const int dtV = flags[1];
    const int which = blockIdx.y;
    const void* src = (which == 0) ? v : (which == 1) ? k : q;
    unsigned short* dst = (which == 0) ? vb : (which == 1) ? kb : qb;
    size_t off = ((size_t)blockIdx.x * 256 + threadIdx.x) * 8;
    uint4 r = load8bf(src, off, dtV);
    *(uint4*)(dst + off) = r;
}

// ---------------------------------------------------------------------------
// conv_wt: W[768][768] -> WT bf16 [n][k] (transposed). Grid (144, 4), 256 thr.
// ---------------------------------------------------------------------------
__global__ __launch_bounds__(256) void conv_wt_kernel(
        const void* __restrict__ W0, const void* __restrict__ W1,
        const void* __restrict__ W2, const void* __restrict__ W3,
        const int* __restrict__ flags,
        unsigned short* __restrict__ T0, unsigned short* __restrict__ T1,
        unsigned short* __restrict__ T2, unsigned short* __restrict__ T3)
{
    __shared__ unsigned short tile[64][65];
    const int t = threadIdx.x;
    const int dtW = flags[2];
    const int which = blockIdx.y;
    const void* W = (which == 0) ? W0 : (which == 1) ? W1 : (which == 2) ? W2 : W3;
    unsigned short* T = (which == 0) ? T0 : (which == 1) ? T1 : (which == 2) ? T2 : T3;
    const int tk = (blockIdx.x / 12) << 6;
    const int tn = (blockIdx.x % 12) << 6;
    #pragma unroll
    for (int i = 0; i < 16; i++) {
        int idx = (i << 8) + t;
        int r = idx >> 6, c = idx & 63;
        tile[r][c] = f2b(loadF(W, (tk + r) * 768 + tn + c, dtW));
    }
    __syncthreads();
    #pragma unroll
    for (int i = 0; i < 16; i++) {
        int idx = (i << 8) + t;
        int rn = idx >> 6, ck = idx & 63;
        T[(size_t)(tn + rn) * 768 + tk + ck] = tile[ck][rn];
    }
}

// ---------------------------------------------------------------------------
// Mask bit-pack: pm[grow*16 + lm], grow = (l*8+b)*512 + n,
// bit g = mask[l,b,n, g*16+lm]. One block packs 32 rows.
// ---------------------------------------------------------------------------
__global__ __launch_bounds__(256) void pack_kernel(
        const void* __restrict__ masks, const int* __restrict__ flags,
        unsigned int* __restrict__ pm)
{
    __shared__ unsigned char flg[32 * 512];
    const int t = threadIdx.x;
    const int mode = flags[0];
    const size_t e0 = (size_t)blockIdx.x * (32 * 512);
    if (mode == 0 || mode == 2) {
        const uint4* p = (const uint4*)((const unsigned int*)masks + e0);
        for (int i = t; i < 4096; i += 256) {
            uint4 u = p[i];
            int base = i << 2;
            flg[base + 0] = u.x ? 1 : 0;
            flg[base + 1] = u.y ? 1 : 0;
            flg[base + 2] = u.z ? 1 : 0;
            flg[base + 3] = u.w ? 1 : 0;
        }
    } else if (mode == 1) {
        const uint4* p = (const uint4*)((const unsigned char*)masks + e0);
        for (int i = t; i < 1024; i += 256) {
            uint4 u = p[i];
            unsigned int uu[4] = {u.x, u.y, u.z, u.w};
            int base = i << 4;
            #pragma unroll
            for (int k2 = 0; k2 < 4; k2++)
                #pragma unroll
                for (int bb = 0; bb < 4; bb++)
                    flg[base + k2 * 4 + bb] = ((uu[k2] >> (bb * 8)) & 0xFFu) ? 1 : 0;
        }
    } else {
        const uint4* p = (const uint4*)((const unsigned short*)masks + e0);
        for (int i = t; i < 2048; i += 256) {
            uint4 u = p[i];
            unsigned int uu[4] = {u.x, u.y, u.z, u.w};
            int base = i << 3;
            #pragma unroll
            for (int k2 = 0; k2 < 4; k2++) {
                flg[base + k2 * 2 + 0] = (uu[k2] & 0xFFFFu) ? 1 : 0;
                flg[base + k2 * 2 + 1] = (uu[k2] >> 16) ? 1 : 0;
            }
        }
    }
    __syncthreads();
    for (int widx = t; widx < 512; widx += 256) {
        int rl = widx >> 4, lm = widx & 15;
        unsigned int bits = 0;
        #pragma unroll
        for (int g = 0; g < 32; g++)
            bits |= ((unsigned int)(flg[rl * 512 + (g << 4) + lm] & 1)) << g;
        pm[(size_t)blockIdx.x * 512 + widx] = bits;
    }
}

// ---------------------------------------------------------------------------
// Routing stage 1: raw pooling scores per row (64 rows/block, 4 thr/row).
// ---------------------------------------------------------------------------
__global__ __launch_bounds__(256) void route_score_kernel(
        const void* __restrict__ v, const void* __restrict__ pool_w,
        const void* __restrict__ pool_b, const int* __restrict__ flags,
        float* __restrict__ scores)
{
    __shared__ float pw[768];
    const int t = threadIdx.x;
    const int b = blockIdx.x >> 3, ch = blockIdx.x & 7;
    const int dtV = flags[1], dtW = flags[2];
    for (int d = t; d < 768; d += 256) pw[d] = loadF(pool_w, d, dtW);
    __syncthreads();
    const int r = t >> 2, c4 = t & 3;
    const int n = (ch << 6) + r;
    float dot = 0.f, asum = 0.f;
    if (!dtV) {
        const unsigned int* vr = (const unsigned int*)v + ((size_t)(b * 512 + n)) * 384;
        for (int j = 0; j < 96; j++) {
            int p = c4 + (j << 2);
            unsigned int u = vr[p];
            float f0 = b2f((unsigned short)(u & 0xFFFF));
            float f1 = b2f((unsigned short)(u >> 16));
            asum += fabsf(f0) + fabsf(f1);
            dot += f0 * pw[2 * p] + f1 * pw[2 * p + 1];
        }
    } else {
        const float* vf = (const float*)v + ((size_t)(b * 512 + n)) * 768;
        for (int j = 0; j < 48; j++) {
            float4 u = ((const float4*)vf)[c4 + (j << 2)];
            int e = (c4 + (j << 2)) << 2;
            asum += fabsf(u.x) + fabsf(u.y) + fabsf(u.z) + fabsf(u.w);
            dot += u.x * pw[e] + u.y * pw[e + 1] + u.z * pw[e + 2] + u.w * pw[e + 3];
        }
    }
    dot += __shfl_xor(dot, 1); dot += __shfl_xor(dot, 2);
    asum += __shfl_xor(asum, 1); asum += __shfl_xor(asum, 2);
    if (c4 == 0)
        scores[b * 512 + n] = (asum == 0.f) ? NEGV : dot + loadF(pool_b, 0, dtW);
}

// ---------------------------------------------------------------------------
// Routing stage 2: softmax over N per batch -> scs. 8 blocks x 512.
// ---------------------------------------------------------------------------
__global__ __launch_bounds__(512) void route_softmax_kernel(
        const float* __restrict__ scores, float* __restrict__ scs)
{
    __shared__ float red[8];
    const int t = threadIdx.x, b = blockIdx.x;
    float scv = scores[b * 512 + t];
    float mx = scv;
    #pragma unroll
    for (int off = 1; off < 64; off <<= 1) mx = fmaxf(mx, __shfl_xor(mx, off));
    if ((t & 63) == 0) red[t >> 6] = mx;
    __syncthreads();
    float M = red[0];
    #pragma unroll
    for (int i = 1; i < 8; i++) M = fmaxf(M, red[i]);
    float e = __expf(scv - M);
    __syncthreads();
    float sm = e;
    #pragma unroll
    for (int off = 1; off < 64; off <<= 1) sm += __shfl_xor(sm, off);
    if ((t & 63) == 0) red[t >> 6] = sm;
    __syncthreads();
    float SS = 0.f;
    #pragma unroll
    for (int i = 0; i < 8; i++) SS += red[i];
    scs[b * 512 + t] = e / SS;
}

// ---------------------------------------------------------------------------
// Routing stage 3: partial pooled sums. Grid (8 chunks, 8 b), 256 thr.
// ---------------------------------------------------------------------------
__global__ __launch_bounds__(256) void route_pool_kernel(
        const void* __restrict__ v, const int* __restrict__ flags,
        const float* __restrict__ scs, float* __restrict__ ppart)
{
    __shared__ float ps[64];
    const int t = threadIdx.x;
    const int ch = blockIdx.x, b = blockIdx.y;
    const int dtV = flags[1];
    if (t < 64) ps[t] = scs[b * 512 + (ch << 6) + t];
    __syncthreads();
    const int d0 = t * 3;
    float a0 = 0.f, a1 = 0.f, a2 = 0.f;
    if (!dtV) {
        const unsigned short* vb = (const unsigned short*)v
            + ((size_t)(b * 512 + (ch << 6))) * 768 + d0;
        #pragma unroll 4
        for (int r = 0; r < 64; r++) {
            float p = ps[r];
            a0 += b2f(vb[0]) * p; a1 += b2f(vb[1]) * p; a2 += b2f(vb[2]) * p;
            vb += 768;
        }
    } else {
        const float* vb = (const float*)v + ((size_t)(b * 512 + (ch << 6))) * 768 + d0;
        #pragma unroll 4
        for (int r = 0; r < 64; r++) {
            float p = ps[r];
            a0 += vb[0] * p; a1 += vb[1] * p; a2 += vb[2] * p;
            vb += 768;
        }
    }
    float* o = ppart + ((size_t)(b * 8 + ch)) * 768 + d0;
    o[0] = a0; o[1] = a1; o[2] = a2;
}

// ---------------------------------------------------------------------------
// Routing stage 4: hidden units + partial logits. Grid (12 jc, 8 b), 256 thr.
// ---------------------------------------------------------------------------
__global__ __launch_bounds__(256) void route_hid_kernel(
        const void* __restrict__ w1, const void* __restrict__ w2,
        const int* __restrict__ flags, const float* __restrict__ ppart,
        float* __restrict__ plog)
{
    __shared__ float pool[768];
    __shared__ float red[4][32];
    const int t = threadIdx.x;
    const int jc = blockIdx.x, b = blockIdx.y;
    const int dtW = flags[2];
    for (int d = t; d < 768; d += 256) {
        float a = 0.f;
        #pragma unroll
        for (int c = 0; c < 8; c++) a += ppart[((size_t)(b * 8 + c)) * 768 + d];
        pool[d] = a;
    }
    __syncthreads();
    const int jo = (t & 3) << 3;
    const int dr = t >> 2;
    float acc[8];
    #pragma unroll
    for (int j = 0; j < 8; j++) acc[j] = 0.f;
    for (int it = 0; it < 12; it++) {
        int d = (it << 6) + dr;
        float pv = pool[d];
        size_t off = (size_t)d * 384 + (jc << 5) + jo;
        if (!dtW) {
            uint4 u = *(const uint4*)((const unsigned short*)w1 + off);
            unsigned int uu[4] = {u.x, u.y, u.z, u.w};
            #pragma unroll
            for (int j2 = 0; j2 < 4; j2++) {
                acc[2 * j2]     += pv * b2f((unsigned short)(uu[j2] & 0xFFFF));
                acc[2 * j2 + 1] += pv * b2f((unsigned short)(uu[j2] >> 16));
            }
        } else {
            const float4* f = (const float4*)((const float*)w1 + off);
            float4 u0 = f[0], u1 = f[1];
            acc[0] += pv * u0.x; acc[1] += pv * u0.y;
            acc[2] += pv * u0.z; acc[3] += pv * u0.w;
            acc[4] += pv * u1.x; acc[5] += pv * u1.y;
            acc[6] += pv * u1.z; acc[7] += pv * u1.w;
        }
    }
    #pragma unroll
    for (int off = 4; off < 64; off <<= 1)
        #pragma unroll
        for (int j = 0; j < 8; j++) acc[j] += __shfl_xor(acc[j], off);
    const int w = t >> 6, lane = t & 63;
    if (lane < 4) {
        #pragma unroll
        for (int j = 0; j < 8; j++) red[w][lane * 8 + j] = acc[j];
    }
    __syncthreads();
    if (t < 32) {
        float h = red[0][t] + red[1][t] + red[2][t] + red[3][t];
        h = fmaxf(h, 0.f);
        int jg = (jc << 5) + t;
        float l0 = h * loadF(w2, jg * 3 + 0, dtW);
        float l1 = h * loadF(w2, jg * 3 + 1, dtW);
        float l2 = h * loadF(w2, jg * 3 + 2, dtW);
        #pragma unroll
        for (int off = 1; off < 32; off <<= 1) {
            l0 += __shfl_xor(l0, off);
            l1 += __shfl_xor(l1, off);
            l2 += __shfl_xor(l2, off);
        }
        if (t == 0) {
            float* o = plog + ((size_t)(b * 12 + jc)) * 3;
            o[0] = l0; o[1] = l1; o[2] = l2;
        }
    }
}

// ---------------------------------------------------------------------------
// Routing stage 5: reduce partial logits, softmax -> alphas. 8 tiny blocks.
// ---------------------------------------------------------------------------
__global__ __launch_bounds__(64) void route_alpha_kernel(
        const void* __restrict__ b2, const int* __restrict__ flags,
        const float* __restrict__ plog, float* __restrict__ alphas)
{
    const int t = threadIdx.x, b = blockIdx.x;
    if (t == 0) {
        const int dtW = flags[2];
        float lg[3];
        #pragma unroll
        for (int l = 0; l < 3; l++) {
            float a = loadF(b2, l, dtW);
            for (int jc = 0; jc < 12; jc++) a += plog[((size_t)(b * 12 + jc)) * 3 + l];
            lg[l] = a;
        }
        float mm = fmaxf(lg[0], fmaxf(lg[1], lg[2]));
        float e0 = __expf(lg[0] - mm), e1 = __expf(lg[1] - mm), e2 = __expf(lg[2] - mm);
        float ss = e0 + e1 + e2;
        alphas[b * 3 + 0] = e0 / ss;
        alphas[b * 3 + 1] = e1 / ss;
        alphas[b * 3 + 2] = e2 / ss;
    }
}

// ---------------------------------------------------------------------------
// Pipelined MFMA bf16 GEMM, up to 3 sub-gemms selected by blockIdx.y.
// C[4096x768] = X @ WT^T + bias; BK=64 (12 steps), register prefetch across
// the barrier. LDS 16 KB. 1-D x-grid id = y + 64*x (XCD co-location).
// mode 0: dst[b][h][n][64]; mode 1: dst[row][col] (bf16/f32); mode 2: V^T.
// ---------------------------------------------------------------------------
__global__ __launch_bounds__(256) void gemm3_kernel(
        const unsigned short* __restrict__ X0, const unsigned short* __restrict__ X1,
        const unsigned short* __restrict__ X2,
        const unsigned short* __restrict__ W0, const unsigned short* __restrict__ W1,
        const unsigned short* __restrict__ W2,
        const void* __restrict__ bias0, const void* __restrict__ bias1,
        const void* __restrict__ bias2,
        const int* __restrict__ flags,
        void* __restrict__ dst0, void* __restrict__ dst1, void* __restrict__ dst2,
        int m0, int m1, int m2)
{
    __shared__ unsigned short smem[8192];   // At[4096] + Bt[4096], 16 KB
    unsigned short* At = smem;
    unsigned short* Bt = smem + 4096;
    const int t = threadIdx.x;
    const int which = blockIdx.y;
    const unsigned short* X  = (which == 0) ? X0 : (which == 1) ? X1 : X2;
    const unsigned short* WT = (which == 0) ? W0 : (which == 1) ? W1 : W2;
    const void* bias = (which == 0) ? bias0 : (which == 1) ? bias1 : bias2;
    void* dst = (which == 0) ? dst0 : (which == 1) ? dst1 : dst2;
    const int mode = (which == 0) ? m0 : (which == 1) ? m1 : m2;

    const int id = blockIdx.x;
    const int bx = id >> 6, by = id & 63;
    const int row0 = by << 6, col0 = bx << 6;
    const int w = t >> 6, lane = t & 63, quad = lane >> 4, lm = lane & 15;
    const int r0 = t >> 3, c0 = (t & 7) << 3;
    const int wr0 = r0 * 64 + (c0 ^ ((r0 & 7) << 3));   // +2048 for rows 32..63
    const int dtW = flags[2];
    const int dtOut = flags[1];

    const unsigned short* xp  = X  + (size_t)(row0 + r0) * 768 + c0;
    const unsigned short* xp2 = xp + 32 * 768;
    const unsigned short* wp  = WT + (size_t)(col0 + r0) * 768 + c0;
    const unsigned short* wp2 = wp + 32 * 768;

    uint4 a0 = *(const uint4*)xp,  a1 = *(const uint4*)xp2;
    uint4 g0 = *(const uint4*)wp,  g1 = *(const uint4*)wp2;

    f32x4 acc[4];
    #pragma unroll
    for (int i = 0; i < 4; i++) acc[i] = (f32x4){0.f, 0.f, 0.f, 0.f};

    const int am = (w << 4) + lm;
    const int abase = am * 64, akey = (am & 7) << 3;

    for (int k0 = 0;;) {
        __syncthreads();
        *(uint4*)&At[wr0] = a0;        *(uint4*)&At[wr0 + 2048] = a1;
        *(uint4*)&Bt[wr0] = g0;        *(uint4*)&Bt[wr0 + 2048] = g1;
        __syncthreads();
        k0 += 64;
        if (k0 < 768) {    // prefetch next step; latency overlaps MFMAs below
            a0 = *(const uint4*)(xp + k0);  a1 = *(const uint4*)(xp2 + k0);
            g0 = *(const uint4*)(wp + k0);  g1 = *(const uint4*)(wp2 + k0);
        }
        #pragma unroll
        for (int ks = 0; ks < 2; ks++) {
            int ko = (quad << 3) + (ks << 5);
            bf16x8 afr = *(const bf16x8*)&At[abase + (ko ^ akey)];
            #pragma unroll
            for (int t4 = 0; t4 < 4; t4++) {
                int bn = (t4 << 4) + lm;
                bf16x8 bfr = *(const bf16x8*)&Bt[bn * 64 + (ko ^ ((bn & 7) << 3))];
                acc[t4] = __builtin_amdgcn_mfma_f32_16x16x32_bf16(afr, bfr, acc[t4], 0, 0, 0);
            }
        }
        if (k0 >= 768) break;
    }

    if (mode == 1 && dtOut) {
        #pragma unroll
        for (int t4 = 0; t4 < 4; t4++) {
            int col = col0 + (t4 << 4) + lm;
            float bsv = loadF(bias, col, dtW);
            #pragma unroll
            for (int rg = 0; rg < 4; rg++) {
                int row = row0 + (w << 4) + (quad << 2) + rg;
                ((float*)dst)[(size_t)row * 768 + col] = acc[t4][rg] + bsv;
            }
        }
        return;
    }

    __syncthreads();   // reuse smem[0..4608] as output tile (stride 72)
    #pragma unroll
    for (int t4 = 0; t4 < 4; t4++) {
        int colL = (t4 << 4) + lm;
        float bsv = loadF(bias, col0 + colL, dtW);
        #pragma unroll
        for (int rg = 0; rg < 4; rg++) {
            int rowL = (w << 4) + (quad << 2) + rg;
            unsigned short hv = f2b(acc[t4][rg] + bsv);
            if (mode == 2) smem[colL * 72 + rowL] = hv;
            else           smem[rowL * 72 + colL] = hv;
        }
    }
    __syncthreads();
    const int g = t >> 2, cc = (t & 3) << 4;
    uint4 o0 = *(const uint4*)&smem[g * 72 + cc];
    uint4 o1 = *(const uint4*)&smem[g * 72 + cc + 8];
    unsigned short* o;
    if (mode == 0) {
        int b = row0 >> 9, n0b = row0 & 511, h = col0 >> 6;
        o = (unsigned short*)dst + ((size_t)(b * 12 + h) * 512 + n0b + g) * 64 + cc;
    } else if (mode == 2) {
        int b = row0 >> 9, n0b = row0 & 511, h = col0 >> 6;
        o = (unsigned short*)dst + ((size_t)(b * 12 + h) * 64 + g) * 512 + n0b + cc;
    } else {
        o = (unsigned short*)dst + (size_t)(row0 + g) * 768 + col0 + cc;
    }
    *(uint4*)o = o0;
    *(uint4*)(o + 8) = o1;
}

// ---------------------------------------------------------------------------
// MFMA attention. Block = 16 Q rows of one (b,h). 4 waves.
// 1-D grid, id = bh + 96*qb (XCD-resident K/V). Masks pre-shifted by w*8.
// ---------------------------------------------------------------------------
__global__ __launch_bounds__(256) void attn_kernel(
        const unsigned short* __restrict__ qh, const unsigned short* __restrict__ kh,
        const unsigned short* __restrict__ vT, const unsigned int* __restrict__ pm,
        const float* __restrict__ alphas, unsigned short* __restrict__ atted)
{
    __shared__ unsigned short P[16 * 512];
    __shared__ float Zp[4][16][3];
    __shared__ unsigned short Ost[16 * 72];
    const int t = threadIdx.x;
    const int w = t >> 6, lane = t & 63, quad = lane >> 4, lm = lane & 15;
    const int id = blockIdx.x;
    const int bh = id % 96, qb = id / 96;
    const int b = bh / 12, h = bh % 12;
    const int n0 = qb << 4;

    const unsigned short* qrow = qh + ((size_t)(bh * 512 + n0 + lm)) * 64 + (quad << 3);
    bf16x8 qa0 = *(const bf16x8*)qrow;
    bf16x8 qa1 = *(const bf16x8*)(qrow + 32);
    f32x4 acc[8];
    #pragma unroll
    for (int i = 0; i < 8; i++) acc[i] = (f32x4){0.f, 0.f, 0.f, 0.f};
    const unsigned short* kb0 = kh + ((size_t)(bh * 512 + (w << 7) + lm)) * 64 + (quad << 3);
    #pragma unroll
    for (int nt = 0; nt < 8; nt++) {
        const unsigned short* kr = kb0 + nt * (16 * 64);
        bf16x8 k0 = *(const bf16x8*)kr;
        bf16x8 k1 = *(const bf16x8*)(kr + 32);
        acc[nt] = __builtin_amdgcn_mfma_f32_16x16x32_bf16(qa0, k0, acc[nt], 0, 0, 0);
        acc[nt] = __builtin_amdgcn_mfma_f32_16x16x32_bf16(qa1, k1, acc[nt], 0, 0, 0);
    }

    float al[3];
    #pragma unroll
    for (int l = 0; l < 3; l++) al[l] = alphas[b * 3 + l];

    #pragma unroll
    for (int nt = 0; nt < 8; nt++)
        #pragma unroll
        for (int rg = 0; rg < 4; rg++)
            acc[nt][rg] = __expf(acc[nt][rg] * 0.125f);

    // pre-shift mask words by w*8: bit nt (compile-time) = this wave's key g
    unsigned int mkw[4][3];
    #pragma unroll
    for (int rg = 0; rg < 4; rg++)
        #pragma unroll
        for (int l = 0; l < 3; l++)
            mkw[rg][l] = pm[((size_t)((l << 3) + b) * 512 + n0 + (quad << 2) + rg) * 16 + lm]
                         >> (w << 3);

    #pragma unroll
    for (int rg = 0; rg < 4; rg++) {
        float z0 = 0.f, z1 = 0.f, z2 = 0.f;
        #pragma unroll
        for (int nt = 0; nt < 8; nt++) {
            float e = acc[nt][rg];
            if (!((mkw[rg][0] >> nt) & 1)) z0 += e;
            if (!((mkw[rg][1] >> nt) & 1)) z1 += e;
            if (!((mkw[rg][2] >> nt) & 1)) z2 += e;
        }
        #pragma unroll
        for (int off = 1; off < 16; off <<= 1) {
            z0 += __shfl_xor(z0, off);
            z1 += __shfl_xor(z1, off);
            z2 += __shfl_xor(z2, off);
        }
        if (lm == 0) {
            int row = (quad << 2) + rg;
            Zp[w][row][0] = z0; Zp[w][row][1] = z1; Zp[w][row][2] = z2;
        }
    }
    __syncthreads();

    #pragma unroll
    for (int rg = 0; rg < 4; rg++) {
        int row = (quad << 2) + rg;
        float coef[3]; float addu = 0.f;
        #pragma unroll
        for (int l = 0; l < 3; l++) {
            float Z = Zp[0][row][l] + Zp[1][row][l] + Zp[2][row][l] + Zp[3][row][l];
            if (Z > 0.f) coef[l] = al[l] / Z;
            else { coef[l] = 0.f; addu += al[l] * (1.0f / 512.0f); }
        }
        #pragma unroll
        for (int nt = 0; nt < 8; nt++) {
            int g = (w << 3) + nt;
            float p = addu;
            float e = acc[nt][rg];
            if (!((mkw[rg][0] >> nt) & 1)) p += coef[0] * e;
            if (!((mkw[rg][1] >> nt) & 1)) p += coef[1] * e;
            if (!((mkw[rg][2] >> nt) & 1)) p += coef[2] * e;
            int c = (g << 4) + lm;
            int chunk = c >> 3, j = c & 7;
            P[row * 512 + (((chunk ^ (row & 7))) << 3) + j] = f2b(p);
        }
    }
    __syncthreads();

    f32x4 accO = (f32x4){0.f, 0.f, 0.f, 0.f};
    const unsigned short* vb = vT + ((size_t)(bh * 64 + (w << 4) + lm)) * 512 + (quad << 3);
    #pragma unroll
    for (int ks = 0; ks < 16; ks++) {
        bf16x8 pa = *(const bf16x8*)&P[lm * 512 + ((((ks << 2) + quad) ^ (lm & 7)) << 3)];
        bf16x8 vf = *(const bf16x8*)(vb + (ks << 5));
        accO = __builtin_amdgcn_mfma_f32_16x16x32_bf16(pa, vf, accO, 0, 0, 0);
    }
    #pragma unroll
    for (int rg = 0; rg < 4; rg++)
        Ost[((quad << 2) + rg) * 72 + (w << 4) + lm] = f2b(accO[rg]);
    __syncthreads();
    const int r2 = t >> 4, c4 = t & 15;
    uint2 val = *(const uint2*)&Ost[r2 * 72 + (c4 << 2)];
    *(uint2*)&atted[((size_t)(b * 512 + n0 + r2)) * 768 + (h << 6) + (c4 << 2)] = val;
}

// ---------------------------------------------------------------------------
extern "C" void kernel_launch(void* const* d_in, const int* in_sizes, int n_in,
                              void* d_out, int out_size, void* d_ws, size_t ws_size,
                              hipStream_t stream)
{
    const void* v  = d_in[0];
    const void* k  = d_in[1];
    const void* q  = d_in[2];
    const void* mk = d_in[3];
    const void* Wv = d_in[6];
    const void* bv = d_in[7];
    const void* Wk = d_in[8];
    const void* bk = d_in[9];
    const void* Wq = d_in[10];
    const void* bq = d_in[11];
    const void* Wm = d_in[12];
    const void* bm = d_in[13];
    const void* pool_w = d_in[14];
    const void* pool_b = d_in[15];
    const void* w1 = d_in[16];
    const void* w2 = d_in[17];
    const void* b2 = d_in[18];

    char* ws = (char*)d_ws;
    int*   flags  = (int*)ws;                                   // 64 B
    float* alphas = (float*)(ws + 256);
    float* scores = (float*)(ws + 512);                         // 16 KB
    float* scs    = (float*)(ws + 16896);                       // 16 KB
    float* ppart  = (float*)(ws + 33280);                       // 196 KB
    float* plog   = (float*)(ws + 229888);                      // 1.2 KB
    unsigned int* pm = (unsigned int*)(ws + 262144);            // 786 KB
    unsigned short* qh  = (unsigned short*)(ws + 1048576);      // 6.29 MB each
    unsigned short* kh  = (unsigned short*)(ws + 1048576 + 1 * 6291456L);
    unsigned short* vT  = (unsigned short*)(ws + 1048576 + 2 * 6291456L);
    unsigned short* vb  = (unsigned short*)(ws + 1048576 + 3 * 6291456L);
    unsigned short* kb  = (unsigned short*)(ws + 1048576 + 4 * 6291456L);
    unsigned short* qb  = (unsigned short*)(ws + 1048576 + 5 * 6291456L);
    unsigned short* atted = vb;  // alias: vb dead by attention time
    char* wt0 = ws + 1048576 + 6 * 6291456L;                    // 1.18 MB each
    unsigned short* WTv = (unsigned short*)(wt0);
    unsigned short* WTk = (unsigned short*)(wt0 + 1 * 1179648L);
    unsigned short* WTq = (unsigned short*)(wt0 + 2 * 1179648L);
    unsigned short* WTm = (unsigned short*)(wt0 + 3 * 1179648L);

    sniff_kernel<<<dim3(1), dim3(256), 0, stream>>>(
        (const unsigned int*)mk, (const unsigned int*)v, (const unsigned int*)Wv, flags);
    conv_act_kernel<<<dim3(1536, 3), dim3(256), 0, stream>>>(v, k, q, flags, vb, kb, qb);
    conv_wt_kernel<<<dim3(144, 4), dim3(256), 0, stream>>>(
        Wv, Wk, Wq, Wm, flags, WTv, WTk, WTq, WTm);
    pack_kernel<<<dim3(384), dim3(256), 0, stream>>>(mk, flags, pm);
    route_score_kernel<<<dim3(64), dim3(256), 0, stream>>>(v, pool_w, pool_b, flags, scores);
    route_softmax_kernel<<<dim3(8), dim3(512), 0, stream>>>(scores, scs);
    route_pool_kernel<<<dim3(8, 8), dim3(256), 0, stream>>>(v, flags, scs, ppart);
    route_hid_kernel<<<dim3(12, 8), dim3(256), 0, stream>>>(w1, w2, flags, ppart, plog);
    route_alpha_kernel<<<dim3(8), dim3(64), 0, stream>>>(b2, flags, plog, alphas);
    gemm3_kernel<<<dim3(768, 3), dim3(256), 0, stream>>>(
        vb, kb, qb, WTv, WTk, WTq, bv, bk, bq, flags,
        (void*)vT, (void*)kh, (void*)qh, 2, 0, 0);
    attn_kernel<<<dim3(3072), dim3(256), 0, stream>>>(qh, kh, vT, pm, alphas, atted);
    gemm3_kernel<<<dim3(768, 1), dim3(256), 0, stream>>>(
        atted, atted, atted, WTm, WTm, WTm, bm, bm, bm, flags,
        d_out, d_out, d_out, 1, 1, 1);
}